// Round 1
// 1956.618 us; speedup vs baseline: 1.1331x; 1.1331x over previous
//
#include <hip/hip_runtime.h>
#include <hip/hip_bf16.h>

typedef __hip_bfloat16 bf16;
typedef __bf16 bfv8 __attribute__((ext_vector_type(8)));
typedef float fv4 __attribute__((ext_vector_type(4)));

#define B_  8
#define T_  1024
#define INP 512
#define D_  1024
#define I_  2048
#define N_  64
#define H_  16
#define P_  128
#define L_  4
#define OUT_ 512
#define CB_ 1024
#define CONV_DIM 2176
#define PROJ 4240
#define M_  (B_*T_)       // 8192 rows
#define TC  64            // scan chunk length
#define NC  (T_/TC)       // 16 chunks

typedef const __attribute__((address_space(1))) void gv_t;
typedef __attribute__((address_space(3))) void lv_t;

__device__ __forceinline__ void load_lds16(const bf16* g, char* l) {
    __builtin_amdgcn_global_load_lds((gv_t*)g, (lv_t*)l, 16, 0, 0);
}

template <int N> __device__ __forceinline__ void wait_vm() {
    if constexpr (N == 0) asm volatile("s_waitcnt vmcnt(0)" ::: "memory");
    else if constexpr (N == 6) asm volatile("s_waitcnt vmcnt(6)" ::: "memory");
    else asm volatile("s_waitcnt vmcnt(8)" ::: "memory");
}
__device__ __forceinline__ void barrier_sync() {
    asm volatile("s_barrier" ::: "memory");
}

// ---------------------------------------------------------------------------
// fp32 -> bf16 copy
// ---------------------------------------------------------------------------
__global__ __launch_bounds__(256) void ingest_k(const float* __restrict__ src,
                                                bf16* __restrict__ dst, int n) {
    int i = blockIdx.x * 256 + threadIdx.x;
    if (i >= n) return;
    dst[i] = __float2bfloat16(src[i]);
}

// ---------------------------------------------------------------------------
// Transpose fp32 [R][C] -> bf16 [Cp][R], zero-padding rows C..Cp.
// ---------------------------------------------------------------------------
__global__ __launch_bounds__(256) void transpose_any(const float* __restrict__ in,
                                                     size_t off,
                                                     bf16* __restrict__ out,
                                                     int R, int C) {
    __shared__ bf16 tile[32][33];
    int c0 = blockIdx.x * 32, r0 = blockIdx.y * 32;
    int tx = threadIdx.x, ty = threadIdx.y;
#pragma unroll
    for (int i = 0; i < 4; ++i) {
        int r = r0 + ty + i * 8, c = c0 + tx;
        bf16 v = __float2bfloat16(0.f);
        if (c < C) v = __float2bfloat16(in[off + (size_t)r * C + c]);
        tile[ty + i * 8][tx] = v;
    }
    __syncthreads();
#pragma unroll
    for (int i = 0; i < 4; ++i) {
        int c = c0 + ty + i * 8;
        out[(size_t)c * R + r0 + tx] = tile[tx][ty + i * 8];
    }
}

// ---------------------------------------------------------------------------
// GEMM 256-class: C[M,BNxTiles] = A[M,K] @ Bt[N,K]^T.
// BM=256, BK=64, 512 thr = 8 waves (WGM x WGN), double-buffered LDS,
// T2 XOR-swizzle (linear LDS dest + pre-swizzled global source, involution),
// raw s_barrier + counted vmcnt (never 0 in steady state), T5 setprio,
// T1 bijective XCD swizzle (m204).
// Pipeline per tile t: compute from buf[t&1] -> lgkmcnt(0)+barrier ->
// stage tile t+2 into buf[t&1] -> vmcnt(LOADS) [tile t+1 landed] -> barrier.
// MODE 0: outF = acc + bias  MODE 1: split gate/hBC/dt  MODE 2: outF += acc
// ---------------------------------------------------------------------------
template <int MODE, int BN, int WGM, int WGN>
__global__ __launch_bounds__(512) void gemm256(const bf16* __restrict__ A,
                                               const bf16* __restrict__ Bt,
                                               int K, int N,
                                               const bf16* __restrict__ bias,
                                               float* __restrict__ outF,
                                               bf16* __restrict__ outB,
                                               bf16* __restrict__ outB2,
                                               float* __restrict__ outF2) {
    constexpr int BM = 256, BK = 64;
    constexpr int MT = BM / WGM / 16;
    constexpr int NT = BN / WGN / 16;
    constexpr int ABYTES = BM * BK * 2;          // 32768
    constexpr int BBYTES = BN * BK * 2;          // 32768 or 16384
    constexpr int BUF = ABYTES + BBYTES;
    constexpr int AL = ABYTES / 8192;            // 4 issues of 8KB
    constexpr int BL = BBYTES / 8192;            // 4 or 2
    constexpr int LOADS = AL + BL;               // 8 or 6

    extern __shared__ char lds[];

    const int tid = threadIdx.x;
    const int wv = tid >> 6, lane = tid & 63;
    const int l16 = lane & 15, quad = lane >> 4;
    const int wm = (wv / WGN) * (BM / WGM);
    const int wn = (wv % WGN) * (BN / WGN);

    // T1: bijective XCD swizzle on linear block id (m204)
    const int NX = gridDim.x;
    const int nwg = NX * gridDim.y;
    const int orig = blockIdx.y * NX + blockIdx.x;
    const int q = nwg >> 3, r = nwg & 7, xcd = orig & 7, lid = orig >> 3;
    const int wg = (xcd < r ? xcd * (q + 1) : r * (q + 1) + (xcd - r) * q) + lid;
    const int m0 = (wg / NX) * BM;
    const int n0 = (wg % NX) * BN;

    // staging geometry: thread t covers LDS linear (row = t>>3, 16B-slot = t&7);
    // global source pre-swizzled: fetch block (slot ^ (row&7)) so that a
    // swizzled READ recovers linear K (rule #21: same involution both sides).
    const int srow = tid >> 3, sslot = tid & 7;
    const int swz = (sslot ^ (srow & 7)) << 3;   // element offset
    const bf16* ga = A  + (size_t)(m0 + srow) * K + swz;
    const bf16* gb = Bt + (size_t)(n0 + srow) * K + swz;
    char* la0 = lds + wv * 1024;
    char* lb0 = lds + ABYTES + wv * 1024;

    auto stage = [&](int k0, int b) {
#pragma unroll
        for (int j = 0; j < AL; ++j)
            load_lds16(ga + (size_t)(j * 64) * K + k0, la0 + b * BUF + j * 8192);
#pragma unroll
        for (int j = 0; j < BL; ++j)
            load_lds16(gb + (size_t)(j * 64) * K + k0, lb0 + b * BUF + j * 8192);
    };

    const int KT = K / BK;
    stage(0, 0);
    stage(BK, 1);
    wait_vm<LOADS>();          // oldest LOADS = tile 0 fully in LDS
    barrier_sync();

    fv4 acc[MT][NT] = {};

    for (int t = 0; t < KT; ++t) {
        const char* Ab = lds + (t & 1) * BUF;
        const char* Bb = Ab + ABYTES;
#pragma unroll
        for (int kk = 0; kk < 2; ++kk) {
            bfv8 af[MT], bfr[NT];
#pragma unroll
            for (int i = 0; i < MT; ++i) {
                int rr = wm + i * 16 + l16;
                af[i] = *(const bfv8*)(Ab + rr * 128 +
                        ((((kk << 2) + quad) ^ (rr & 7)) << 4));
            }
#pragma unroll
            for (int i = 0; i < NT; ++i) {
                int rr = wn + i * 16 + l16;
                bfr[i] = *(const bfv8*)(Bb + rr * 128 +
                         ((((kk << 2) + quad) ^ (rr & 7)) << 4));
            }
            __builtin_amdgcn_s_setprio(1);
#pragma unroll
            for (int mt = 0; mt < MT; ++mt)
#pragma unroll
                for (int nt = 0; nt < NT; ++nt)
                    acc[mt][nt] = __builtin_amdgcn_mfma_f32_16x16x32_bf16(
                        af[mt], bfr[nt], acc[mt][nt], 0, 0, 0);
            __builtin_amdgcn_s_setprio(0);
        }
        if (t + 1 < KT) {
            asm volatile("s_waitcnt lgkmcnt(0)" ::: "memory");
            barrier_sync();                       // all waves done reading buf[t&1]
            if (t + 2 < KT) {
                stage((t + 2) * BK, t & 1);
                wait_vm<LOADS>();                 // completes tile t+1 (issued last iter)
            } else {
                wait_vm<0>();                     // epilogue drain
            }
            barrier_sync();                       // tile t+1 visible to all waves
        }
    }

#pragma unroll
    for (int mt = 0; mt < MT; ++mt) {
#pragma unroll
        for (int nt = 0; nt < NT; ++nt) {
#pragma unroll
            for (int i = 0; i < 4; ++i) {
                int row = m0 + wm + mt * 16 + quad * 4 + i;
                int col = n0 + wn + nt * 16 + l16;
                float v = acc[mt][nt][i];
                if (MODE == 0) {
                    v += __bfloat162float(bias[col]);
                    outF[(size_t)row * N + col] = v;
                } else if (MODE == 1) {
                    if (col < I_)
                        outB[(size_t)row * I_ + col] = __float2bfloat16(v);
                    else if (col < I_ + CONV_DIM)
                        outB2[(size_t)row * CONV_DIM + (col - I_)] = __float2bfloat16(v);
                    else if (col < PROJ)
                        outF2[(size_t)row * H_ + (col - (I_ + CONV_DIM))] = v;
                } else if (MODE == 2) {
                    outF[(size_t)row * N + col] += v;
                }
            }
        }
    }
}

// ---------------------------------------------------------------------------
__global__ __launch_bounds__(256) void rmsnorm_k(const float* __restrict__ x,
                                                 const bf16* __restrict__ w,
                                                 bf16* __restrict__ out) {
    int row = blockIdx.x, tid = threadIdx.x;
    float4 v = *(const float4*)&x[(size_t)row * D_ + tid * 4];
    float ss = v.x * v.x + v.y * v.y + v.z * v.z + v.w * v.w;
#pragma unroll
    for (int off = 32; off; off >>= 1) ss += __shfl_down(ss, off);
    __shared__ float sb[4];
    if ((tid & 63) == 0) sb[tid >> 6] = ss;
    __syncthreads();
    ss = sb[0] + sb[1] + sb[2] + sb[3];
    float rs = rsqrtf(ss * (1.f / D_) + 1e-6f);
    float xv[4] = {v.x, v.y, v.z, v.w};
#pragma unroll
    for (int j = 0; j < 4; ++j)
        out[(size_t)row * D_ + tid * 4 + j] =
            __float2bfloat16(xv[j] * rs * __bfloat162float(w[tid * 4 + j]));
}

// ---------------------------------------------------------------------------
__global__ __launch_bounds__(256) void gatednorm_k(const bf16* __restrict__ y,
                                                   const bf16* __restrict__ g,
                                                   const bf16* __restrict__ w,
                                                   bf16* __restrict__ out) {
    int row = blockIdx.x, tid = threadIdx.x;
    size_t base = (size_t)row * I_ + tid * 8;
    bf16 yv[8], gv[8];
    *(uint4*)yv = *(const uint4*)&y[base];
    *(uint4*)gv = *(const uint4*)&g[base];
    float vv[8]; float ss = 0.f;
#pragma unroll
    for (int j = 0; j < 8; ++j) {
        float yf = __bfloat162float(yv[j]);
        float gf = __bfloat162float(gv[j]);
        float sig = 1.f / (1.f + expf(-gf));
        vv[j] = yf * gf * sig;
        ss += vv[j] * vv[j];
    }
#pragma unroll
    for (int off = 32; off; off >>= 1) ss += __shfl_down(ss, off);
    __shared__ float sb[4];
    if ((tid & 63) == 0) sb[tid >> 6] = ss;
    __syncthreads();
    ss = sb[0] + sb[1] + sb[2] + sb[3];
    float rs = rsqrtf(ss * (1.f / I_) + 1e-6f);
    bf16 ov[8];
#pragma unroll
    for (int j = 0; j < 8; ++j)
        ov[j] = __float2bfloat16(vv[j] * rs * __bfloat162float(w[tid * 8 + j]));
    *(uint4*)&out[base] = *(uint4*)ov;
}

// ---------------------------------------------------------------------------
__global__ __launch_bounds__(256) void conv_k(const bf16* __restrict__ hbc,
                                              const bf16* __restrict__ w,
                                              const bf16* __restrict__ bias,
                                              bf16* __restrict__ xs,
                                              float* __restrict__ bc) {
    int cq = blockIdx.x * 256 + threadIdx.x;
    if (cq >= CONV_DIM / 4) return;
    int c = cq * 4;
    int bt = blockIdx.y;
    int t = bt & (T_ - 1);
    float acc[4];
#pragma unroll
    for (int j = 0; j < 4; ++j) acc[j] = __bfloat162float(bias[c + j]);
#pragma unroll
    for (int k = 0; k < 3; ++k) {
        int tt = t - 2 + k;
        if (tt < 0) continue;
        const bf16* src = &hbc[(size_t)(bt - 2 + k) * CONV_DIM + c];
#pragma unroll
        for (int j = 0; j < 4; ++j)
            acc[j] = fmaf(__bfloat162float(w[k * CONV_DIM + c + j]),
                          __bfloat162float(src[j]), acc[j]);
    }
#pragma unroll
    for (int j = 0; j < 4; ++j) {
        float v = acc[j];
        v = v / (1.f + expf(-v));     // silu
        if (c + j < I_) xs[(size_t)bt * I_ + c + j] = __float2bfloat16(v);
        else            bc[(size_t)bt * 128 + (c + j - I_)] = v;
    }
}

// ---------------------------------------------------------------------------
// dt prep, wave-parallel: one wave per (b,h,chunk) chain. dt = softplus;
// gamma = exp(inclusive-prefix-sum(dt*a)) == cumprod(exp(dt*a)).
// ---------------------------------------------------------------------------
__global__ __launch_bounds__(256) void dtprep_k(const float* __restrict__ dtraw,
                                                const float* __restrict__ dtb,
                                                const float* __restrict__ alog,
                                                float* __restrict__ wco,
                                                float* __restrict__ gma) {
    int chain = blockIdx.x * 4 + (threadIdx.x >> 6);   // b*256 + ci*16 + h
    int s = threadIdx.x & 63;
    int h = chain & 15, ci = (chain >> 4) & (NC - 1), b = chain >> 8;
    float a = -expf(alog[h]);
    float bz = dtb[h];
    int idx = (b * T_ + ci * TC + s) * H_ + h;
    float z = dtraw[idx] + bz;
    float dt = fmaxf(z, 0.f) + log1pf(expf(-fabsf(z)));
    float ps = dt * a;
#pragma unroll
    for (int d = 1; d < 64; d <<= 1) {
        float o = __shfl_up(ps, d, 64);
        if (s >= d) ps += o;
    }
    float g = expf(ps);
    wco[idx] = dt / g;
    gma[idx] = g;
}

// ---------------------------------------------------------------------------
// Scan pass A (normalized form): per (b,h,chunk) local scan from zero state.
// ---------------------------------------------------------------------------
__global__ __launch_bounds__(128) void scan_local_k(const bf16* __restrict__ xs,
                                                    const float* __restrict__ bc,
                                                    const float* __restrict__ wco,
                                                    const float* __restrict__ gma,
                                                    const float* __restrict__ dvec,
                                                    bf16* __restrict__ yout,
                                                    bf16* __restrict__ sfin) {
    int bid = blockIdx.x;                   // b*256 + h*16 + ci
    int ci = bid & (NC - 1);
    int h  = (bid >> 4) & (H_ - 1);
    int b  = bid >> 8;
    int p = threadIdx.x;
    float Dv = dvec[h];
    float st[64];
#pragma unroll
    for (int n = 0; n < 64; ++n) st[n] = 0.f;
    int bt0 = b * T_ + ci * TC;
    const bf16* xptr = xs + (size_t)bt0 * I_ + h * P_ + p;
    bf16* yptr = yout + (size_t)bt0 * I_ + h * P_ + p;
    float xv_n = __bfloat162float(xptr[0]);
    for (int s = 0; s < TC; ++s) {
        float xv = xv_n;
        if (s + 1 < TC) xv_n = __bfloat162float(xptr[(size_t)(s + 1) * I_]);
        float w = wco[(bt0 + s) * H_ + h];          // uniform
        float g = gma[(bt0 + s) * H_ + h];
        float cc = w * xv;
        const float4* B4 = (const float4*)&bc[(size_t)(bt0 + s) * 128];
#pragma unroll
        for (int j = 0; j < 16; ++j) {
            float4 bv = B4[j];
            st[4 * j + 0] = fmaf(cc, bv.x, st[4 * j + 0]);
            st[4 * j + 1] = fmaf(cc, bv.y, st[4 * j + 1]);
            st[4 * j + 2] = fmaf(cc, bv.z, st[4 * j + 2]);
            st[4 * j + 3] = fmaf(cc, bv.w, st[4 * j + 3]);
        }
        float y0 = 0.f, y1 = 0.f, y2 = 0.f, y3 = 0.f;
#pragma unroll
        for (int j = 0; j < 16; ++j) {
            float4 cv = B4[16 + j];
            y0 = fmaf(st[4 * j + 0], cv.x, y0);
            y1 = fmaf(st[4 * j + 1], cv.y, y1);
            y2 = fmaf(st[4 * j + 2], cv.z, y2);
            y3 = fmaf(st[4 * j + 3], cv.w, y3);
        }
        yptr[(size_t)s * I_] = __float2bfloat16(fmaf(g, (y0 + y1) + (y2 + y3), Dv * xv));
    }
    float G = gma[(bt0 + TC - 1) * H_ + h];
    bf16* sf = sfin + (size_t)bid * (128 * 64);
#pragma unroll
    for (int n = 0; n < 64; ++n) sf[n * 128 + p] = __float2bfloat16(st[n] * G);
}

// ---------------------------------------------------------------------------
// Pass B: chunk combine, PARALLEL over (b,h,n,p) — sequential only in ci.
// ---------------------------------------------------------------------------
__global__ __launch_bounds__(128) void scan_combine_k(bf16* __restrict__ sbuf,
                                                      const float* __restrict__ gma) {
    int bid = blockIdx.x;                   // b*H*64 + h*64 + n
    int n = bid & 63;
    int h = (bid >> 6) & (H_ - 1);
    int b = bid >> 10;
    int p = threadIdx.x;
    size_t base0 = ((size_t)(b * (H_ * NC) + h * NC) * (128 * 64)) + n * 128 + p;
    int gbase = b * T_ * H_ + h;
    float S = 0.f;
#pragma unroll
    for (int ci = 0; ci < NC; ++ci) {
        bf16* addr = sbuf + base0 + (size_t)ci * (128 * 64);
        float tmp = __bfloat162float(*addr);            // S_fin of chunk ci
        *addr = __float2bfloat16(S);                    // S_init of chunk ci
        float G = gma[gbase + (ci * TC + TC - 1) * H_]; // uniform per block
        S = fmaf(G, S, tmp);
    }
}

// ---------------------------------------------------------------------------
// Pass C: y += gamma_t * (C_t . S_init)
// ---------------------------------------------------------------------------
__global__ __launch_bounds__(128) void scan_correct_k(const bf16* __restrict__ sinit,
                                                      const float* __restrict__ gma,
                                                      const float* __restrict__ bc,
                                                      bf16* __restrict__ yout) {
    int bid = blockIdx.x;
    int ci = bid & (NC - 1);
    if (ci == 0) return;
    int h = (bid >> 4) & (H_ - 1);
    int b = bid >> 8;
    int p = threadIdx.x;
    const bf16* sb = sinit + (size_t)bid * (128 * 64);
    float S[64];
#pragma unroll
    for (int n = 0; n < 64; ++n) S[n] = __bfloat162float(sb[n * 128 + p]);
    int bt0 = b * T_ + ci * TC;
    bf16* yptr = yout + (size_t)bt0 * I_ + h * P_ + p;
    for (int s = 0; s < TC; ++s) {
        float g = gma[(bt0 + s) * H_ + h];
        const float4* C4 = (const float4*)&bc[(size_t)(bt0 + s) * 128 + 64];
        float y0 = 0.f, y1 = 0.f, y2 = 0.f, y3 = 0.f;
#pragma unroll
        for (int j = 0; j < 16; ++j) {
            float4 cv = C4[j];
            y0 = fmaf(S[4 * j + 0], cv.x, y0);
            y1 = fmaf(S[4 * j + 1], cv.y, y1);
            y2 = fmaf(S[4 * j + 2], cv.z, y2);
            y3 = fmaf(S[4 * j + 3], cv.w, y3);
        }
        float y = __bfloat162float(yptr[(size_t)s * I_]);
        yptr[(size_t)s * I_] = __float2bfloat16(fmaf(g, (y0 + y1) + (y2 + y3), y));
    }
}

// ---------------------------------------------------------------------------
__global__ __launch_bounds__(256) void cast_f2b_k(const float* __restrict__ in,
                                                  bf16* __restrict__ out) {
    int i = (blockIdx.x * 256 + threadIdx.x) * 4;
    float4 v = *(const float4*)&in[i];
    bf16 ov[4] = {__float2bfloat16(v.x), __float2bfloat16(v.y),
                  __float2bfloat16(v.z), __float2bfloat16(v.w)};
    *(uint2*)&out[i] = *(uint2*)ov;
}

// ---------------------------------------------------------------------------

static inline size_t align256(size_t x) { return (x + 255) & ~(size_t)255; }

extern "C" void kernel_launch(void* const* d_in, const int* in_sizes, int n_in,
                              void* d_out, int out_size, void* d_ws, size_t ws_size,
                              hipStream_t stream) {
    const float* x_in     = (const float*)d_in[0];
    const float* in_w     = (const float*)d_in[1];
    const float* in_b     = (const float*)d_in[2];
    const float* norm_w   = (const float*)d_in[3];
    const float* mix_in_w = (const float*)d_in[4];
    const float* conv_w   = (const float*)d_in[5];
    const float* conv_b   = (const float*)d_in[6];
    const float* dt_bias  = (const float*)d_in[7];
    const float* A_log    = (const float*)d_in[8];
    const float* Dvec     = (const float*)d_in[9];
    const float* gnorm_w  = (const float*)d_in[10];
    const float* mix_out_w= (const float*)d_in[11];
    const float* out_w    = (const float*)d_in[12];
    const float* out_b    = (const float*)d_in[13];
    const float* code_w   = (const float*)d_in[14];
    const float* code_b   = (const float*)d_in[15];
    float* outF0 = (float*)d_out;                       // [8192][512]
    float* outF1 = (float*)d_out + (size_t)M_ * OUT_;   // [8192][1024]

    char* p = (char*)d_ws;
    auto alloc = [&](size_t bytes) -> char* { char* r = p; p += align256(bytes); return r; };

    bf16*  xb       = (bf16*)alloc((size_t)M_ * INP * 2);
    bf16*  v_inb    = (bf16*)alloc(D_ * 2);
    bf16*  v_normw  = (bf16*)alloc(L_ * D_ * 2);
    bf16*  v_convw  = (bf16*)alloc(L_ * 3 * CONV_DIM * 2);
    bf16*  v_convb  = (bf16*)alloc(L_ * CONV_DIM * 2);
    bf16*  v_gnw    = (bf16*)alloc(L_ * I_ * 2);
    bf16*  v_outb   = (bf16*)alloc(OUT_ * 2);
    bf16*  v_codeb  = (bf16*)alloc(CB_ * 2);
    bf16*  wt_in    = (bf16*)alloc((size_t)1024 * 512 * 2);
    bf16*  wt_big   = (bf16*)alloc((size_t)4352 * 1024 * 2);   // per-layer reuse
    bf16*  wt_small = (bf16*)alloc((size_t)1024 * 2048 * 2);   // per-layer reuse
    bf16*  wt_out   = (bf16*)alloc((size_t)512 * 1024 * 2);
    bf16*  wt_code  = (bf16*)alloc((size_t)1024 * 1024 * 2);
    float* hbuf     = (float*)alloc((size_t)M_ * D_ * 4);      // residual fp32
    bf16*  hn       = (bf16*)alloc((size_t)M_ * D_ * 2);
    bf16*  gate     = (bf16*)alloc((size_t)M_ * I_ * 2);
    bf16*  hbc      = (bf16*)alloc((size_t)M_ * CONV_DIM * 2); // conv in; reused as yscan
    float* dtraw    = (float*)alloc((size_t)M_ * H_ * 4);
    bf16*  xs       = (bf16*)alloc((size_t)M_ * I_ * 2);
    float* bcbuf    = (float*)alloc((size_t)M_ * 128 * 4);     // B | C
    float* wcob     = (float*)alloc((size_t)M_ * H_ * 4);
    float* gmab     = (float*)alloc((size_t)M_ * H_ * 4);
    bf16*  sfin     = (bf16*)alloc((size_t)B_ * H_ * NC * 128 * 64 * 2); // 33.5 MiB
    (void)in_sizes; (void)n_in; (void)out_size;

    size_t needed = (size_t)(p - (char*)d_ws);
    if (needed > ws_size) return;   // diagnostic: absmax reads max|ref| (zeros)

    constexpr size_t SH256 = 131072;   // 2 bufs x (256+256)x64 bf16
    constexpr size_t SH128 = 98304;    // 2 bufs x (256+128)x64 bf16
    static bool attr_done = false;
    if (!attr_done) {
        attr_done = true;
        (void)hipFuncSetAttribute((const void*)gemm256<0, 128, 4, 2>,
                                  hipFuncAttributeMaxDynamicSharedMemorySize, (int)SH256);
        (void)hipFuncSetAttribute((const void*)gemm256<1, 256, 2, 4>,
                                  hipFuncAttributeMaxDynamicSharedMemorySize, (int)SH256);
        (void)hipFuncSetAttribute((const void*)gemm256<2, 128, 4, 2>,
                                  hipFuncAttributeMaxDynamicSharedMemorySize, (int)SH256);
    }

    auto ing = [&](const float* src, bf16* dst, int n) {
        ingest_k<<<(n + 255) / 256, 256, 0, stream>>>(src, dst, n);
    };
    ing(x_in, xb, M_ * INP);
    ing(in_b, v_inb, D_);
    ing(norm_w, v_normw, L_ * D_);
    ing(conv_w, v_convw, L_ * 3 * CONV_DIM);
    ing(conv_b, v_convb, L_ * CONV_DIM);
    ing(gnorm_w, v_gnw, L_ * I_);
    ing(out_b, v_outb, OUT_);
    ing(code_b, v_codeb, CB_);

    dim3 tb(32, 8);
    transpose_any<<<dim3(32, 16), tb, 0, stream>>>(in_w, 0, wt_in, 512, 1024);
    transpose_any<<<dim3(16, 32), tb, 0, stream>>>(out_w, 0, wt_out, 1024, 512);
    transpose_any<<<dim3(32, 32), tb, 0, stream>>>(code_w, 0, wt_code, 1024, 1024);

    // h = x @ in_w + in_b     (M=8192, K=512, N=1024)
    gemm256<0, 128, 4, 2><<<dim3(8, 32), 512, SH128, stream>>>(
        xb, wt_in, INP, D_, v_inb, hbuf, nullptr, nullptr, nullptr);

    for (int i = 0; i < L_; ++i) {
        transpose_any<<<dim3(136, 32), tb, 0, stream>>>(mix_in_w, (size_t)i * 1024 * PROJ,
                                                        wt_big, 1024, PROJ);
        transpose_any<<<dim3(32, 64), tb, 0, stream>>>(mix_out_w, (size_t)i * 2048 * 1024,
                                                       wt_small, 2048, 1024);
        rmsnorm_k<<<M_, 256, 0, stream>>>(hbuf, v_normw + i * D_, hn);
        // proj: M=8192, K=1024, N=4352(pad)
        gemm256<1, 256, 2, 4><<<dim3(17, 32), 512, SH256, stream>>>(
            hn, wt_big, D_, 4352, nullptr, nullptr, gate, hbc, dtraw);
        conv_k<<<dim3(3, M_), 256, 0, stream>>>(hbc, v_convw + i * 3 * CONV_DIM,
                                                v_convb + i * CONV_DIM, xs, bcbuf);
        dtprep_k<<<B_ * NC * H_ / 4, 256, 0, stream>>>(
            dtraw, dt_bias + i * H_, A_log + i * H_, wcob, gmab);
        scan_local_k<<<B_ * H_ * NC, 128, 0, stream>>>(xs, bcbuf, wcob, gmab,
                                                       Dvec + i * H_, hbc, sfin);
        scan_combine_k<<<B_ * H_ * 64, 128, 0, stream>>>(sfin, gmab);
        scan_correct_k<<<B_ * H_ * NC, 128, 0, stream>>>(sfin, gmab, bcbuf, hbc);
        gatednorm_k<<<M_, 256, 0, stream>>>(hbc, gate, v_gnw + i * I_, xs);
        // out proj: M=8192, K=2048, N=1024, accumulate into residual
        gemm256<2, 128, 4, 2><<<dim3(8, 32), 512, SH128, stream>>>(
            xs, wt_small, I_, D_, nullptr, hbuf, nullptr, nullptr, nullptr);
    }

    // heads -> fp32 d_out
    cast_f2b_k<<<(M_ * D_) / 1024, 256, 0, stream>>>(hbuf, hn);
    gemm256<0, 128, 4, 2><<<dim3(4, 32), 512, SH128, stream>>>(
        hn, wt_out, D_, OUT_, v_outb, outF0, nullptr, nullptr, nullptr);
    gemm256<0, 128, 4, 2><<<dim3(8, 32), 512, SH128, stream>>>(
        hn, wt_code, D_, CB_, v_codeb, outF1, nullptr, nullptr, nullptr);
}

// Round 2
// 1931.726 us; speedup vs baseline: 1.1477x; 1.0129x over previous
//
#include <hip/hip_runtime.h>
#include <hip/hip_bf16.h>

typedef __hip_bfloat16 bf16;
typedef __bf16 bfv8 __attribute__((ext_vector_type(8)));
typedef float fv4 __attribute__((ext_vector_type(4)));

#define B_  8
#define T_  1024
#define INP 512
#define D_  1024
#define I_  2048
#define N_  64
#define H_  16
#define P_  128
#define L_  4
#define OUT_ 512
#define CB_ 1024
#define CONV_DIM 2176
#define PROJ 4240
#define M_  (B_*T_)       // 8192 rows
#define TC  64            // scan chunk length
#define NC  (T_/TC)       // 16 chunks

typedef const __attribute__((address_space(1))) void gv_t;
typedef __attribute__((address_space(3))) void lv_t;

__device__ __forceinline__ void load_lds16(const bf16* g, char* l) {
    __builtin_amdgcn_global_load_lds((gv_t*)g, (lv_t*)l, 16, 0, 0);
}

template <int N> __device__ __forceinline__ void wait_vm() {
    if constexpr (N == 0) asm volatile("s_waitcnt vmcnt(0)" ::: "memory");
    else if constexpr (N == 3) asm volatile("s_waitcnt vmcnt(3)" ::: "memory");
    else if constexpr (N == 4) asm volatile("s_waitcnt vmcnt(4)" ::: "memory");
    else asm volatile("s_waitcnt vmcnt(8)" ::: "memory");
}
__device__ __forceinline__ void barrier_sync() {
    asm volatile("s_barrier" ::: "memory");
}

// ---------------------------------------------------------------------------
// fp32 -> bf16 copy
// ---------------------------------------------------------------------------
__global__ __launch_bounds__(256) void ingest_k(const float* __restrict__ src,
                                                bf16* __restrict__ dst, int n) {
    int i = blockIdx.x * 256 + threadIdx.x;
    if (i >= n) return;
    dst[i] = __float2bfloat16(src[i]);
}

// ---------------------------------------------------------------------------
// Transpose fp32 [R][C] -> bf16 [Cp][R], zero-padding rows C..Cp.
// ---------------------------------------------------------------------------
__global__ __launch_bounds__(256) void transpose_any(const float* __restrict__ in,
                                                     size_t off,
                                                     bf16* __restrict__ out,
                                                     int R, int C) {
    __shared__ bf16 tile[32][33];
    int c0 = blockIdx.x * 32, r0 = blockIdx.y * 32;
    int tx = threadIdx.x, ty = threadIdx.y;
#pragma unroll
    for (int i = 0; i < 4; ++i) {
        int r = r0 + ty + i * 8, c = c0 + tx;
        bf16 v = __float2bfloat16(0.f);
        if (c < C) v = __float2bfloat16(in[off + (size_t)r * C + c]);
        tile[ty + i * 8][tx] = v;
    }
    __syncthreads();
#pragma unroll
    for (int i = 0; i < 4; ++i) {
        int c = c0 + ty + i * 8;
        out[(size_t)c * R + r0 + tx] = tile[tx][ty + i * 8];
    }
}

// ---------------------------------------------------------------------------
// GEMM, 8-phase style (m201 port): C[M,N] = A[M,K] @ Bt[N,K]^T.
// BM=256, half-tile K=32, RING LDS buffers, 512 thr = 8 waves (WGM x WGN).
// Per phase: {ds_read frags | issue stage loads for ht+RING-1} -> setprio+MFMA
// -> counted vmcnt (never 0 mid-loop) -> s_barrier. Cross-wave vmcnt safety:
// own-wait THEN barrier => collective completion.
// Swizzle: row stride 64B, 4 slots of 16B, slot ^= (row>>1)&3 (2-way = free).
// MODE 0: outF = acc + bias  MODE 1: split gate/hBC/dt  MODE 2: outF += acc
// ---------------------------------------------------------------------------
template <int MODE, int BN, int WGM, int WGN, int RING>
__global__ __launch_bounds__(512) void gemm8p(const bf16* __restrict__ A,
                                              const bf16* __restrict__ Bt,
                                              int K, int N,
                                              const bf16* __restrict__ bias,
                                              float* __restrict__ outF,
                                              bf16* __restrict__ outB,
                                              bf16* __restrict__ outB2,
                                              float* __restrict__ outF2) {
    constexpr int BM = 256, HK = 32;
    constexpr int MT = BM / WGM / 16;            // 8 (BN=256) or 4
    constexpr int NT = BN / WGN / 16;            // 4
    constexpr int SUB = (BN == 256) ? 2 : 1;
    constexpr int MTS = MT / SUB;                // 4
    constexpr int ABY = BM * HK * 2;             // 16384
    constexpr int BBY = BN * HK * 2;             // 16384 or 8192
    constexpr int BUF = ABY + BBY;
    constexpr int AL = ABY / 8192;               // 2
    constexpr int BL = BBY / 8192;               // 2 or 1
    constexpr int LD = AL + BL;                  // 4 or 3

    extern __shared__ char lds[];
    const int tid = threadIdx.x;
    const int wv = tid >> 6, lane = tid & 63;
    const int l16 = lane & 15, quad = lane >> 4;
    const int wm = (wv / WGN) * (BM / WGM);
    const int wn = (wv % WGN) * (BN / WGN);

    // T1: bijective XCD swizzle (m204)
    const int NX = gridDim.x;
    const int nwg = NX * gridDim.y;
    const int orig = blockIdx.y * NX + blockIdx.x;
    const int q = nwg >> 3, r = nwg & 7, xcd = orig & 7, lid = orig >> 3;
    const int wg = (xcd < r ? xcd * (q + 1) : r * (q + 1) + (xcd - r) * q) + lid;
    const int m0 = (wg / NX) * BM;
    const int n0 = (wg % NX) * BN;

    // staging: thread covers LDS linear (row=tid>>2, 16B slot=tid&3);
    // global source pre-swizzled with the same involution used on reads.
    const int srow = tid >> 2, sslot = tid & 3;
    const int swz = (sslot ^ ((srow >> 1) & 3)) << 3;   // element offset
    const bf16* ga = A  + (size_t)(m0 + srow) * K + swz;
    const bf16* gb = Bt + (size_t)(n0 + srow) * K + swz;
    char* lw = lds + wv * 1024;   // wave-uniform stage base (lane*16 implicit)

    const int HT = K / HK;

    auto stageA = [&](int stg, int rbuf) {
#pragma unroll
        for (int j = 0; j < AL; ++j)
            load_lds16(ga + (size_t)stg * HK + (size_t)(j * 128) * K,
                       lw + rbuf * BUF + j * 8192);
    };
    auto stageB = [&](int stg, int rbuf) {
#pragma unroll
        for (int j = 0; j < BL; ++j)
            load_lds16(gb + (size_t)stg * HK + (size_t)(j * 128) * K,
                       lw + rbuf * BUF + ABY + j * 8192);
    };

    // prologue: fill RING-1 buffers, wait own ht0 loads, barrier -> all done
#pragma unroll
    for (int h = 0; h < RING - 1; ++h) { stageA(h, h); stageB(h, h); }
    if constexpr (RING == 4) wait_vm<8>(); else wait_vm<3>();
    barrier_sync();

    fv4 acc[MT][NT] = {};
    int rb = 0;
    for (int ht = 0; ht < HT; ++ht) {
        const char* Ab = lds + rb * BUF;
        const char* Bb = Ab + ABY;
        const int stg = ht + RING - 1;
        const int sb = (rb == 0) ? RING - 1 : rb - 1;   // (ht+RING-1)%RING
        const bool dostage = stg < HT;

        // ---- sub-phase 0: B frags + first half of A frags ----
        bfv8 bf[NT], af[MTS];
#pragma unroll
        for (int i = 0; i < NT; ++i) {
            int rr = wn + i * 16 + l16;
            bf[i] = *(const bfv8*)(Bb + rr * 64 + ((quad ^ ((rr >> 1) & 3)) << 4));
        }
#pragma unroll
        for (int i = 0; i < MTS; ++i) {
            int rr = wm + i * 16 + l16;
            af[i] = *(const bfv8*)(Ab + rr * 64 + ((quad ^ ((rr >> 1) & 3)) << 4));
        }
        if (dostage) stageA(stg, sb);
        if constexpr (SUB == 1) { if (dostage) stageB(stg, sb); }
        __builtin_amdgcn_s_setprio(1);
#pragma unroll
        for (int mt = 0; mt < MTS; ++mt)
#pragma unroll
            for (int nt = 0; nt < NT; ++nt)
                acc[mt][nt] = __builtin_amdgcn_mfma_f32_16x16x32_bf16(
                    af[mt], bf[nt], acc[mt][nt], 0, 0, 0);
        __builtin_amdgcn_s_setprio(0);

        if constexpr (SUB == 2) {
            barrier_sync();
            // ---- sub-phase 1: second half of A frags, reuse bf ----
            bfv8 af2[MTS];
#pragma unroll
            for (int i = 0; i < MTS; ++i) {
                int rr = wm + (MTS + i) * 16 + l16;
                af2[i] = *(const bfv8*)(Ab + rr * 64 + ((quad ^ ((rr >> 1) & 3)) << 4));
            }
            if (dostage) stageB(stg, sb);
            __builtin_amdgcn_s_setprio(1);
#pragma unroll
            for (int mt = 0; mt < MTS; ++mt)
#pragma unroll
                for (int nt = 0; nt < NT; ++nt)
                    acc[MTS + mt][nt] = __builtin_amdgcn_mfma_f32_16x16x32_bf16(
                        af2[mt], bf[nt], acc[MTS + mt][nt], 0, 0, 0);
            __builtin_amdgcn_s_setprio(0);
        }

        // tail-aware counted wait: ensure ht+1's buffer landed (own loads),
        // then barrier => collective completion for all waves.
        int fut = HT - 1 - ht; if (fut > RING - 1) fut = RING - 1;
        if (fut >= 1) {
            int w = (fut - 1) * LD;
            if (w >= 8) wait_vm<8>();
            else if (w == 4) wait_vm<4>();
            else if (w == 3) wait_vm<3>();
            else wait_vm<0>();
        }
        barrier_sync();
        rb = (rb + 1 == RING) ? 0 : rb + 1;
    }

#pragma unroll
    for (int mt = 0; mt < MT; ++mt) {
#pragma unroll
        for (int nt = 0; nt < NT; ++nt) {
#pragma unroll
            for (int i = 0; i < 4; ++i) {
                int row = m0 + wm + mt * 16 + quad * 4 + i;
                int col = n0 + wn + nt * 16 + l16;
                float v = acc[mt][nt][i];
                if (MODE == 0) {
                    v += __bfloat162float(bias[col]);
                    outF[(size_t)row * N + col] = v;
                } else if (MODE == 1) {
                    if (col < I_)
                        outB[(size_t)row * I_ + col] = __float2bfloat16(v);
                    else if (col < I_ + CONV_DIM)
                        outB2[(size_t)row * CONV_DIM + (col - I_)] = __float2bfloat16(v);
                    else if (col < PROJ)
                        outF2[(size_t)row * H_ + (col - (I_ + CONV_DIM))] = v;
                } else if (MODE == 2) {
                    outF[(size_t)row * N + col] += v;
                }
            }
        }
    }
}

// ---------------------------------------------------------------------------
__global__ __launch_bounds__(256) void rmsnorm_k(const float* __restrict__ x,
                                                 const bf16* __restrict__ w,
                                                 bf16* __restrict__ out) {
    int row = blockIdx.x, tid = threadIdx.x;
    float4 v = *(const float4*)&x[(size_t)row * D_ + tid * 4];
    float ss = v.x * v.x + v.y * v.y + v.z * v.z + v.w * v.w;
#pragma unroll
    for (int off = 32; off; off >>= 1) ss += __shfl_down(ss, off);
    __shared__ float sb[4];
    if ((tid & 63) == 0) sb[tid >> 6] = ss;
    __syncthreads();
    ss = sb[0] + sb[1] + sb[2] + sb[3];
    float rs = rsqrtf(ss * (1.f / D_) + 1e-6f);
    float xv[4] = {v.x, v.y, v.z, v.w};
#pragma unroll
    for (int j = 0; j < 4; ++j)
        out[(size_t)row * D_ + tid * 4 + j] =
            __float2bfloat16(xv[j] * rs * __bfloat162float(w[tid * 4 + j]));
}

// ---------------------------------------------------------------------------
__global__ __launch_bounds__(256) void gatednorm_k(const bf16* __restrict__ y,
                                                   const bf16* __restrict__ g,
                                                   const bf16* __restrict__ w,
                                                   bf16* __restrict__ out) {
    int row = blockIdx.x, tid = threadIdx.x;
    size_t base = (size_t)row * I_ + tid * 8;
    bf16 yv[8], gv[8];
    *(uint4*)yv = *(const uint4*)&y[base];
    *(uint4*)gv = *(const uint4*)&g[base];
    float vv[8]; float ss = 0.f;
#pragma unroll
    for (int j = 0; j < 8; ++j) {
        float yf = __bfloat162float(yv[j]);
        float gf = __bfloat162float(gv[j]);
        float sig = 1.f / (1.f + expf(-gf));
        vv[j] = yf * gf * sig;
        ss += vv[j] * vv[j];
    }
#pragma unroll
    for (int off = 32; off; off >>= 1) ss += __shfl_down(ss, off);
    __shared__ float sb[4];
    if ((tid & 63) == 0) sb[tid >> 6] = ss;
    __syncthreads();
    ss = sb[0] + sb[1] + sb[2] + sb[3];
    float rs = rsqrtf(ss * (1.f / I_) + 1e-6f);
    bf16 ov[8];
#pragma unroll
    for (int j = 0; j < 8; ++j)
        ov[j] = __float2bfloat16(vv[j] * rs * __bfloat162float(w[tid * 8 + j]));
    *(uint4*)&out[base] = *(uint4*)ov;
}

// ---------------------------------------------------------------------------
__global__ __launch_bounds__(256) void conv_k(const bf16* __restrict__ hbc,
                                              const bf16* __restrict__ w,
                                              const bf16* __restrict__ bias,
                                              bf16* __restrict__ xs,
                                              float* __restrict__ bc) {
    int cq = blockIdx.x * 256 + threadIdx.x;
    if (cq >= CONV_DIM / 4) return;
    int c = cq * 4;
    int bt = blockIdx.y;
    int t = bt & (T_ - 1);
    float acc[4];
#pragma unroll
    for (int j = 0; j < 4; ++j) acc[j] = __bfloat162float(bias[c + j]);
#pragma unroll
    for (int k = 0; k < 3; ++k) {
        int tt = t - 2 + k;
        if (tt < 0) continue;
        const bf16* src = &hbc[(size_t)(bt - 2 + k) * CONV_DIM + c];
#pragma unroll
        for (int j = 0; j < 4; ++j)
            acc[j] = fmaf(__bfloat162float(w[k * CONV_DIM + c + j]),
                          __bfloat162float(src[j]), acc[j]);
    }
#pragma unroll
    for (int j = 0; j < 4; ++j) {
        float v = acc[j];
        v = v / (1.f + expf(-v));     // silu
        if (c + j < I_) xs[(size_t)bt * I_ + c + j] = __float2bfloat16(v);
        else            bc[(size_t)bt * 128 + (c + j - I_)] = v;
    }
}

// ---------------------------------------------------------------------------
// dt prep, wave-parallel: one wave per (b,h,chunk) chain. dt = softplus;
// gamma = exp(inclusive-prefix-sum(dt*a)) == cumprod(exp(dt*a)).
// ---------------------------------------------------------------------------
__global__ __launch_bounds__(256) void dtprep_k(const float* __restrict__ dtraw,
                                                const float* __restrict__ dtb,
                                                const float* __restrict__ alog,
                                                float* __restrict__ wco,
                                                float* __restrict__ gma) {
    int chain = blockIdx.x * 4 + (threadIdx.x >> 6);   // b*256 + ci*16 + h
    int s = threadIdx.x & 63;
    int h = chain & 15, ci = (chain >> 4) & (NC - 1), b = chain >> 8;
    float a = -expf(alog[h]);
    float bz = dtb[h];
    int idx = (b * T_ + ci * TC + s) * H_ + h;
    float z = dtraw[idx] + bz;
    float dt = fmaxf(z, 0.f) + log1pf(expf(-fabsf(z)));
    float ps = dt * a;
#pragma unroll
    for (int d = 1; d < 64; d <<= 1) {
        float o = __shfl_up(ps, d, 64);
        if (s >= d) ps += o;
    }
    float g = expf(ps);
    wco[idx] = dt / g;
    gma[idx] = g;
}

// ---------------------------------------------------------------------------
// Scan pass A (normalized form): per (b,h,chunk) local scan from zero state.
// ---------------------------------------------------------------------------
__global__ __launch_bounds__(128) void scan_local_k(const bf16* __restrict__ xs,
                                                    const float* __restrict__ bc,
                                                    const float* __restrict__ wco,
                                                    const float* __restrict__ gma,
                                                    const float* __restrict__ dvec,
                                                    bf16* __restrict__ yout,
                                                    bf16* __restrict__ sfin) {
    int bid = blockIdx.x;                   // b*256 + h*16 + ci
    int ci = bid & (NC - 1);
    int h  = (bid >> 4) & (H_ - 1);
    int b  = bid >> 8;
    int p = threadIdx.x;
    float Dv = dvec[h];
    float st[64];
#pragma unroll
    for (int n = 0; n < 64; ++n) st[n] = 0.f;
    int bt0 = b * T_ + ci * TC;
    const bf16* xptr = xs + (size_t)bt0 * I_ + h * P_ + p;
    bf16* yptr = yout + (size_t)bt0 * I_ + h * P_ + p;
    float xv_n = __bfloat162float(xptr[0]);
    for (int s = 0; s < TC; ++s) {
        float xv = xv_n;
        if (s + 1 < TC) xv_n = __bfloat162float(xptr[(size_t)(s + 1) * I_]);
        float w = wco[(bt0 + s) * H_ + h];          // uniform
        float g = gma[(bt0 + s) * H_ + h];
        float cc = w * xv;
        const float4* B4 = (const float4*)&bc[(size_t)(bt0 + s) * 128];
#pragma unroll
        for (int j = 0; j < 16; ++j) {
            float4 bv = B4[j];
            st[4 * j + 0] = fmaf(cc, bv.x, st[4 * j + 0]);
            st[4 * j + 1] = fmaf(cc, bv.y, st[4 * j + 1]);
            st[4 * j + 2] = fmaf(cc, bv.z, st[4 * j + 2]);
            st[4 * j + 3] = fmaf(cc, bv.w, st[4 * j + 3]);
        }
        float y0 = 0.f, y1 = 0.f, y2 = 0.f, y3 = 0.f;
#pragma unroll
        for (int j = 0; j < 16; ++j) {
            float4 cv = B4[16 + j];
            y0 = fmaf(st[4 * j + 0], cv.x, y0);
            y1 = fmaf(st[4 * j + 1], cv.y, y1);
            y2 = fmaf(st[4 * j + 2], cv.z, y2);
            y3 = fmaf(st[4 * j + 3], cv.w, y3);
        }
        yptr[(size_t)s * I_] = __float2bfloat16(fmaf(g, (y0 + y1) + (y2 + y3), Dv * xv));
    }
    float G = gma[(bt0 + TC - 1) * H_ + h];
    bf16* sf = sfin + (size_t)bid * (128 * 64);
#pragma unroll
    for (int n = 0; n < 64; ++n) sf[n * 128 + p] = __float2bfloat16(st[n] * G);
}

// ---------------------------------------------------------------------------
// Pass B: chunk combine, PARALLEL over (b,h,n,p) — sequential only in ci.
// ---------------------------------------------------------------------------
__global__ __launch_bounds__(128) void scan_combine_k(bf16* __restrict__ sbuf,
                                                      const float* __restrict__ gma) {
    int bid = blockIdx.x;                   // b*H*64 + h*64 + n
    int n = bid & 63;
    int h = (bid >> 6) & (H_ - 1);
    int b = bid >> 10;
    int p = threadIdx.x;
    size_t base0 = ((size_t)(b * (H_ * NC) + h * NC) * (128 * 64)) + n * 128 + p;
    int gbase = b * T_ * H_ + h;
    float S = 0.f;
#pragma unroll
    for (int ci = 0; ci < NC; ++ci) {
        bf16* addr = sbuf + base0 + (size_t)ci * (128 * 64);
        float tmp = __bfloat162float(*addr);            // S_fin of chunk ci
        *addr = __float2bfloat16(S);                    // S_init of chunk ci
        float G = gma[gbase + (ci * TC + TC - 1) * H_]; // uniform per block
        S = fmaf(G, S, tmp);
    }
}

// ---------------------------------------------------------------------------
// Pass C: y += gamma_t * (C_t . S_init)
// ---------------------------------------------------------------------------
__global__ __launch_bounds__(128) void scan_correct_k(const bf16* __restrict__ sinit,
                                                      const float* __restrict__ gma,
                                                      const float* __restrict__ bc,
                                                      bf16* __restrict__ yout) {
    int bid = blockIdx.x;
    int ci = bid & (NC - 1);
    if (ci == 0) return;
    int h = (bid >> 4) & (H_ - 1);
    int b = bid >> 8;
    int p = threadIdx.x;
    const bf16* sb = sinit + (size_t)bid * (128 * 64);
    float S[64];
#pragma unroll
    for (int n = 0; n < 64; ++n) S[n] = __bfloat162float(sb[n * 128 + p]);
    int bt0 = b * T_ + ci * TC;
    bf16* yptr = yout + (size_t)bt0 * I_ + h * P_ + p;
    for (int s = 0; s < TC; ++s) {
        float g = gma[(bt0 + s) * H_ + h];
        const float4* C4 = (const float4*)&bc[(size_t)(bt0 + s) * 128 + 64];
        float y0 = 0.f, y1 = 0.f, y2 = 0.f, y3 = 0.f;
#pragma unroll
        for (int j = 0; j < 16; ++j) {
            float4 cv = C4[j];
            y0 = fmaf(S[4 * j + 0], cv.x, y0);
            y1 = fmaf(S[4 * j + 1], cv.y, y1);
            y2 = fmaf(S[4 * j + 2], cv.z, y2);
            y3 = fmaf(S[4 * j + 3], cv.w, y3);
        }
        float y = __bfloat162float(yptr[(size_t)s * I_]);
        yptr[(size_t)s * I_] = __float2bfloat16(fmaf(g, (y0 + y1) + (y2 + y3), y));
    }
}

// ---------------------------------------------------------------------------
__global__ __launch_bounds__(256) void cast_f2b_k(const float* __restrict__ in,
                                                  bf16* __restrict__ out) {
    int i = (blockIdx.x * 256 + threadIdx.x) * 4;
    float4 v = *(const float4*)&in[i];
    bf16 ov[4] = {__float2bfloat16(v.x), __float2bfloat16(v.y),
                  __float2bfloat16(v.z), __float2bfloat16(v.w)};
    *(uint2*)&out[i] = *(uint2*)ov;
}

// ---------------------------------------------------------------------------

static inline size_t align256(size_t x) { return (x + 255) & ~(size_t)255; }

extern "C" void kernel_launch(void* const* d_in, const int* in_sizes, int n_in,
                              void* d_out, int out_size, void* d_ws, size_t ws_size,
                              hipStream_t stream) {
    const float* x_in     = (const float*)d_in[0];
    const float* in_w     = (const float*)d_in[1];
    const float* in_b     = (const float*)d_in[2];
    const float* norm_w   = (const float*)d_in[3];
    const float* mix_in_w = (const float*)d_in[4];
    const float* conv_w   = (const float*)d_in[5];
    const float* conv_b   = (const float*)d_in[6];
    const float* dt_bias  = (const float*)d_in[7];
    const float* A_log    = (const float*)d_in[8];
    const float* Dvec     = (const float*)d_in[9];
    const float* gnorm_w  = (const float*)d_in[10];
    const float* mix_out_w= (const float*)d_in[11];
    const float* out_w    = (const float*)d_in[12];
    const float* out_b    = (const float*)d_in[13];
    const float* code_w   = (const float*)d_in[14];
    const float* code_b   = (const float*)d_in[15];
    float* outF0 = (float*)d_out;                       // [8192][512]
    float* outF1 = (float*)d_out + (size_t)M_ * OUT_;   // [8192][1024]

    char* p = (char*)d_ws;
    auto alloc = [&](size_t bytes) -> char* { char* r = p; p += align256(bytes); return r; };

    bf16*  xb       = (bf16*)alloc((size_t)M_ * INP * 2);
    bf16*  v_inb    = (bf16*)alloc(D_ * 2);
    bf16*  v_normw  = (bf16*)alloc(L_ * D_ * 2);
    bf16*  v_convw  = (bf16*)alloc(L_ * 3 * CONV_DIM * 2);
    bf16*  v_convb  = (bf16*)alloc(L_ * CONV_DIM * 2);
    bf16*  v_gnw    = (bf16*)alloc(L_ * I_ * 2);
    bf16*  v_outb   = (bf16*)alloc(OUT_ * 2);
    bf16*  v_codeb  = (bf16*)alloc(CB_ * 2);
    bf16*  wt_in    = (bf16*)alloc((size_t)1024 * 512 * 2);
    bf16*  wt_big   = (bf16*)alloc((size_t)4352 * 1024 * 2);   // per-layer reuse
    bf16*  wt_small = (bf16*)alloc((size_t)1024 * 2048 * 2);   // per-layer reuse
    bf16*  wt_out   = (bf16*)alloc((size_t)512 * 1024 * 2);
    bf16*  wt_code  = (bf16*)alloc((size_t)1024 * 1024 * 2);
    float* hbuf     = (float*)alloc((size_t)M_ * D_ * 4);      // residual fp32
    bf16*  hn       = (bf16*)alloc((size_t)M_ * D_ * 2);
    bf16*  gate     = (bf16*)alloc((size_t)M_ * I_ * 2);
    bf16*  hbc      = (bf16*)alloc((size_t)M_ * CONV_DIM * 2); // conv in; reused as yscan
    float* dtraw    = (float*)alloc((size_t)M_ * H_ * 4);
    bf16*  xs       = (bf16*)alloc((size_t)M_ * I_ * 2);
    float* bcbuf    = (float*)alloc((size_t)M_ * 128 * 4);     // B | C
    float* wcob     = (float*)alloc((size_t)M_ * H_ * 4);
    float* gmab     = (float*)alloc((size_t)M_ * H_ * 4);
    bf16*  sfin     = (bf16*)alloc((size_t)B_ * H_ * NC * 128 * 64 * 2); // 33.5 MiB
    (void)in_sizes; (void)n_in; (void)out_size;

    size_t needed = (size_t)(p - (char*)d_ws);
    if (needed > ws_size) return;   // diagnostic: absmax reads max|ref| (zeros)

    constexpr size_t SH256 = 131072;   // RING4 x (256+256)x32 bf16
    constexpr size_t SH128 = 73728;    // RING3 x (256+128)x32 bf16
    static bool attr_done = false;
    if (!attr_done) {
        attr_done = true;
        (void)hipFuncSetAttribute((const void*)gemm8p<1, 256, 2, 4, 4>,
                                  hipFuncAttributeMaxDynamicSharedMemorySize, (int)SH256);
        (void)hipFuncSetAttribute((const void*)gemm8p<0, 128, 4, 2, 3>,
                                  hipFuncAttributeMaxDynamicSharedMemorySize, (int)SH128);
        (void)hipFuncSetAttribute((const void*)gemm8p<2, 128, 4, 2, 3>,
                                  hipFuncAttributeMaxDynamicSharedMemorySize, (int)SH128);
    }

    auto ing = [&](const float* src, bf16* dst, int n) {
        ingest_k<<<(n + 255) / 256, 256, 0, stream>>>(src, dst, n);
    };
    ing(x_in, xb, M_ * INP);
    ing(in_b, v_inb, D_);
    ing(norm_w, v_normw, L_ * D_);
    ing(conv_w, v_convw, L_ * 3 * CONV_DIM);
    ing(conv_b, v_convb, L_ * CONV_DIM);
    ing(gnorm_w, v_gnw, L_ * I_);
    ing(out_b, v_outb, OUT_);
    ing(code_b, v_codeb, CB_);

    dim3 tb(32, 8);
    transpose_any<<<dim3(32, 16), tb, 0, stream>>>(in_w, 0, wt_in, 512, 1024);
    transpose_any<<<dim3(16, 32), tb, 0, stream>>>(out_w, 0, wt_out, 1024, 512);
    transpose_any<<<dim3(32, 32), tb, 0, stream>>>(code_w, 0, wt_code, 1024, 1024);

    // h = x @ in_w + in_b     (M=8192, K=512, N=1024)
    gemm8p<0, 128, 4, 2, 3><<<dim3(8, 32), 512, SH128, stream>>>(
        xb, wt_in, INP, D_, v_inb, hbuf, nullptr, nullptr, nullptr);

    for (int i = 0; i < L_; ++i) {
        transpose_any<<<dim3(136, 32), tb, 0, stream>>>(mix_in_w, (size_t)i * 1024 * PROJ,
                                                        wt_big, 1024, PROJ);
        transpose_any<<<dim3(32, 64), tb, 0, stream>>>(mix_out_w, (size_t)i * 2048 * 1024,
                                                       wt_small, 2048, 1024);
        rmsnorm_k<<<M_, 256, 0, stream>>>(hbuf, v_normw + i * D_, hn);
        // proj: M=8192, K=1024, N=4352(pad)
        gemm8p<1, 256, 2, 4, 4><<<dim3(17, 32), 512, SH256, stream>>>(
            hn, wt_big, D_, 4352, nullptr, nullptr, gate, hbc, dtraw);
        conv_k<<<dim3(3, M_), 256, 0, stream>>>(hbc, v_convw + i * 3 * CONV_DIM,
                                                v_convb + i * CONV_DIM, xs, bcbuf);
        dtprep_k<<<B_ * NC * H_ / 4, 256, 0, stream>>>(
            dtraw, dt_bias + i * H_, A_log + i * H_, wcob, gmab);
        scan_local_k<<<B_ * H_ * NC, 128, 0, stream>>>(xs, bcbuf, wcob, gmab,
                                                       Dvec + i * H_, hbc, sfin);
        scan_combine_k<<<B_ * H_ * 64, 128, 0, stream>>>(sfin, gmab);
        scan_correct_k<<<B_ * H_ * NC, 128, 0, stream>>>(sfin, gmab, bcbuf, hbc);
        gatednorm_k<<<M_, 256, 0, stream>>>(hbc, gate, v_gnw + i * I_, xs);
        // out proj: M=8192, K=2048, N=1024, accumulate into residual
        gemm8p<2, 128, 4, 2, 3><<<dim3(8, 32), 512, SH128, stream>>>(
            xs, wt_small, I_, D_, nullptr, hbuf, nullptr, nullptr, nullptr);
    }

    // heads -> fp32 d_out
    cast_f2b_k<<<(M_ * D_) / 1024, 256, 0, stream>>>(hbuf, hn);
    gemm8p<0, 128, 4, 2, 3><<<dim3(4, 32), 512, SH128, stream>>>(
        hn, wt_out, D_, OUT_, v_outb, outF0, nullptr, nullptr, nullptr);
    gemm8p<0, 128, 4, 2, 3><<<dim3(8, 32), 512, SH128, stream>>>(
        hn, wt_code, D_, CB_, v_codeb, outF1, nullptr, nullptr, nullptr);
}

// Round 3
// 1902.139 us; speedup vs baseline: 1.1655x; 1.0156x over previous
//
#include <hip/hip_runtime.h>
#include <hip/hip_bf16.h>

typedef __hip_bfloat16 bf16;
typedef __bf16 bfv8 __attribute__((ext_vector_type(8)));
typedef float fv4 __attribute__((ext_vector_type(4)));

#define B_  8
#define T_  1024
#define INP 512
#define D_  1024
#define I_  2048
#define N_  64
#define H_  16
#define P_  128
#define L_  4
#define OUT_ 512
#define CB_ 1024
#define CONV_DIM 2176
#define PROJ 4240
#define M_  (B_*T_)       // 8192 rows
#define TC  64            // scan chunk length
#define NC  (T_/TC)       // 16 chunks

typedef const __attribute__((address_space(1))) void gv_t;
typedef __attribute__((address_space(3))) void lv_t;

__device__ __forceinline__ void load_lds16(const bf16* g, char* l) {
    __builtin_amdgcn_global_load_lds((gv_t*)g, (lv_t*)l, 16, 0, 0);
}

template <int N> __device__ __forceinline__ void wait_vm() {
    if constexpr (N == 0)      asm volatile("s_waitcnt vmcnt(0)" ::: "memory");
    else if constexpr (N == 2) asm volatile("s_waitcnt vmcnt(2)" ::: "memory");
    else if constexpr (N == 3) asm volatile("s_waitcnt vmcnt(3)" ::: "memory");
    else if constexpr (N == 4) asm volatile("s_waitcnt vmcnt(4)" ::: "memory");
    else if constexpr (N == 6) asm volatile("s_waitcnt vmcnt(6)" ::: "memory");
    else                       asm volatile("s_waitcnt vmcnt(8)" ::: "memory");
}
__device__ __forceinline__ void barrier_sync() {
    asm volatile("s_barrier" ::: "memory");
}

// ---------------------------------------------------------------------------
// fp32 -> bf16 copy
// ---------------------------------------------------------------------------
__global__ __launch_bounds__(256) void ingest_k(const float* __restrict__ src,
                                                bf16* __restrict__ dst, int n) {
    int i = blockIdx.x * 256 + threadIdx.x;
    if (i >= n) return;
    dst[i] = __float2bfloat16(src[i]);
}

// ---------------------------------------------------------------------------
// Transpose fp32 [R][C] -> bf16 [Cp][R], zero-padding rows C..Cp.
// ---------------------------------------------------------------------------
__global__ __launch_bounds__(256) void transpose_any(const float* __restrict__ in,
                                                     size_t off,
                                                     bf16* __restrict__ out,
                                                     int R, int C) {
    __shared__ bf16 tile[32][33];
    int c0 = blockIdx.x * 32, r0 = blockIdx.y * 32;
    int tx = threadIdx.x, ty = threadIdx.y;
#pragma unroll
    for (int i = 0; i < 4; ++i) {
        int r = r0 + ty + i * 8, c = c0 + tx;
        bf16 v = __float2bfloat16(0.f);
        if (c < C) v = __float2bfloat16(in[off + (size_t)r * C + c]);
        tile[ty + i * 8][tx] = v;
    }
    __syncthreads();
#pragma unroll
    for (int i = 0; i < 4; ++i) {
        int c = c0 + ty + i * 8;
        out[(size_t)c * R + r0 + tx] = tile[tx][ty + i * 8];
    }
}

// ---------------------------------------------------------------------------
// GEMM, half-tile ring pipeline: C[M,N] = A[M,K] @ Bt[N,K]^T.
// Key requirement (r2 theory): >=2 resident blocks/CU so block-local phase
// stalls (barrier convoy, LDS latency, vmcnt edges) are hidden by the other
// block's waves. LDS budget per block <= 72KB.
// Per half-tile (K=32): {ds_read MT+NT frags | issue stage for ht+RING-1}
// -> setprio+16 MFMA -> counted vmcnt (never 0 mid-loop) -> s_barrier.
// Swizzle: rows of 64B, 4 slots of 16B, slot ^= (row>>1)&3 (pre-swizzled
// global source + swizzled read = same involution; 2-way residue is free).
// MODE 0: outF = acc + bias  MODE 1: split gate/hBC/dt  MODE 2: outF += acc
// ---------------------------------------------------------------------------
template <int MODE, int BM, int BN, int WGM, int WGN, int RING, int NTHR>
__global__ __launch_bounds__(NTHR) void gemm8p(const bf16* __restrict__ A,
                                               const bf16* __restrict__ Bt,
                                               int K, int N,
                                               const bf16* __restrict__ bias,
                                               float* __restrict__ outF,
                                               bf16* __restrict__ outB,
                                               bf16* __restrict__ outB2,
                                               float* __restrict__ outF2) {
    constexpr int HK = 32;
    constexpr int MT = BM / WGM / 16;            // 4
    constexpr int NT = BN / WGN / 16;            // 4
    constexpr int ABY = BM * HK * 2;
    constexpr int BBY = BN * HK * 2;
    constexpr int BUF = ABY + BBY;
    constexpr int RPI = NTHR / 4;                // rows per staging issue
    constexpr int AL = BM / RPI;
    constexpr int BL = BN / RPI;
    constexpr int LD = AL + BL;                  // own loads per half-tile
    constexpr int IB = NTHR * 16;                // bytes per staging issue

    extern __shared__ char lds[];
    const int tid = threadIdx.x;
    const int wv = tid >> 6, lane = tid & 63;
    const int l16 = lane & 15, quad = lane >> 4;
    const int wm = (wv / WGN) * (BM / WGM);
    const int wn = (wv % WGN) * (BN / WGN);

    // T1: bijective XCD swizzle (m204); all grids here are %8==0
    const int NX = gridDim.x;
    const int nwg = NX * gridDim.y;
    const int orig = blockIdx.y * NX + blockIdx.x;
    const int q = nwg >> 3, r = nwg & 7, xcd = orig & 7, lid = orig >> 3;
    const int wg = (xcd < r ? xcd * (q + 1) : r * (q + 1) + (xcd - r) * q) + lid;
    const int m0 = (wg / NX) * BM;
    const int n0 = (wg % NX) * BN;

    // staging: thread covers LDS linear (row=tid>>2, 16B slot=tid&3);
    // global source pre-swizzled with the same involution used on reads.
    const int srow = tid >> 2, sslot = tid & 3;
    const int swz = (sslot ^ ((srow >> 1) & 3)) << 3;   // element offset
    const bf16* ga = A  + (size_t)(m0 + srow) * K + swz;
    const bf16* gb = Bt + (size_t)(n0 + srow) * K + swz;
    char* lw = lds + wv * 1024;   // wave-uniform stage base (lane*16 implicit)

    const int HT = K / HK;

    auto stageA = [&](int stg, int rbuf) {
#pragma unroll
        for (int j = 0; j < AL; ++j)
            load_lds16(ga + (size_t)stg * HK + (size_t)(j * RPI) * K,
                       lw + rbuf * BUF + j * IB);
    };
    auto stageB = [&](int stg, int rbuf) {
#pragma unroll
        for (int j = 0; j < BL; ++j)
            load_lds16(gb + (size_t)stg * HK + (size_t)(j * RPI) * K,
                       lw + rbuf * BUF + ABY + j * IB);
    };

    // prologue: fill RING-1 buffers; wait until ht0 landed (allow LD
    // outstanding = ht1's own loads), barrier => collective completion.
#pragma unroll
    for (int h = 0; h < RING - 1; ++h) { stageA(h, h); stageB(h, h); }
    wait_vm<LD>();
    barrier_sync();

    fv4 acc[MT][NT] = {};
    int rb = 0;
    for (int ht = 0; ht < HT; ++ht) {
        const char* Ab = lds + rb * BUF;
        const char* Bb = Ab + ABY;
        const int stg = ht + RING - 1;
        const int sb = (rb == 0) ? RING - 1 : rb - 1;   // (ht+RING-1)%RING
        const bool dostage = stg < HT;

        bfv8 bf[NT], af[MT];
#pragma unroll
        for (int i = 0; i < NT; ++i) {
            int rr = wn + i * 16 + l16;
            bf[i] = *(const bfv8*)(Bb + rr * 64 + ((quad ^ ((rr >> 1) & 3)) << 4));
        }
#pragma unroll
        for (int i = 0; i < MT; ++i) {
            int rr = wm + i * 16 + l16;
            af[i] = *(const bfv8*)(Ab + rr * 64 + ((quad ^ ((rr >> 1) & 3)) << 4));
        }
        if (dostage) { stageA(stg, sb); stageB(stg, sb); }
        __builtin_amdgcn_s_setprio(1);
#pragma unroll
        for (int mt = 0; mt < MT; ++mt)
#pragma unroll
            for (int nt = 0; nt < NT; ++nt)
                acc[mt][nt] = __builtin_amdgcn_mfma_f32_16x16x32_bf16(
                    af[mt], bf[nt], acc[mt][nt], 0, 0, 0);
        __builtin_amdgcn_s_setprio(0);

        // counted wait: ensure ht+1's buffer landed (own loads), then barrier
        // => collective completion across all waves of this block.
        int fut = HT - 1 - ht; if (fut > RING - 1) fut = RING - 1;
        if (fut >= 1) {
            int w = (fut - 1) * LD;
            if (w >= LD) wait_vm<LD>();
            else wait_vm<0>();
        }
        barrier_sync();
        rb = (rb + 1 == RING) ? 0 : rb + 1;
    }

#pragma unroll
    for (int mt = 0; mt < MT; ++mt) {
#pragma unroll
        for (int nt = 0; nt < NT; ++nt) {
#pragma unroll
            for (int i = 0; i < 4; ++i) {
                int row = m0 + wm + mt * 16 + quad * 4 + i;
                int col = n0 + wn + nt * 16 + l16;
                float v = acc[mt][nt][i];
                if (MODE == 0) {
                    v += __bfloat162float(bias[col]);
                    outF[(size_t)row * N + col] = v;
                } else if (MODE == 1) {
                    if (col < I_)
                        outB[(size_t)row * I_ + col] = __float2bfloat16(v);
                    else if (col < I_ + CONV_DIM)
                        outB2[(size_t)row * CONV_DIM + (col - I_)] = __float2bfloat16(v);
                    else if (col < PROJ)
                        outF2[(size_t)row * H_ + (col - (I_ + CONV_DIM))] = v;
                } else if (MODE == 2) {
                    outF[(size_t)row * N + col] += v;
                }
            }
        }
    }
}

// ---------------------------------------------------------------------------
__global__ __launch_bounds__(256) void rmsnorm_k(const float* __restrict__ x,
                                                 const bf16* __restrict__ w,
                                                 bf16* __restrict__ out) {
    int row = blockIdx.x, tid = threadIdx.x;
    float4 v = *(const float4*)&x[(size_t)row * D_ + tid * 4];
    float ss = v.x * v.x + v.y * v.y + v.z * v.z + v.w * v.w;
#pragma unroll
    for (int off = 32; off; off >>= 1) ss += __shfl_down(ss, off);
    __shared__ float sb[4];
    if ((tid & 63) == 0) sb[tid >> 6] = ss;
    __syncthreads();
    ss = sb[0] + sb[1] + sb[2] + sb[3];
    float rs = rsqrtf(ss * (1.f / D_) + 1e-6f);
    float xv[4] = {v.x, v.y, v.z, v.w};
#pragma unroll
    for (int j = 0; j < 4; ++j)
        out[(size_t)row * D_ + tid * 4 + j] =
            __float2bfloat16(xv[j] * rs * __bfloat162float(w[tid * 4 + j]));
}

// ---------------------------------------------------------------------------
__global__ __launch_bounds__(256) void gatednorm_k(const bf16* __restrict__ y,
                                                   const bf16* __restrict__ g,
                                                   const bf16* __restrict__ w,
                                                   bf16* __restrict__ out) {
    int row = blockIdx.x, tid = threadIdx.x;
    size_t base = (size_t)row * I_ + tid * 8;
    bf16 yv[8], gv[8];
    *(uint4*)yv = *(const uint4*)&y[base];
    *(uint4*)gv = *(const uint4*)&g[base];
    float vv[8]; float ss = 0.f;
#pragma unroll
    for (int j = 0; j < 8; ++j) {
        float yf = __bfloat162float(yv[j]);
        float gf = __bfloat162float(gv[j]);
        float sig = 1.f / (1.f + expf(-gf));
        vv[j] = yf * gf * sig;
        ss += vv[j] * vv[j];
    }
#pragma unroll
    for (int off = 32; off; off >>= 1) ss += __shfl_down(ss, off);
    __shared__ float sb[4];
    if ((tid & 63) == 0) sb[tid >> 6] = ss;
    __syncthreads();
    ss = sb[0] + sb[1] + sb[2] + sb[3];
    float rs = rsqrtf(ss * (1.f / I_) + 1e-6f);
    bf16 ov[8];
#pragma unroll
    for (int j = 0; j < 8; ++j)
        ov[j] = __float2bfloat16(vv[j] * rs * __bfloat162float(w[tid * 8 + j]));
    *(uint4*)&out[base] = *(uint4*)ov;
}

// ---------------------------------------------------------------------------
__global__ __launch_bounds__(256) void conv_k(const bf16* __restrict__ hbc,
                                              const bf16* __restrict__ w,
                                              const bf16* __restrict__ bias,
                                              bf16* __restrict__ xs,
                                              float* __restrict__ bc) {
    int cq = blockIdx.x * 256 + threadIdx.x;
    if (cq >= CONV_DIM / 4) return;
    int c = cq * 4;
    int bt = blockIdx.y;
    int t = bt & (T_ - 1);
    float acc[4];
#pragma unroll
    for (int j = 0; j < 4; ++j) acc[j] = __bfloat162float(bias[c + j]);
#pragma unroll
    for (int k = 0; k < 3; ++k) {
        int tt = t - 2 + k;
        if (tt < 0) continue;
        const bf16* src = &hbc[(size_t)(bt - 2 + k) * CONV_DIM + c];
#pragma unroll
        for (int j = 0; j < 4; ++j)
            acc[j] = fmaf(__bfloat162float(w[k * CONV_DIM + c + j]),
                          __bfloat162float(src[j]), acc[j]);
    }
#pragma unroll
    for (int j = 0; j < 4; ++j) {
        float v = acc[j];
        v = v / (1.f + expf(-v));     // silu
        if (c + j < I_) xs[(size_t)bt * I_ + c + j] = __float2bfloat16(v);
        else            bc[(size_t)bt * 128 + (c + j - I_)] = v;
    }
}

// ---------------------------------------------------------------------------
// dt prep, wave-parallel: one wave per (b,h,chunk) chain. dt = softplus;
// gamma = exp(inclusive-prefix-sum(dt*a)) == cumprod(exp(dt*a)).
// ---------------------------------------------------------------------------
__global__ __launch_bounds__(256) void dtprep_k(const float* __restrict__ dtraw,
                                                const float* __restrict__ dtb,
                                                const float* __restrict__ alog,
                                                float* __restrict__ wco,
                                                float* __restrict__ gma) {
    int chain = blockIdx.x * 4 + (threadIdx.x >> 6);   // b*256 + ci*16 + h
    int s = threadIdx.x & 63;
    int h = chain & 15, ci = (chain >> 4) & (NC - 1), b = chain >> 8;
    float a = -expf(alog[h]);
    float bz = dtb[h];
    int idx = (b * T_ + ci * TC + s) * H_ + h;
    float z = dtraw[idx] + bz;
    float dt = fmaxf(z, 0.f) + log1pf(expf(-fabsf(z)));
    float ps = dt * a;
#pragma unroll
    for (int d = 1; d < 64; d <<= 1) {
        float o = __shfl_up(ps, d, 64);
        if (s >= d) ps += o;
    }
    float g = expf(ps);
    wco[idx] = dt / g;
    gma[idx] = g;
}

// ---------------------------------------------------------------------------
// Scan pass A (normalized form): per (b,h,chunk) local scan from zero state.
// ---------------------------------------------------------------------------
__global__ __launch_bounds__(128) void scan_local_k(const bf16* __restrict__ xs,
                                                    const float* __restrict__ bc,
                                                    const float* __restrict__ wco,
                                                    const float* __restrict__ gma,
                                                    const float* __restrict__ dvec,
                                                    bf16* __restrict__ yout,
                                                    bf16* __restrict__ sfin) {
    int bid = blockIdx.x;                   // b*256 + h*16 + ci
    int ci = bid & (NC - 1);
    int h  = (bid >> 4) & (H_ - 1);
    int b  = bid >> 8;
    int p = threadIdx.x;
    float Dv = dvec[h];
    float st[64];
#pragma unroll
    for (int n = 0; n < 64; ++n) st[n] = 0.f;
    int bt0 = b * T_ + ci * TC;
    const bf16* xptr = xs + (size_t)bt0 * I_ + h * P_ + p;
    bf16* yptr = yout + (size_t)bt0 * I_ + h * P_ + p;
    float xv_n = __bfloat162float(xptr[0]);
    for (int s = 0; s < TC; ++s) {
        float xv = xv_n;
        if (s + 1 < TC) xv_n = __bfloat162float(xptr[(size_t)(s + 1) * I_]);
        float w = wco[(bt0 + s) * H_ + h];          // uniform
        float g = gma[(bt0 + s) * H_ + h];
        float cc = w * xv;
        const float4* B4 = (const float4*)&bc[(size_t)(bt0 + s) * 128];
#pragma unroll
        for (int j = 0; j < 16; ++j) {
            float4 bv = B4[j];
            st[4 * j + 0] = fmaf(cc, bv.x, st[4 * j + 0]);
            st[4 * j + 1] = fmaf(cc, bv.y, st[4 * j + 1]);
            st[4 * j + 2] = fmaf(cc, bv.z, st[4 * j + 2]);
            st[4 * j + 3] = fmaf(cc, bv.w, st[4 * j + 3]);
        }
        float y0 = 0.f, y1 = 0.f, y2 = 0.f, y3 = 0.f;
#pragma unroll
        for (int j = 0; j < 16; ++j) {
            float4 cv = B4[16 + j];
            y0 = fmaf(st[4 * j + 0], cv.x, y0);
            y1 = fmaf(st[4 * j + 1], cv.y, y1);
            y2 = fmaf(st[4 * j + 2], cv.z, y2);
            y3 = fmaf(st[4 * j + 3], cv.w, y3);
        }
        yptr[(size_t)s * I_] = __float2bfloat16(fmaf(g, (y0 + y1) + (y2 + y3), Dv * xv));
    }
    float G = gma[(bt0 + TC - 1) * H_ + h];
    bf16* sf = sfin + (size_t)bid * (128 * 64);
#pragma unroll
    for (int n = 0; n < 64; ++n) sf[n * 128 + p] = __float2bfloat16(st[n] * G);
}

// ---------------------------------------------------------------------------
// Pass B: chunk combine, PARALLEL over (b,h,n,p) — sequential only in ci.
// ---------------------------------------------------------------------------
__global__ __launch_bounds__(128) void scan_combine_k(bf16* __restrict__ sbuf,
                                                      const float* __restrict__ gma) {
    int bid = blockIdx.x;                   // b*H*64 + h*64 + n
    int n = bid & 63;
    int h = (bid >> 6) & (H_ - 1);
    int b = bid >> 10;
    int p = threadIdx.x;
    size_t base0 = ((size_t)(b * (H_ * NC) + h * NC) * (128 * 64)) + n * 128 + p;
    int gbase = b * T_ * H_ + h;
    float S = 0.f;
#pragma unroll
    for (int ci = 0; ci < NC; ++ci) {
        bf16* addr = sbuf + base0 + (size_t)ci * (128 * 64);
        float tmp = __bfloat162float(*addr);            // S_fin of chunk ci
        *addr = __float2bfloat16(S);                    // S_init of chunk ci
        float G = gma[gbase + (ci * TC + TC - 1) * H_]; // uniform per block
        S = fmaf(G, S, tmp);
    }
}

// ---------------------------------------------------------------------------
// Pass C: y += gamma_t * (C_t . S_init)
// ---------------------------------------------------------------------------
__global__ __launch_bounds__(128) void scan_correct_k(const bf16* __restrict__ sinit,
                                                      const float* __restrict__ gma,
                                                      const float* __restrict__ bc,
                                                      bf16* __restrict__ yout) {
    int bid = blockIdx.x;
    int ci = bid & (NC - 1);
    if (ci == 0) return;
    int h = (bid >> 4) & (H_ - 1);
    int b = bid >> 8;
    int p = threadIdx.x;
    const bf16* sb = sinit + (size_t)bid * (128 * 64);
    float S[64];
#pragma unroll
    for (int n = 0; n < 64; ++n) S[n] = __bfloat162float(sb[n * 128 + p]);
    int bt0 = b * T_ + ci * TC;
    bf16* yptr = yout + (size_t)bt0 * I_ + h * P_ + p;
    for (int s = 0; s < TC; ++s) {
        float g = gma[(bt0 + s) * H_ + h];
        const float4* C4 = (const float4*)&bc[(size_t)(bt0 + s) * 128 + 64];
        float y0 = 0.f, y1 = 0.f, y2 = 0.f, y3 = 0.f;
#pragma unroll
        for (int j = 0; j < 16; ++j) {
            float4 cv = C4[j];
            y0 = fmaf(S[4 * j + 0], cv.x, y0);
            y1 = fmaf(S[4 * j + 1], cv.y, y1);
            y2 = fmaf(S[4 * j + 2], cv.z, y2);
            y3 = fmaf(S[4 * j + 3], cv.w, y3);
        }
        float y = __bfloat162float(yptr[(size_t)s * I_]);
        yptr[(size_t)s * I_] = __float2bfloat16(fmaf(g, (y0 + y1) + (y2 + y3), y));
    }
}

// ---------------------------------------------------------------------------
__global__ __launch_bounds__(256) void cast_f2b_k(const float* __restrict__ in,
                                                  bf16* __restrict__ out) {
    int i = (blockIdx.x * 256 + threadIdx.x) * 4;
    float4 v = *(const float4*)&in[i];
    bf16 ov[4] = {__float2bfloat16(v.x), __float2bfloat16(v.y),
                  __float2bfloat16(v.z), __float2bfloat16(v.w)};
    *(uint2*)&out[i] = *(uint2*)ov;
}

// ---------------------------------------------------------------------------

static inline size_t align256(size_t x) { return (x + 255) & ~(size_t)255; }

extern "C" void kernel_launch(void* const* d_in, const int* in_sizes, int n_in,
                              void* d_out, int out_size, void* d_ws, size_t ws_size,
                              hipStream_t stream) {
    const float* x_in     = (const float*)d_in[0];
    const float* in_w     = (const float*)d_in[1];
    const float* in_b     = (const float*)d_in[2];
    const float* norm_w   = (const float*)d_in[3];
    const float* mix_in_w = (const float*)d_in[4];
    const float* conv_w   = (const float*)d_in[5];
    const float* conv_b   = (const float*)d_in[6];
    const float* dt_bias  = (const float*)d_in[7];
    const float* A_log    = (const float*)d_in[8];
    const float* Dvec     = (const float*)d_in[9];
    const float* gnorm_w  = (const float*)d_in[10];
    const float* mix_out_w= (const float*)d_in[11];
    const float* out_w    = (const float*)d_in[12];
    const float* out_b    = (const float*)d_in[13];
    const float* code_w   = (const float*)d_in[14];
    const float* code_b   = (const float*)d_in[15];
    float* outF0 = (float*)d_out;                       // [8192][512]
    float* outF1 = (float*)d_out + (size_t)M_ * OUT_;   // [8192][1024]

    char* p = (char*)d_ws;
    auto alloc = [&](size_t bytes) -> char* { char* r = p; p += align256(bytes); return r; };

    bf16*  xb       = (bf16*)alloc((size_t)M_ * INP * 2);
    bf16*  v_inb    = (bf16*)alloc(D_ * 2);
    bf16*  v_normw  = (bf16*)alloc(L_ * D_ * 2);
    bf16*  v_convw  = (bf16*)alloc(L_ * 3 * CONV_DIM * 2);
    bf16*  v_convb  = (bf16*)alloc(L_ * CONV_DIM * 2);
    bf16*  v_gnw    = (bf16*)alloc(L_ * I_ * 2);
    bf16*  v_outb   = (bf16*)alloc(OUT_ * 2);
    bf16*  v_codeb  = (bf16*)alloc(CB_ * 2);
    bf16*  wt_in    = (bf16*)alloc((size_t)1024 * 512 * 2);
    bf16*  wt_big   = (bf16*)alloc((size_t)4352 * 1024 * 2);   // per-layer reuse
    bf16*  wt_small = (bf16*)alloc((size_t)1024 * 2048 * 2);   // per-layer reuse
    bf16*  wt_out   = (bf16*)alloc((size_t)512 * 1024 * 2);
    bf16*  wt_code  = (bf16*)alloc((size_t)1024 * 1024 * 2);
    float* hbuf     = (float*)alloc((size_t)M_ * D_ * 4);      // residual fp32
    bf16*  hn       = (bf16*)alloc((size_t)M_ * D_ * 2);
    bf16*  gate     = (bf16*)alloc((size_t)M_ * I_ * 2);
    bf16*  hbc      = (bf16*)alloc((size_t)M_ * CONV_DIM * 2); // conv in; reused as yscan
    float* dtraw    = (float*)alloc((size_t)M_ * H_ * 4);
    bf16*  xs       = (bf16*)alloc((size_t)M_ * I_ * 2);
    float* bcbuf    = (float*)alloc((size_t)M_ * 128 * 4);     // B | C
    float* wcob     = (float*)alloc((size_t)M_ * H_ * 4);
    float* gmab     = (float*)alloc((size_t)M_ * H_ * 4);
    bf16*  sfin     = (bf16*)alloc((size_t)B_ * H_ * NC * 128 * 64 * 2); // 33.5 MiB
    (void)in_sizes; (void)n_in; (void)out_size;

    size_t needed = (size_t)(p - (char*)d_ws);
    if (needed > ws_size) return;   // diagnostic: absmax reads max|ref| (zeros)

    constexpr size_t SH_PROJ = 73728;   // RING3 x (256+128)x32 bf16 -> 2 blk/CU
    constexpr size_t SH_SQ   = 49152;   // RING3 x (128+128)x32 bf16 -> 3 blk/CU
    static bool attr_done = false;
    if (!attr_done) {
        attr_done = true;
        (void)hipFuncSetAttribute((const void*)gemm8p<1, 256, 128, 4, 2, 3, 512>,
                                  hipFuncAttributeMaxDynamicSharedMemorySize, (int)SH_PROJ);
        (void)hipFuncSetAttribute((const void*)gemm8p<0, 128, 128, 2, 2, 3, 256>,
                                  hipFuncAttributeMaxDynamicSharedMemorySize, (int)SH_SQ);
        (void)hipFuncSetAttribute((const void*)gemm8p<2, 128, 128, 2, 2, 3, 256>,
                                  hipFuncAttributeMaxDynamicSharedMemorySize, (int)SH_SQ);
    }

    auto ing = [&](const float* src, bf16* dst, int n) {
        ingest_k<<<(n + 255) / 256, 256, 0, stream>>>(src, dst, n);
    };
    ing(x_in, xb, M_ * INP);
    ing(in_b, v_inb, D_);
    ing(norm_w, v_normw, L_ * D_);
    ing(conv_w, v_convw, L_ * 3 * CONV_DIM);
    ing(conv_b, v_convb, L_ * CONV_DIM);
    ing(gnorm_w, v_gnw, L_ * I_);
    ing(out_b, v_outb, OUT_);
    ing(code_b, v_codeb, CB_);

    dim3 tb(32, 8);
    transpose_any<<<dim3(32, 16), tb, 0, stream>>>(in_w, 0, wt_in, 512, 1024);
    transpose_any<<<dim3(16, 32), tb, 0, stream>>>(out_w, 0, wt_out, 1024, 512);
    transpose_any<<<dim3(32, 32), tb, 0, stream>>>(code_w, 0, wt_code, 1024, 1024);

    // h = x @ in_w + in_b     (M=8192, K=512, N=1024) -> 512 blocks
    gemm8p<0, 128, 128, 2, 2, 3, 256><<<dim3(8, 64), 256, SH_SQ, stream>>>(
        xb, wt_in, INP, D_, v_inb, hbuf, nullptr, nullptr, nullptr);

    for (int i = 0; i < L_; ++i) {
        transpose_any<<<dim3(136, 32), tb, 0, stream>>>(mix_in_w, (size_t)i * 1024 * PROJ,
                                                        wt_big, 1024, PROJ);
        transpose_any<<<dim3(32, 64), tb, 0, stream>>>(mix_out_w, (size_t)i * 2048 * 1024,
                                                       wt_small, 2048, 1024);
        rmsnorm_k<<<M_, 256, 0, stream>>>(hbuf, v_normw + i * D_, hn);
        // proj: M=8192, K=1024, N=4352(pad) -> 1088 blocks, 2 blk/CU
        gemm8p<1, 256, 128, 4, 2, 3, 512><<<dim3(34, 32), 512, SH_PROJ, stream>>>(
            hn, wt_big, D_, 4352, nullptr, nullptr, gate, hbc, dtraw);
        conv_k<<<dim3(3, M_), 256, 0, stream>>>(hbc, v_convw + i * 3 * CONV_DIM,
                                                v_convb + i * CONV_DIM, xs, bcbuf);
        dtprep_k<<<B_ * NC * H_ / 4, 256, 0, stream>>>(
            dtraw, dt_bias + i * H_, A_log + i * H_, wcob, gmab);
        scan_local_k<<<B_ * H_ * NC, 128, 0, stream>>>(xs, bcbuf, wcob, gmab,
                                                       Dvec + i * H_, hbc, sfin);
        scan_combine_k<<<B_ * H_ * 64, 128, 0, stream>>>(sfin, gmab);
        scan_correct_k<<<B_ * H_ * NC, 128, 0, stream>>>(sfin, gmab, bcbuf, hbc);
        gatednorm_k<<<M_, 256, 0, stream>>>(hbc, gate, v_gnw + i * I_, xs);
        // out proj: M=8192, K=2048, N=1024 -> 512 blocks, 3 blk/CU
        gemm8p<2, 128, 128, 2, 2, 3, 256><<<dim3(8, 64), 256, SH_SQ, stream>>>(
            xs, wt_small, I_, D_, nullptr, hbuf, nullptr, nullptr, nullptr);
    }

    // heads -> fp32 d_out
    cast_f2b_k<<<(M_ * D_) / 1024, 256, 0, stream>>>(hbuf, hn);
    gemm8p<0, 128, 128, 2, 2, 3, 256><<<dim3(4, 64), 256, SH_SQ, stream>>>(
        hn, wt_out, D_, OUT_, v_outb, outF0, nullptr, nullptr, nullptr);
    gemm8p<0, 128, 128, 2, 2, 3, 256><<<dim3(8, 64), 256, SH_SQ, stream>>>(
        hn, wt_code, D_, CB_, v_codeb, outF1, nullptr, nullptr, nullptr);
}

// Round 5
// 1647.040 us; speedup vs baseline: 1.3460x; 1.1549x over previous
//
#include <hip/hip_runtime.h>
#include <hip/hip_bf16.h>

typedef __hip_bfloat16 bf16;
typedef __bf16 bfv8 __attribute__((ext_vector_type(8)));
typedef float fv4 __attribute__((ext_vector_type(4)));

#define B_  8
#define T_  1024
#define INP 512
#define D_  1024
#define I_  2048
#define N_  64
#define H_  16
#define P_  128
#define L_  4
#define OUT_ 512
#define CB_ 1024
#define CONV_DIM 2176
#define PROJ 4240
#define M_  (B_*T_)       // 8192 rows
#define TC  64            // scan chunk length
#define NC  (T_/TC)       // 16 chunks

typedef const __attribute__((address_space(1))) void gv_t;
typedef __attribute__((address_space(3))) void lv_t;

__device__ __forceinline__ void load_lds16(const bf16* g, char* l) {
    __builtin_amdgcn_global_load_lds((gv_t*)g, (lv_t*)l, 16, 0, 0);
}

template <int N> __device__ __forceinline__ void wait_vm() {
    if constexpr (N == 0)      asm volatile("s_waitcnt vmcnt(0)" ::: "memory");
    else if constexpr (N == 2) asm volatile("s_waitcnt vmcnt(2)" ::: "memory");
    else if constexpr (N == 3) asm volatile("s_waitcnt vmcnt(3)" ::: "memory");
    else if constexpr (N == 4) asm volatile("s_waitcnt vmcnt(4)" ::: "memory");
    else if constexpr (N == 6) asm volatile("s_waitcnt vmcnt(6)" ::: "memory");
    else                       asm volatile("s_waitcnt vmcnt(8)" ::: "memory");
}
__device__ __forceinline__ void barrier_sync() {
    asm volatile("s_barrier" ::: "memory");
}

__device__ __forceinline__ fv4 MF(bfv8 a, bfv8 b, fv4 c) {
    return __builtin_amdgcn_mfma_f32_16x16x32_bf16(a, b, c, 0, 0, 0);
}
__device__ __forceinline__ __bf16 f2b(float x) {
    __hip_bfloat16 h = __float2bfloat16(x);
    union { unsigned short u; __bf16 b; } t;
    t.u = *reinterpret_cast<unsigned short*>(&h);
    return t.b;
}
__device__ __forceinline__ float bb2f(__bf16 x) {
    union { __bf16 b; unsigned short u; } t; t.b = x;
    union { unsigned int u; float f; } r; r.u = (unsigned int)t.u << 16;
    return r.f;
}
__device__ __forceinline__ bfv8 cvt8f(const float* p) {
    float4 a = *(const float4*)p, b = *(const float4*)(p + 4);
    bfv8 r;
    r[0] = f2b(a.x); r[1] = f2b(a.y); r[2] = f2b(a.z); r[3] = f2b(a.w);
    r[4] = f2b(b.x); r[5] = f2b(b.y); r[6] = f2b(b.z); r[7] = f2b(b.w);
    return r;
}

// ---------------------------------------------------------------------------
// fp32 -> bf16 copy
// ---------------------------------------------------------------------------
__global__ __launch_bounds__(256) void ingest_k(const float* __restrict__ src,
                                                bf16* __restrict__ dst, int n) {
    int i = blockIdx.x * 256 + threadIdx.x;
    if (i >= n) return;
    dst[i] = __float2bfloat16(src[i]);
}

// ---------------------------------------------------------------------------
// Transpose fp32 [R][C] -> bf16 [Cp][R], zero-padding rows C..Cp.
// ---------------------------------------------------------------------------
__global__ __launch_bounds__(256) void transpose_any(const float* __restrict__ in,
                                                     size_t off,
                                                     bf16* __restrict__ out,
                                                     int R, int C) {
    __shared__ bf16 tile[32][33];
    int c0 = blockIdx.x * 32, r0 = blockIdx.y * 32;
    int tx = threadIdx.x, ty = threadIdx.y;
#pragma unroll
    for (int i = 0; i < 4; ++i) {
        int r = r0 + ty + i * 8, c = c0 + tx;
        bf16 v = __float2bfloat16(0.f);
        if (c < C) v = __float2bfloat16(in[off + (size_t)r * C + c]);
        tile[ty + i * 8][tx] = v;
    }
    __syncthreads();
#pragma unroll
    for (int i = 0; i < 4; ++i) {
        int c = c0 + ty + i * 8;
        out[(size_t)c * R + r0 + tx] = tile[tx][ty + i * 8];
    }
}

// ---------------------------------------------------------------------------
// GEMM, half-tile ring pipeline (r3 config — verified fastest so far).
// ---------------------------------------------------------------------------
template <int MODE, int BM, int BN, int WGM, int WGN, int RING, int NTHR>
__global__ __launch_bounds__(NTHR) void gemm8p(const bf16* __restrict__ A,
                                               const bf16* __restrict__ Bt,
                                               int K, int N,
                                               const bf16* __restrict__ bias,
                                               float* __restrict__ outF,
                                               bf16* __restrict__ outB,
                                               bf16* __restrict__ outB2,
                                               float* __restrict__ outF2) {
    constexpr int HK = 32;
    constexpr int MT = BM / WGM / 16;
    constexpr int NT = BN / WGN / 16;
    constexpr int ABY = BM * HK * 2;
    constexpr int BBY = BN * HK * 2;
    constexpr int BUF = ABY + BBY;
    constexpr int RPI = NTHR / 4;
    constexpr int AL = BM / RPI;
    constexpr int BL = BN / RPI;
    constexpr int LD = AL + BL;
    constexpr int IB = NTHR * 16;

    extern __shared__ char lds[];
    const int tid = threadIdx.x;
    const int wv = tid >> 6, lane = tid & 63;
    const int l16 = lane & 15, quad = lane >> 4;
    const int wm = (wv / WGN) * (BM / WGM);
    const int wn = (wv % WGN) * (BN / WGN);

    const int NX = gridDim.x;
    const int nwg = NX * gridDim.y;
    const int orig = blockIdx.y * NX + blockIdx.x;
    const int q = nwg >> 3, r = nwg & 7, xcd = orig & 7, lid = orig >> 3;
    const int wg = (xcd < r ? xcd * (q + 1) : r * (q + 1) + (xcd - r) * q) + lid;
    const int m0 = (wg / NX) * BM;
    const int n0 = (wg % NX) * BN;

    const int srow = tid >> 2, sslot = tid & 3;
    const int swz = (sslot ^ ((srow >> 1) & 3)) << 3;
    const bf16* ga = A  + (size_t)(m0 + srow) * K + swz;
    const bf16* gb = Bt + (size_t)(n0 + srow) * K + swz;
    char* lw = lds + wv * 1024;

    const int HT = K / HK;

    auto stageA = [&](int stg, int rbuf) {
#pragma unroll
        for (int j = 0; j < AL; ++j)
            load_lds16(ga + (size_t)stg * HK + (size_t)(j * RPI) * K,
                       lw + rbuf * BUF + j * IB);
    };
    auto stageB = [&](int stg, int rbuf) {
#pragma unroll
        for (int j = 0; j < BL; ++j)
            load_lds16(gb + (size_t)stg * HK + (size_t)(j * RPI) * K,
                       lw + rbuf * BUF + ABY + j * IB);
    };

#pragma unroll
    for (int h = 0; h < RING - 1; ++h) { stageA(h, h); stageB(h, h); }
    wait_vm<LD>();
    barrier_sync();

    fv4 acc[MT][NT] = {};
    int rb = 0;
    for (int ht = 0; ht < HT; ++ht) {
        const char* Ab = lds + rb * BUF;
        const char* Bb = Ab + ABY;
        const int stg = ht + RING - 1;
        const int sb = (rb == 0) ? RING - 1 : rb - 1;
        const bool dostage = stg < HT;

        bfv8 bf[NT], af[MT];
#pragma unroll
        for (int i = 0; i < NT; ++i) {
            int rr = wn + i * 16 + l16;
            bf[i] = *(const bfv8*)(Bb + rr * 64 + ((quad ^ ((rr >> 1) & 3)) << 4));
        }
#pragma unroll
        for (int i = 0; i < MT; ++i) {
            int rr = wm + i * 16 + l16;
            af[i] = *(const bfv8*)(Ab + rr * 64 + ((quad ^ ((rr >> 1) & 3)) << 4));
        }
        if (dostage) { stageA(stg, sb); stageB(stg, sb); }
        __builtin_amdgcn_s_setprio(1);
#pragma unroll
        for (int mt = 0; mt < MT; ++mt)
#pragma unroll
            for (int nt = 0; nt < NT; ++nt)
                acc[mt][nt] = MF(af[mt], bf[nt], acc[mt][nt]);
        __builtin_amdgcn_s_setprio(0);

        int fut = HT - 1 - ht; if (fut > RING - 1) fut = RING - 1;
        if (fut >= 1) {
            int w = (fut - 1) * LD;
            if (w >= LD) wait_vm<LD>();
            else wait_vm<0>();
        }
        barrier_sync();
        rb = (rb + 1 == RING) ? 0 : rb + 1;
    }

#pragma unroll
    for (int mt = 0; mt < MT; ++mt) {
#pragma unroll
        for (int nt = 0; nt < NT; ++nt) {
#pragma unroll
            for (int i = 0; i < 4; ++i) {
                int row = m0 + wm + mt * 16 + quad * 4 + i;
                int col = n0 + wn + nt * 16 + l16;
                float v = acc[mt][nt][i];
                if (MODE == 0) {
                    v += __bfloat162float(bias[col]);
                    outF[(size_t)row * N + col] = v;
                } else if (MODE == 1) {
                    if (col < I_)
                        outB[(size_t)row * I_ + col] = __float2bfloat16(v);
                    else if (col < I_ + CONV_DIM)
                        outB2[(size_t)row * CONV_DIM + (col - I_)] = __float2bfloat16(v);
                    else if (col < PROJ)
                        outF2[(size_t)row * H_ + (col - (I_ + CONV_DIM))] = v;
                } else if (MODE == 2) {
                    outF[(size_t)row * N + col] += v;
                }
            }
        }
    }
}

// ---------------------------------------------------------------------------
__global__ __launch_bounds__(256) void rmsnorm_k(const float* __restrict__ x,
                                                 const bf16* __restrict__ w,
                                                 bf16* __restrict__ out) {
    int row = blockIdx.x, tid = threadIdx.x;
    float4 v = *(const float4*)&x[(size_t)row * D_ + tid * 4];
    float ss = v.x * v.x + v.y * v.y + v.z * v.z + v.w * v.w;
#pragma unroll
    for (int off = 32; off; off >>= 1) ss += __shfl_down(ss, off);
    __shared__ float sb[4];
    if ((tid & 63) == 0) sb[tid >> 6] = ss;
    __syncthreads();
    ss = sb[0] + sb[1] + sb[2] + sb[3];
    float rs = rsqrtf(ss * (1.f / D_) + 1e-6f);
    float xv[4] = {v.x, v.y, v.z, v.w};
#pragma unroll
    for (int j = 0; j < 4; ++j)
        out[(size_t)row * D_ + tid * 4 + j] =
            __float2bfloat16(xv[j] * rs * __bfloat162float(w[tid * 4 + j]));
}

// ---------------------------------------------------------------------------
__global__ __launch_bounds__(256) void gatednorm_k(const bf16* __restrict__ y,
                                                   const bf16* __restrict__ g,
                                                   const bf16* __restrict__ w,
                                                   bf16* __restrict__ out) {
    int row = blockIdx.x, tid = threadIdx.x;
    size_t base = (size_t)row * I_ + tid * 8;
    bf16 yv[8], gv[8];
    *(uint4*)yv = *(const uint4*)&y[base];
    *(uint4*)gv = *(const uint4*)&g[base];
    float vv[8]; float ss = 0.f;
#pragma unroll
    for (int j = 0; j < 8; ++j) {
        float yf = __bfloat162float(yv[j]);
        float gf = __bfloat162float(gv[j]);
        float sig = 1.f / (1.f + expf(-gf));
        vv[j] = yf * gf * sig;
        ss += vv[j] * vv[j];
    }
#pragma unroll
    for (int off = 32; off; off >>= 1) ss += __shfl_down(ss, off);
    __shared__ float sb[4];
    if ((tid & 63) == 0) sb[tid >> 6] = ss;
    __syncthreads();
    ss = sb[0] + sb[1] + sb[2] + sb[3];
    float rs = rsqrtf(ss * (1.f / I_) + 1e-6f);
    bf16 ov[8];
#pragma unroll
    for (int j = 0; j < 8; ++j)
        ov[j] = __float2bfloat16(vv[j] * rs * __bfloat162float(w[tid * 8 + j]));
    *(uint4*)&out[base] = *(uint4*)ov;
}

// ---------------------------------------------------------------------------
__global__ __launch_bounds__(256) void conv_k(const bf16* __restrict__ hbc,
                                              const bf16* __restrict__ w,
                                              const bf16* __restrict__ bias,
                                              bf16* __restrict__ xs,
                                              float* __restrict__ bc) {
    int cq = blockIdx.x * 256 + threadIdx.x;
    if (cq >= CONV_DIM / 4) return;
    int c = cq * 4;
    int bt = blockIdx.y;
    int t = bt & (T_ - 1);
    float acc[4];
#pragma unroll
    for (int j = 0; j < 4; ++j) acc[j] = __bfloat162float(bias[c + j]);
#pragma unroll
    for (int k = 0; k < 3; ++k) {
        int tt = t - 2 + k;
        if (tt < 0) continue;
        const bf16* src = &hbc[(size_t)(bt - 2 + k) * CONV_DIM + c];
#pragma unroll
        for (int j = 0; j < 4; ++j)
            acc[j] = fmaf(__bfloat162float(w[k * CONV_DIM + c + j]),
                          __bfloat162float(src[j]), acc[j]);
    }
#pragma unroll
    for (int j = 0; j < 4; ++j) {
        float v = acc[j];
        v = v / (1.f + expf(-v));     // silu
        if (c + j < I_) xs[(size_t)bt * I_ + c + j] = __float2bfloat16(v);
        else            bc[(size_t)bt * 128 + (c + j - I_)] = v;
    }
}

// ---------------------------------------------------------------------------
// dt prep, wave-parallel prefix scan.
// ---------------------------------------------------------------------------
__global__ __launch_bounds__(256) void dtprep_k(const float* __restrict__ dtraw,
                                                const float* __restrict__ dtb,
                                                const float* __restrict__ alog,
                                                float* __restrict__ wco,
                                                float* __restrict__ gma) {
    int chain = blockIdx.x * 4 + (threadIdx.x >> 6);   // b*256 + ci*16 + h
    int s = threadIdx.x & 63;
    int h = chain & 15, ci = (chain >> 4) & (NC - 1), b = chain >> 8;
    float a = -expf(alog[h]);
    float bz = dtb[h];
    int idx = (b * T_ + ci * TC + s) * H_ + h;
    float z = dtraw[idx] + bz;
    float dt = fmaxf(z, 0.f) + log1pf(expf(-fabsf(z)));
    float ps = dt * a;
#pragma unroll
    for (int d = 1; d < 64; d <<= 1) {
        float o = __shfl_up(ps, d, 64);
        if (s >= d) ps += o;
    }
    float g = expf(ps);
    wco[idx] = dt / g;
    gma[idx] = g;
}

// ---------------------------------------------------------------------------
// X transpose: xs [b*T][h*128+p] bf16 -> xt [(b*16+h)*128+p][T] bf16
// ---------------------------------------------------------------------------
__global__ __launch_bounds__(256) void xpose_k(const bf16* __restrict__ in,
                                               bf16* __restrict__ out) {
    __shared__ bf16 tl[64][72];
    int t0 = blockIdx.x * 64;
    int by = blockIdx.y;                  // b*32 + h*2 + pg
    int pg = by & 1, h = (by >> 1) & 15, b = by >> 5;
    int p0 = pg * 64;
    int tx = threadIdx.x & 15, ty = threadIdx.x >> 4;
#pragma unroll
    for (int i = 0; i < 4; ++i) {
        ushort4 v = *(const ushort4*)&in[(size_t)(b * T_ + t0 + ty + 16 * i) * 2048
                                         + h * 128 + p0 + tx * 4];
        tl[ty + 16 * i][tx * 4 + 0] = *(bf16*)&v.x;
        tl[ty + 16 * i][tx * 4 + 1] = *(bf16*)&v.y;
        tl[ty + 16 * i][tx * 4 + 2] = *(bf16*)&v.z;
        tl[ty + 16 * i][tx * 4 + 3] = *(bf16*)&v.w;
    }
    __syncthreads();
#pragma unroll
    for (int i = 0; i < 4; ++i) {
        ushort4 v;
        v.x = *(unsigned short*)&tl[tx * 4 + 0][ty + 16 * i];
        v.y = *(unsigned short*)&tl[tx * 4 + 1][ty + 16 * i];
        v.z = *(unsigned short*)&tl[tx * 4 + 2][ty + 16 * i];
        v.w = *(unsigned short*)&tl[tx * 4 + 3][ty + 16 * i];
        *(ushort4*)&out[(size_t)((b * 16 + h) * 128 + p0 + ty + 16 * i) * 1024
                        + t0 + tx * 4] = v;
    }
}

// ---------------------------------------------------------------------------
// B transpose: bc [b*T][128] fp32 (cols 0..63 = B) -> bt16 [b*64+n][T] bf16
// ---------------------------------------------------------------------------
__global__ __launch_bounds__(256) void btpose_k(const float* __restrict__ in,
                                                bf16* __restrict__ out) {
    __shared__ bf16 tl[64][72];
    int t0 = blockIdx.x * 64;
    int b = blockIdx.y;
    int tx = threadIdx.x & 15, ty = threadIdx.x >> 4;
#pragma unroll
    for (int i = 0; i < 4; ++i) {
        float4 v = *(const float4*)&in[(size_t)(b * T_ + t0 + ty + 16 * i) * 128 + tx * 4];
        tl[ty + 16 * i][tx * 4 + 0] = __float2bfloat16(v.x);
        tl[ty + 16 * i][tx * 4 + 1] = __float2bfloat16(v.y);
        tl[ty + 16 * i][tx * 4 + 2] = __float2bfloat16(v.z);
        tl[ty + 16 * i][tx * 4 + 3] = __float2bfloat16(v.w);
    }
    __syncthreads();
#pragma unroll
    for (int i = 0; i < 4; ++i) {
        ushort4 v;
        v.x = *(unsigned short*)&tl[tx * 4 + 0][ty + 16 * i];
        v.y = *(unsigned short*)&tl[tx * 4 + 1][ty + 16 * i];
        v.z = *(unsigned short*)&tl[tx * 4 + 2][ty + 16 * i];
        v.w = *(unsigned short*)&tl[tx * 4 + 3][ty + 16 * i];
        *(ushort4*)&out[(size_t)(b * 64 + ty + 16 * i) * 1024 + t0 + tx * 4] = v;
    }
}

// ---------------------------------------------------------------------------
// Chunked scan via MFMA (Mamba2 matmul form). One wave per (b,h,ci).
//   G = C @ B^T                               [64t x 64s]  (K=64n)
//   P[t][s] = G * gma_t * wco_s * (s<=t)      -> LDS bf16, XOR-swizzled
//   Y[t][p] = P @ X^T_rows + D*x              (K=64s; kq pruned by causality)
//   SfinT[p][n] = X^T @ (w2 . B)^T            (K=64s), w2 = gma63*wco
// sfin layout: [wid][p*64+n] (element-wise combine is layout-agnostic).
// ---------------------------------------------------------------------------
__global__ __launch_bounds__(256) void scan_mm_k(const float* __restrict__ bc,
                                                 const bf16* __restrict__ xt,
                                                 const bf16* __restrict__ btb,
                                                 const float* __restrict__ wco,
                                                 const float* __restrict__ gma,
                                                 const float* __restrict__ dvec,
                                                 const bf16* __restrict__ xs,
                                                 bf16* __restrict__ yout,
                                                 bf16* __restrict__ sfin) {
    __shared__ __align__(64) char plds[4][8192];
    const int wv = threadIdx.x >> 6, lane = threadIdx.x & 63;
    const int l16 = lane & 15, quad = lane >> 4;
    const int wid = blockIdx.x * 4 + wv;
    const int ci = wid & (NC - 1), h = (wid >> 4) & (H_ - 1), b = wid >> 8;
    const int bt0 = b * T_ + ci * TC;
    char* Pb = plds[wv];

    float wl = wco[(size_t)(bt0 + lane) * H_ + h];
    float gl = gma[(size_t)(bt0 + lane) * H_ + h];
    float g63 = __shfl(gl, 63);
    float Dv = dvec[h];

    float wsv[4], gmv[4][4];
#pragma unroll
    for (int s4 = 0; s4 < 4; ++s4) wsv[s4] = __shfl(wl, s4 * 16 + l16);
#pragma unroll
    for (int t4 = 0; t4 < 4; ++t4)
#pragma unroll
        for (int i = 0; i < 4; ++i) gmv[t4][i] = __shfl(gl, t4 * 16 + quad * 4 + i);

    // ---- G = C @ B^T ----
    fv4 g[4][4] = {};
#pragma unroll
    for (int kq = 0; kq < 2; ++kq) {
        bfv8 cf[4], bfr[4];
#pragma unroll
        for (int i = 0; i < 4; ++i) {
            cf[i]  = cvt8f(&bc[(size_t)(bt0 + i * 16 + l16) * 128 + 64 + kq * 32 + quad * 8]);
            bfr[i] = cvt8f(&bc[(size_t)(bt0 + i * 16 + l16) * 128 + kq * 32 + quad * 8]);
        }
#pragma unroll
        for (int t4 = 0; t4 < 4; ++t4)
#pragma unroll
            for (int s4 = 0; s4 < 4; ++s4)
                g[t4][s4] = MF(cf[t4], bfr[s4], g[t4][s4]);
    }

    // ---- P -> LDS (decay, causal mask, swizzled) ----
#pragma unroll
    for (int t4 = 0; t4 < 4; ++t4)
#pragma unroll
        for (int s4 = 0; s4 < 4; ++s4)
#pragma unroll
            for (int i = 0; i < 4; ++i) {
                int t = t4 * 16 + quad * 4 + i, s = s4 * 16 + l16;
                float pv = (s <= t) ? g[t4][s4][i] * gmv[t4][i] * wsv[s4] : 0.f;
                int slot = (s >> 3) ^ (t & 7);
                *(__bf16*)(Pb + t * 128 + slot * 16 + (s & 7) * 2) = f2b(pv);
            }

    // ---- load X^T fragments (shared by PV and Sfin) ----
    bfv8 xf[8][2];
    const bf16* xtp = xt + (size_t)((b * 16 + h) * 128) * 1024 + ci * 64;
#pragma unroll
    for (int p4 = 0; p4 < 8; ++p4)
#pragma unroll
        for (int kq = 0; kq < 2; ++kq)
            xf[p4][kq] = *(const bfv8*)&xtp[(size_t)(p4 * 16 + l16) * 1024 + kq * 32 + quad * 8];

    // ---- Y = P @ X (causality-pruned kq) ----
    fv4 y[4][8] = {};
#pragma unroll
    for (int t4 = 0; t4 < 4; ++t4) {
#pragma unroll
        for (int kq = 0; kq < ((t4 < 2) ? 1 : 2); ++kq) {
            int rr = t4 * 16 + l16;
            bfv8 pf = *(const bfv8*)(Pb + rr * 128 + (((kq * 4 + quad) ^ (rr & 7)) << 4));
#pragma unroll
            for (int p4 = 0; p4 < 8; ++p4)
                y[t4][p4] = MF(pf, xf[p4][kq], y[t4][p4]);
        }
    }

    // ---- write yout (+ exact D*x) ----
    bf16* yp = yout + (size_t)bt0 * I_ + h * P_;
    const bf16* xp = xs + (size_t)bt0 * I_ + h * P_;
#pragma unroll
    for (int t4 = 0; t4 < 4; ++t4)
#pragma unroll
        for (int p4 = 0; p4 < 8; ++p4)
#pragma unroll
            for (int i = 0; i < 4; ++i) {
                size_t a = (size_t)(t4 * 16 + quad * 4 + i) * I_ + p4 * 16 + l16;
                float xv = __bfloat162float(xp[a]);
                yp[a] = __float2bfloat16(y[t4][p4][i] + Dv * xv);
            }

    // ---- SfinT[p][n] = X^T @ (w2 . B)^T ----
    float ws8[2][8];
#pragma unroll
    for (int kq = 0; kq < 2; ++kq)
#pragma unroll
        for (int j = 0; j < 8; ++j)
            ws8[kq][j] = g63 * __shfl(wl, kq * 32 + quad * 8 + j);

    fv4 sa[8][4] = {};
    const bf16* btp = btb + (size_t)b * 64 * 1024 + ci * 64;
#pragma unroll
    for (int kq = 0; kq < 2; ++kq) {
        bfv8 sbv[4];
#pragma unroll
        for (int n4 = 0; n4 < 4; ++n4) {
            bfv8 raw = *(const bfv8*)&btp[(size_t)(n4 * 16 + l16) * 1024 + kq * 32 + quad * 8];
            bfv8 sb;
#pragma unroll
            for (int j = 0; j < 8; ++j) sb[j] = f2b(bb2f(raw[j]) * ws8[kq][j]);
            sbv[n4] = sb;
        }
#pragma unroll
        for (int p4 = 0; p4 < 8; ++p4)
#pragma unroll
            for (int n4 = 0; n4 < 4; ++n4)
                sa[p4][n4] = MF(xf[p4][kq], sbv[n4], sa[p4][n4]);
    }

    bf16* sp = sfin + (size_t)wid * (128 * 64);
#pragma unroll
    for (int p4 = 0; p4 < 8; ++p4)
#pragma unroll
        for (int n4 = 0; n4 < 4; ++n4)
#pragma unroll
            for (int i = 0; i < 4; ++i)
                sp[(p4 * 16 + quad * 4 + i) * 64 + n4 * 16 + l16] =
                    __float2bfloat16(sa[p4][n4][i]);
}

// ---------------------------------------------------------------------------
// Pass B: chunk combine — element-wise in state index, layout-agnostic.
// ---------------------------------------------------------------------------
__global__ __launch_bounds__(128) void scan_combine_k(bf16* __restrict__ sbuf,
                                                      const float* __restrict__ gma) {
    int bid = blockIdx.x;                   // b*H*64 + h*64 + q
    int n = bid & 63;
    int h = (bid >> 6) & (H_ - 1);
    int b = bid >> 10;
    int p = threadIdx.x;
    size_t base0 = ((size_t)(b * (H_ * NC) + h * NC) * (128 * 64)) + n * 128 + p;
    int gbase = b * T_ * H_ + h;
    float S = 0.f;
#pragma unroll
    for (int ci = 0; ci < NC; ++ci) {
        bf16* addr = sbuf + base0 + (size_t)ci * (128 * 64);
        float tmp = __bfloat162float(*addr);            // S_fin of chunk ci
        *addr = __float2bfloat16(S);                    // S_init of chunk ci
        float G = gma[gbase + (ci * TC + TC - 1) * H_]; // uniform per block
        S = fmaf(G, S, tmp);
    }
}

// ---------------------------------------------------------------------------
// Pass C via MFMA: y[t][p] += gma_t * (C @ S_init)[t][p]
// ---------------------------------------------------------------------------
__global__ __launch_bounds__(256) void scan_corr_k(const float* __restrict__ bc,
                                                   const bf16* __restrict__ sfin,
                                                   const float* __restrict__ gma,
                                                   bf16* __restrict__ yout) {
    const int wv = threadIdx.x >> 6, lane = threadIdx.x & 63;
    const int wid = blockIdx.x * 4 + wv;
    const int ci = wid & (NC - 1), h = (wid >> 4) & (H_ - 1), b = wid >> 8;
    if (ci == 0) return;
    const int l16 = lane & 15, quad = lane >> 4;
    const int bt0 = b * T_ + ci * TC;

    float gl = gma[(size_t)(bt0 + lane) * H_ + h];
    float gmv[4][4];
#pragma unroll
    for (int t4 = 0; t4 < 4; ++t4)
#pragma unroll
        for (int i = 0; i < 4; ++i) gmv[t4][i] = __shfl(gl, t4 * 16 + quad * 4 + i);

    const bf16* sp = sfin + (size_t)wid * (128 * 64);
    fv4 z[4][8] = {};
#pragma unroll
    for (int kq = 0; kq < 2; ++kq) {
        bfv8 cf[4];
#pragma unroll
        for (int i = 0; i < 4; ++i)
            cf[i] = cvt8f(&bc[(size_t)(bt0 + i * 16 + l16) * 128 + 64 + kq * 32 + quad * 8]);
#pragma unroll
        for (int p4 = 0; p4 < 8; ++p4) {
            bfv8 sf = *(const bfv8*)&sp[(p4 * 16 + l16) * 64 + kq * 32 + quad * 8];
#pragma unroll
            for (int t4 = 0; t4 < 4; ++t4)
                z[t4][p4] = MF(cf[t4], sf, z[t4][p4]);
        }
    }

    bf16* yp = yout + (size_t)bt0 * I_ + h * P_;
#pragma unroll
    for (int t4 = 0; t4 < 4; ++t4)
#pragma unroll
        for (int i = 0; i < 4; ++i) {
            float gm = gmv[t4][i];
#pragma unroll
            for (int p4 = 0; p4 < 8; ++p4) {
                size_t a = (size_t)(t4 * 16 + quad * 4 + i) * I_ + p4 * 16 + l16;
                float yv = __bfloat162float(yp[a]);
                yp[a] = __float2bfloat16(yv + gm * z[t4][p4][i]);
            }
        }
}

// ---------------------------------------------------------------------------
__global__ __launch_bounds__(256) void cast_f2b_k(const float* __restrict__ in,
                                                  bf16* __restrict__ out) {
    int i = (blockIdx.x * 256 + threadIdx.x) * 4;
    float4 v = *(const float4*)&in[i];
    bf16 ov[4] = {__float2bfloat16(v.x), __float2bfloat16(v.y),
                  __float2bfloat16(v.z), __float2bfloat16(v.w)};
    *(uint2*)&out[i] = *(uint2*)ov;
}

// ---------------------------------------------------------------------------

static inline size_t align256(size_t x) { return (x + 255) & ~(size_t)255; }

extern "C" void kernel_launch(void* const* d_in, const int* in_sizes, int n_in,
                              void* d_out, int out_size, void* d_ws, size_t ws_size,
                              hipStream_t stream) {
    const float* x_in     = (const float*)d_in[0];
    const float* in_w     = (const float*)d_in[1];
    const float* in_b     = (const float*)d_in[2];
    const float* norm_w   = (const float*)d_in[3];
    const float* mix_in_w = (const float*)d_in[4];
    const float* conv_w   = (const float*)d_in[5];
    const float* conv_b   = (const float*)d_in[6];
    const float* dt_bias  = (const float*)d_in[7];
    const float* A_log    = (const float*)d_in[8];
    const float* Dvec     = (const float*)d_in[9];
    const float* gnorm_w  = (const float*)d_in[10];
    const float* mix_out_w= (const float*)d_in[11];
    const float* out_w    = (const float*)d_in[12];
    const float* out_b    = (const float*)d_in[13];
    const float* code_w   = (const float*)d_in[14];
    const float* code_b   = (const float*)d_in[15];
    float* outF0 = (float*)d_out;                       // [8192][512]
    float* outF1 = (float*)d_out + (size_t)M_ * OUT_;   // [8192][1024]

    char* p = (char*)d_ws;
    auto alloc = [&](size_t bytes) -> char* { char* r = p; p += align256(bytes); return r; };

    // xt region; hn and xb alias its low part (liveness disjoint: xb dead after
    // first GEMM; hn dead after each proj GEMM; xt lives only xpose->scan_mm).
    bf16*  xt       = (bf16*)alloc((size_t)B_ * H_ * 128 * T_ * 2);     // 33.5 MiB
    bf16*  hn       = xt;                                 // [M][D] bf16 (16.8 MiB)
    bf16*  xb       = xt + (size_t)M_ * D_;               // [M][INP] bf16 (8.4 MiB)
    bf16*  v_inb    = (bf16*)alloc(D_ * 2);
    bf16*  v_normw  = (bf16*)alloc(L_ * D_ * 2);
    bf16*  v_convw  = (bf16*)alloc(L_ * 3 * CONV_DIM * 2);
    bf16*  v_convb  = (bf16*)alloc(L_ * CONV_DIM * 2);
    bf16*  v_gnw    = (bf16*)alloc(L_ * I_ * 2);
    bf16*  v_outb   = (bf16*)alloc(OUT_ * 2);
    bf16*  v_codeb  = (bf16*)alloc(CB_ * 2);
    bf16*  wt_in    = (bf16*)alloc((size_t)1024 * 512 * 2);
    bf16*  wt_big   = (bf16*)alloc((size_t)4352 * 1024 * 2);   // per-layer reuse
    bf16*  wt_small = (bf16*)alloc((size_t)1024 * 2048 * 2);   // per-layer reuse
    bf16*  wt_out   = (bf16*)alloc((size_t)512 * 1024 * 2);
    bf16*  wt_code  = (bf16*)alloc((size_t)1024 * 1024 * 2);
    float* hbuf     = (float*)alloc((size_t)M_ * D_ * 4);      // residual fp32
    bf16*  gate     = (bf16*)alloc((size_t)M_ * I_ * 2);
    bf16*  hbc      = (bf16*)alloc((size_t)M_ * CONV_DIM * 2); // conv in; reused as yscan
    float* dtraw    = (float*)alloc((size_t)M_ * H_ * 4);
    bf16*  xs       = (bf16*)alloc((size_t)M_ * I_ * 2);
    float* bcbuf    = (float*)alloc((size_t)M_ * 128 * 4);     // B | C
    float* wcob     = (float*)alloc((size_t)M_ * H_ * 4);
    float* gmab     = (float*)alloc((size_t)M_ * H_ * 4);
    bf16*  sfin     = (bf16*)alloc((size_t)B_ * H_ * NC * 128 * 64 * 2); // 33.5 MiB
    bf16*  bt16     = (bf16*)alloc((size_t)B_ * 64 * T_ * 2);           // 1 MiB
    (void)in_sizes; (void)n_in; (void)out_size;

    size_t needed = (size_t)(p - (char*)d_ws);
    if (needed > ws_size) return;   // diagnostic: absmax reads max|ref| (zeros)

    constexpr size_t SH_PROJ = 73728;   // RING3 x (256+128)x32 bf16 -> 2 blk/CU
    constexpr size_t SH_SQ   = 49152;   // RING3 x (128+128)x32 bf16 -> 3 blk/CU
    static bool attr_done = false;
    if (!attr_done) {
        attr_done = true;
        (void)hipFuncSetAttribute((const void*)gemm8p<1, 256, 128, 4, 2, 3, 512>,
                                  hipFuncAttributeMaxDynamicSharedMemorySize, (int)SH_PROJ);
        (void)hipFuncSetAttribute((const void*)gemm8p<0, 128, 128, 2, 2, 3, 256>,
                                  hipFuncAttributeMaxDynamicSharedMemorySize, (int)SH_SQ);
        (void)hipFuncSetAttribute((const void*)gemm8p<2, 128, 128, 2, 2, 3, 256>,
                                  hipFuncAttributeMaxDynamicSharedMemorySize, (int)SH_SQ);
    }

    auto ing = [&](const float* src, bf16* dst, int n) {
        ingest_k<<<(n + 255) / 256, 256, 0, stream>>>(src, dst, n);
    };
    ing(x_in, xb, M_ * INP);
    ing(in_b, v_inb, D_);
    ing(norm_w, v_normw, L_ * D_);
    ing(conv_w, v_convw, L_ * 3 * CONV_DIM);
    ing(conv_b, v_convb, L_ * CONV_DIM);
    ing(gnorm_w, v_gnw, L_ * I_);
    ing(out_b, v_outb, OUT_);
    ing(code_b, v_codeb, CB_);

    dim3 tb(32, 8);
    transpose_any<<<dim3(32, 16), tb, 0, stream>>>(in_w, 0, wt_in, 512, 1024);
    transpose_any<<<dim3(16, 32), tb, 0, stream>>>(out_w, 0, wt_out, 1024, 512);
    transpose_any<<<dim3(32, 32), tb, 0, stream>>>(code_w, 0, wt_code, 1024, 1024);

    // h = x @ in_w + in_b     (M=8192, K=512, N=1024)
    gemm8p<0, 128, 128, 2, 2, 3, 256><<<dim3(8, 64), 256, SH_SQ, stream>>>(
        xb, wt_in, INP, D_, v_inb, hbuf, nullptr, nullptr, nullptr);

    for (int i = 0; i < L_; ++i) {
        transpose_any<<<dim3(136, 32), tb, 0, stream>>>(mix_in_w, (size_t)i * 1024 * PROJ,
                                                        wt_big, 1024, PROJ);
        transpose_any<<<dim3(32, 64), tb, 0, stream>>>(mix_out_w, (size_t)i * 2048 * 1024,
                                                       wt_small, 2048, 1024);
        rmsnorm_k<<<M_, 256, 0, stream>>>(hbuf, v_normw + i * D_, hn);
        // proj: M=8192, K=1024, N=4352(pad)
        gemm8p<1, 256, 128, 4, 2, 3, 512><<<dim3(34, 32), 512, SH_PROJ, stream>>>(
            hn, wt_big, D_, 4352, nullptr, nullptr, gate, hbc, dtraw);
        conv_k<<<dim3(3, M_), 256, 0, stream>>>(hbc, v_convw + i * 3 * CONV_DIM,
                                                v_convb + i * CONV_DIM, xs, bcbuf);
        dtprep_k<<<B_ * NC * H_ / 4, 256, 0, stream>>>(
            dtraw, dt_bias + i * H_, A_log + i * H_, wcob, gmab);
        xpose_k<<<dim3(16, 256), 256, 0, stream>>>(xs, xt);
        btpose_k<<<dim3(16, 8), 256, 0, stream>>>(bcbuf, bt16);
        scan_mm_k<<<512, 256, 0, stream>>>(bcbuf, xt, bt16, wcob, gmab,
                                           Dvec + i * H_, xs, hbc, sfin);
        scan_combine_k<<<B_ * H_ * 64, 128, 0, stream>>>(sfin, gmab);
        scan_corr_k<<<512, 256, 0, stream>>>(bcbuf, sfin, gmab, hbc);
        gatednorm_k<<<M_, 256, 0, stream>>>(hbc, gate, v_gnw + i * I_, xs);
        // out proj: M=8192, K=2048, N=1024
        gemm8p<2, 128, 128, 2, 2, 3, 256><<<dim3(8, 64), 256, SH_SQ, stream>>>(
            xs, wt_small, I_, D_, nullptr, hbuf, nullptr, nullptr, nullptr);
    }

    // heads -> fp32 d_out
    cast_f2b_k<<<(M_ * D_) / 1024, 256, 0, stream>>>(hbuf, hn);
    gemm8p<0, 128, 128, 2, 2, 3, 256><<<dim3(4, 64), 256, SH_SQ, stream>>>(
        hn, wt_out, D_, OUT_, v_outb, outF0, nullptr, nullptr, nullptr);
    gemm8p<0, 128, 128, 2, 2, 3, 256><<<dim3(8, 64), 256, SH_SQ, stream>>>(
        hn, wt_code, D_, CB_, v_codeb, outF1, nullptr, nullptr, nullptr);
}

// Round 6
// 1623.713 us; speedup vs baseline: 1.3654x; 1.0144x over previous
//
#include <hip/hip_runtime.h>
#include <hip/hip_bf16.h>

typedef __hip_bfloat16 bf16;
typedef __bf16 bfv8 __attribute__((ext_vector_type(8)));
typedef float fv4 __attribute__((ext_vector_type(4)));

#define B_  8
#define T_  1024
#define INP 512
#define D_  1024
#define I_  2048
#define N_  64
#define H_  16
#define P_  128
#define L_  4
#define OUT_ 512
#define CB_ 1024
#define CONV_DIM 2176
#define PROJ 4240
#define M_  (B_*T_)       // 8192 rows
#define TC  64            // scan chunk length
#define NC  (T_/TC)       // 16 chunks

typedef const __attribute__((address_space(1))) void gv_t;
typedef __attribute__((address_space(3))) void lv_t;

__device__ __forceinline__ void load_lds16(const bf16* g, char* l) {
    __builtin_amdgcn_global_load_lds((gv_t*)g, (lv_t*)l, 16, 0, 0);
}

template <int N> __device__ __forceinline__ void wait_vm() {
    if constexpr (N == 0)      asm volatile("s_waitcnt vmcnt(0)" ::: "memory");
    else if constexpr (N == 2) asm volatile("s_waitcnt vmcnt(2)" ::: "memory");
    else if constexpr (N == 3) asm volatile("s_waitcnt vmcnt(3)" ::: "memory");
    else if constexpr (N == 4) asm volatile("s_waitcnt vmcnt(4)" ::: "memory");
    else if constexpr (N == 6) asm volatile("s_waitcnt vmcnt(6)" ::: "memory");
    else                       asm volatile("s_waitcnt vmcnt(8)" ::: "memory");
}
__device__ __forceinline__ void barrier_sync() {
    asm volatile("s_barrier" ::: "memory");
}

__device__ __forceinline__ fv4 MF(bfv8 a, bfv8 b, fv4 c) {
    return __builtin_amdgcn_mfma_f32_16x16x32_bf16(a, b, c, 0, 0, 0);
}
__device__ __forceinline__ __bf16 f2b(float x) {
    __hip_bfloat16 h = __float2bfloat16(x);
    union { unsigned short u; __bf16 b; } t;
    t.u = *reinterpret_cast<unsigned short*>(&h);
    return t.b;
}
__device__ __forceinline__ float bb2f(__bf16 x) {
    union { __bf16 b; unsigned short u; } t; t.b = x;
    union { unsigned int u; float f; } r; r.u = (unsigned int)t.u << 16;
    return r.f;
}
__device__ __forceinline__ bfv8 cvt8f(const float* p) {
    float4 a = *(const float4*)p, b = *(const float4*)(p + 4);
    bfv8 r;
    r[0] = f2b(a.x); r[1] = f2b(a.y); r[2] = f2b(a.z); r[3] = f2b(a.w);
    r[4] = f2b(b.x); r[5] = f2b(b.y); r[6] = f2b(b.z); r[7] = f2b(b.w);
    return r;
}

// ---------------------------------------------------------------------------
// fp32 -> bf16 copy
// ---------------------------------------------------------------------------
__global__ __launch_bounds__(256) void ingest_k(const float* __restrict__ src,
                                                bf16* __restrict__ dst, int n) {
    int i = blockIdx.x * 256 + threadIdx.x;
    if (i >= n) return;
    dst[i] = __float2bfloat16(src[i]);
}

// ---------------------------------------------------------------------------
// Transpose fp32 [R][C] -> bf16 [Cp][R], zero-padding rows C..Cp.
// ---------------------------------------------------------------------------
__global__ __launch_bounds__(256) void transpose_any(const float* __restrict__ in,
                                                     size_t off,
                                                     bf16* __restrict__ out,
                                                     int R, int C) {
    __shared__ bf16 tile[32][33];
    int c0 = blockIdx.x * 32, r0 = blockIdx.y * 32;
    int tx = threadIdx.x, ty = threadIdx.y;
#pragma unroll
    for (int i = 0; i < 4; ++i) {
        int r = r0 + ty + i * 8, c = c0 + tx;
        bf16 v = __float2bfloat16(0.f);
        if (c < C) v = __float2bfloat16(in[off + (size_t)r * C + c]);
        tile[ty + i * 8][tx] = v;
    }
    __syncthreads();
#pragma unroll
    for (int i = 0; i < 4; ++i) {
        int c = c0 + ty + i * 8;
        out[(size_t)c * R + r0 + tx] = tile[tx][ty + i * 8];
    }
}

// ---------------------------------------------------------------------------
// GEMM, half-tile ring pipeline.
// MODE 0: outF = acc + bias         MODE 1: split gate/hBC/dt
// MODE 2: outF += acc               MODE 3: heads, col-split fp32 + bias
// ---------------------------------------------------------------------------
template <int MODE, int BM, int BN, int WGM, int WGN, int RING, int NTHR>
__global__ __launch_bounds__(NTHR) void gemm8p(const bf16* __restrict__ A,
                                               const bf16* __restrict__ Bt,
                                               int K, int N,
                                               const bf16* __restrict__ bias,
                                               float* __restrict__ outF,
                                               bf16* __restrict__ outB,
                                               bf16* __restrict__ outB2,
                                               float* __restrict__ outF2) {
    constexpr int HK = 32;
    constexpr int MT = BM / WGM / 16;
    constexpr int NT = BN / WGN / 16;
    constexpr int ABY = BM * HK * 2;
    constexpr int BBY = BN * HK * 2;
    constexpr int BUF = ABY + BBY;
    constexpr int RPI = NTHR / 4;
    constexpr int AL = BM / RPI;
    constexpr int BL = BN / RPI;
    constexpr int LD = AL + BL;
    constexpr int IB = NTHR * 16;

    extern __shared__ char lds[];
    const int tid = threadIdx.x;
    const int wv = tid >> 6, lane = tid & 63;
    const int l16 = lane & 15, quad = lane >> 4;
    const int wm = (wv / WGN) * (BM / WGM);
    const int wn = (wv % WGN) * (BN / WGN);

    const int NX = gridDim.x;
    const int nwg = NX * gridDim.y;
    const int orig = blockIdx.y * NX + blockIdx.x;
    const int q = nwg >> 3, r = nwg & 7, xcd = orig & 7, lid = orig >> 3;
    const int wg = (xcd < r ? xcd * (q + 1) : r * (q + 1) + (xcd - r) * q) + lid;
    const int m0 = (wg / NX) * BM;
    const int n0 = (wg % NX) * BN;

    const int srow = tid >> 2, sslot = tid & 3;
    const int swz = (sslot ^ ((srow >> 1) & 3)) << 3;
    const bf16* ga = A  + (size_t)(m0 + srow) * K + swz;
    const bf16* gb = Bt + (size_t)(n0 + srow) * K + swz;
    char* lw = lds + wv * 1024;

    const int HT = K / HK;

    auto stageA = [&](int stg, int rbuf) {
#pragma unroll
        for (int j = 0; j < AL; ++j)
            load_lds16(ga + (size_t)stg * HK + (size_t)(j * RPI) * K,
                       lw + rbuf * BUF + j * IB);
    };
    auto stageB = [&](int stg, int rbuf) {
#pragma unroll
        for (int j = 0; j < BL; ++j)
            load_lds16(gb + (size_t)stg * HK + (size_t)(j * RPI) * K,
                       lw + rbuf * BUF + ABY + j * IB);
    };

#pragma unroll
    for (int h = 0; h < RING - 1; ++h) { stageA(h, h); stageB(h, h); }
    wait_vm<LD>();
    barrier_sync();

    fv4 acc[MT][NT] = {};
    int rb = 0;
    for (int ht = 0; ht < HT; ++ht) {
        const char* Ab = lds + rb * BUF;
        const char* Bb = Ab + ABY;
        const int stg = ht + RING - 1;
        const int sb = (rb == 0) ? RING - 1 : rb - 1;
        const bool dostage = stg < HT;

        bfv8 bf[NT], af[MT];
#pragma unroll
        for (int i = 0; i < NT; ++i) {
            int rr = wn + i * 16 + l16;
            bf[i] = *(const bfv8*)(Bb + rr * 64 + ((quad ^ ((rr >> 1) & 3)) << 4));
        }
#pragma unroll
        for (int i = 0; i < MT; ++i) {
            int rr = wm + i * 16 + l16;
            af[i] = *(const bfv8*)(Ab + rr * 64 + ((quad ^ ((rr >> 1) & 3)) << 4));
        }
        if (dostage) { stageA(stg, sb); stageB(stg, sb); }
        __builtin_amdgcn_s_setprio(1);
#pragma unroll
        for (int mt = 0; mt < MT; ++mt)
#pragma unroll
            for (int nt = 0; nt < NT; ++nt)
                acc[mt][nt] = MF(af[mt], bf[nt], acc[mt][nt]);
        __builtin_amdgcn_s_setprio(0);

        int fut = HT - 1 - ht; if (fut > RING - 1) fut = RING - 1;
        if (fut >= 1) {
            int w = (fut - 1) * LD;
            if (w >= LD) wait_vm<LD>();
            else wait_vm<0>();
        }
        barrier_sync();
        rb = (rb + 1 == RING) ? 0 : rb + 1;
    }

#pragma unroll
    for (int mt = 0; mt < MT; ++mt) {
#pragma unroll
        for (int nt = 0; nt < NT; ++nt) {
#pragma unroll
            for (int i = 0; i < 4; ++i) {
                int row = m0 + wm + mt * 16 + quad * 4 + i;
                int col = n0 + wn + nt * 16 + l16;
                float v = acc[mt][nt][i];
                if (MODE == 0) {
                    v += __bfloat162float(bias[col]);
                    outF[(size_t)row * N + col] = v;
                } else if (MODE == 1) {
                    if (col < I_)
                        outB[(size_t)row * I_ + col] = __float2bfloat16(v);
                    else if (col < I_ + CONV_DIM)
                        outB2[(size_t)row * CONV_DIM + (col - I_)] = __float2bfloat16(v);
                    else if (col < PROJ)
                        outF2[(size_t)row * H_ + (col - (I_ + CONV_DIM))] = v;
                } else if (MODE == 2) {
                    outF[(size_t)row * N + col] += v;
                } else if (MODE == 3) {
                    v += __bfloat162float(bias[col]);
                    if (col < OUT_) outF[(size_t)row * OUT_ + col] = v;
                    else            outF2[(size_t)row * CB_ + (col - OUT_)] = v;
                }
            }
        }
    }
}

// ---------------------------------------------------------------------------
__global__ __launch_bounds__(256) void rmsnorm_k(const float* __restrict__ x,
                                                 const bf16* __restrict__ w,
                                                 bf16* __restrict__ out) {
    int row = blockIdx.x, tid = threadIdx.x;
    float4 v = *(const float4*)&x[(size_t)row * D_ + tid * 4];
    float ss = v.x * v.x + v.y * v.y + v.z * v.z + v.w * v.w;
#pragma unroll
    for (int off = 32; off; off >>= 1) ss += __shfl_down(ss, off);
    __shared__ float sb[4];
    if ((tid & 63) == 0) sb[tid >> 6] = ss;
    __syncthreads();
    ss = sb[0] + sb[1] + sb[2] + sb[3];
    float rs = rsqrtf(ss * (1.f / D_) + 1e-6f);
    float xv[4] = {v.x, v.y, v.z, v.w};
#pragma unroll
    for (int j = 0; j < 4; ++j)
        out[(size_t)row * D_ + tid * 4 + j] =
            __float2bfloat16(xv[j] * rs * __bfloat162float(w[tid * 4 + j]));
}

// ---------------------------------------------------------------------------
__global__ __launch_bounds__(256) void gatednorm_k(const bf16* __restrict__ y,
                                                   const bf16* __restrict__ g,
                                                   const bf16* __restrict__ w,
                                                   bf16* __restrict__ out) {
    int row = blockIdx.x, tid = threadIdx.x;
    size_t base = (size_t)row * I_ + tid * 8;
    bf16 yv[8], gv[8];
    *(uint4*)yv = *(const uint4*)&y[base];
    *(uint4*)gv = *(const uint4*)&g[base];
    float vv[8]; float ss = 0.f;
#pragma unroll
    for (int j = 0; j < 8; ++j) {
        float yf = __bfloat162float(yv[j]);
        float gf = __bfloat162float(gv[j]);
        float sig = 1.f / (1.f + expf(-gf));
        vv[j] = yf * gf * sig;
        ss += vv[j] * vv[j];
    }
#pragma unroll
    for (int off = 32; off; off >>= 1) ss += __shfl_down(ss, off);
    __shared__ float sb[4];
    if ((tid & 63) == 0) sb[tid >> 6] = ss;
    __syncthreads();
    ss = sb[0] + sb[1] + sb[2] + sb[3];
    float rs = rsqrtf(ss * (1.f / I_) + 1e-6f);
    bf16 ov[8];
#pragma unroll
    for (int j = 0; j < 8; ++j)
        ov[j] = __float2bfloat16(vv[j] * rs * __bfloat162float(w[tid * 8 + j]));
    *(uint4*)&out[base] = *(uint4*)ov;
}

// ---------------------------------------------------------------------------
// conv: vectorized uint2 taps (4 bf16/thread), uint2/float4 stores.
// ---------------------------------------------------------------------------
__global__ __launch_bounds__(256) void conv_k(const bf16* __restrict__ hbc,
                                              const bf16* __restrict__ w,
                                              const bf16* __restrict__ bias,
                                              bf16* __restrict__ xs,
                                              float* __restrict__ bc) {
    int cq = blockIdx.x * 256 + threadIdx.x;
    if (cq >= CONV_DIM / 4) return;
    int c = cq * 4;
    int bt = blockIdx.y;
    int t = bt & (T_ - 1);
    bf16 bv[4]; *(uint2*)bv = *(const uint2*)&bias[c];
    float acc[4];
#pragma unroll
    for (int j = 0; j < 4; ++j) acc[j] = __bfloat162float(bv[j]);
#pragma unroll
    for (int k = 0; k < 3; ++k) {
        if (t - 2 + k < 0) continue;
        bf16 wv[4], sv[4];
        *(uint2*)wv = *(const uint2*)&w[k * CONV_DIM + c];
        *(uint2*)sv = *(const uint2*)&hbc[(size_t)(bt - 2 + k) * CONV_DIM + c];
#pragma unroll
        for (int j = 0; j < 4; ++j)
            acc[j] = fmaf(__bfloat162float(wv[j]), __bfloat162float(sv[j]), acc[j]);
    }
#pragma unroll
    for (int j = 0; j < 4; ++j) acc[j] = acc[j] / (1.f + expf(-acc[j]));   // silu
    if (c < I_) {
        bf16 ov[4];
#pragma unroll
        for (int j = 0; j < 4; ++j) ov[j] = __float2bfloat16(acc[j]);
        *(uint2*)&xs[(size_t)bt * I_ + c] = *(uint2*)ov;
    } else {
        float4 o; o.x = acc[0]; o.y = acc[1]; o.z = acc[2]; o.w = acc[3];
        *(float4*)&bc[(size_t)bt * 128 + (c - I_)] = o;
    }
}

// ---------------------------------------------------------------------------
// dt prep, wave-parallel prefix scan.
// ---------------------------------------------------------------------------
__global__ __launch_bounds__(256) void dtprep_k(const float* __restrict__ dtraw,
                                                const float* __restrict__ dtb,
                                                const float* __restrict__ alog,
                                                float* __restrict__ wco,
                                                float* __restrict__ gma) {
    int chain = blockIdx.x * 4 + (threadIdx.x >> 6);   // b*256 + ci*16 + h
    int s = threadIdx.x & 63;
    int h = chain & 15, ci = (chain >> 4) & (NC - 1), b = chain >> 8;
    float a = -expf(alog[h]);
    float bz = dtb[h];
    int idx = (b * T_ + ci * TC + s) * H_ + h;
    float z = dtraw[idx] + bz;
    float dt = fmaxf(z, 0.f) + log1pf(expf(-fabsf(z)));
    float ps = dt * a;
#pragma unroll
    for (int d = 1; d < 64; d <<= 1) {
        float o = __shfl_up(ps, d, 64);
        if (s >= d) ps += o;
    }
    float g = expf(ps);
    wco[idx] = dt / g;
    gma[idx] = g;
}

// ---------------------------------------------------------------------------
// X transpose: xs [b*T][h*128+p] bf16 -> xt [(b*16+h)*128+p][T] bf16
// ---------------------------------------------------------------------------
__global__ __launch_bounds__(256) void xpose_k(const bf16* __restrict__ in,
                                               bf16* __restrict__ out) {
    __shared__ bf16 tl[64][72];
    int t0 = blockIdx.x * 64;
    int by = blockIdx.y;                  // b*32 + h*2 + pg
    int pg = by & 1, h = (by >> 1) & 15, b = by >> 5;
    int p0 = pg * 64;
    int tx = threadIdx.x & 15, ty = threadIdx.x >> 4;
#pragma unroll
    for (int i = 0; i < 4; ++i) {
        ushort4 v = *(const ushort4*)&in[(size_t)(b * T_ + t0 + ty + 16 * i) * 2048
                                         + h * 128 + p0 + tx * 4];
        tl[ty + 16 * i][tx * 4 + 0] = *(bf16*)&v.x;
        tl[ty + 16 * i][tx * 4 + 1] = *(bf16*)&v.y;
        tl[ty + 16 * i][tx * 4 + 2] = *(bf16*)&v.z;
        tl[ty + 16 * i][tx * 4 + 3] = *(bf16*)&v.w;
    }
    __syncthreads();
#pragma unroll
    for (int i = 0; i < 4; ++i) {
        ushort4 v;
        v.x = *(unsigned short*)&tl[tx * 4 + 0][ty + 16 * i];
        v.y = *(unsigned short*)&tl[tx * 4 + 1][ty + 16 * i];
        v.z = *(unsigned short*)&tl[tx * 4 + 2][ty + 16 * i];
        v.w = *(unsigned short*)&tl[tx * 4 + 3][ty + 16 * i];
        *(ushort4*)&out[(size_t)((b * 16 + h) * 128 + p0 + ty + 16 * i) * 1024
                        + t0 + tx * 4] = v;
    }
}

// ---------------------------------------------------------------------------
// B transpose: bc [b*T][128] fp32 (cols 0..63 = B) -> bt16 [b*64+n][T] bf16
// ---------------------------------------------------------------------------
__global__ __launch_bounds__(256) void btpose_k(const float* __restrict__ in,
                                                bf16* __restrict__ out) {
    __shared__ bf16 tl[64][72];
    int t0 = blockIdx.x * 64;
    int b = blockIdx.y;
    int tx = threadIdx.x & 15, ty = threadIdx.x >> 4;
#pragma unroll
    for (int i = 0; i < 4; ++i) {
        float4 v = *(const float4*)&in[(size_t)(b * T_ + t0 + ty + 16 * i) * 128 + tx * 4];
        tl[ty + 16 * i][tx * 4 + 0] = __float2bfloat16(v.x);
        tl[ty + 16 * i][tx * 4 + 1] = __float2bfloat16(v.y);
        tl[ty + 16 * i][tx * 4 + 2] = __float2bfloat16(v.z);
        tl[ty + 16 * i][tx * 4 + 3] = __float2bfloat16(v.w);
    }
    __syncthreads();
#pragma unroll
    for (int i = 0; i < 4; ++i) {
        ushort4 v;
        v.x = *(unsigned short*)&tl[tx * 4 + 0][ty + 16 * i];
        v.y = *(unsigned short*)&tl[tx * 4 + 1][ty + 16 * i];
        v.z = *(unsigned short*)&tl[tx * 4 + 2][ty + 16 * i];
        v.w = *(unsigned short*)&tl[tx * 4 + 3][ty + 16 * i];
        *(ushort4*)&out[(size_t)(b * 64 + ty + 16 * i) * 1024 + t0 + tx * 4] = v;
    }
}

// ---------------------------------------------------------------------------
// Chunked scan via MFMA (Mamba2 matmul form). One wave per (b,h,ci).
// Y written per-t4 block to cap live accumulators at 8 fv4.
// ---------------------------------------------------------------------------
__global__ __launch_bounds__(256) void scan_mm_k(const float* __restrict__ bc,
                                                 const bf16* __restrict__ xt,
                                                 const bf16* __restrict__ btb,
                                                 const float* __restrict__ wco,
                                                 const float* __restrict__ gma,
                                                 const float* __restrict__ dvec,
                                                 const bf16* __restrict__ xs,
                                                 bf16* __restrict__ yout,
                                                 bf16* __restrict__ sfin) {
    __shared__ __align__(64) char plds[4][8192];
    const int wv = threadIdx.x >> 6, lane = threadIdx.x & 63;
    const int l16 = lane & 15, quad = lane >> 4;
    const int wid = blockIdx.x * 4 + wv;
    const int ci = wid & (NC - 1), h = (wid >> 4) & (H_ - 1), b = wid >> 8;
    const int bt0 = b * T_ + ci * TC;
    char* Pb = plds[wv];

    float wl = wco[(size_t)(bt0 + lane) * H_ + h];
    float gl = gma[(size_t)(bt0 + lane) * H_ + h];
    float g63 = __shfl(gl, 63);
    float Dv = dvec[h];

    float wsv[4], gmv[4][4];
#pragma unroll
    for (int s4 = 0; s4 < 4; ++s4) wsv[s4] = __shfl(wl, s4 * 16 + l16);
#pragma unroll
    for (int t4 = 0; t4 < 4; ++t4)
#pragma unroll
        for (int i = 0; i < 4; ++i) gmv[t4][i] = __shfl(gl, t4 * 16 + quad * 4 + i);

    // ---- G = C @ B^T ----
    fv4 g[4][4] = {};
#pragma unroll
    for (int kq = 0; kq < 2; ++kq) {
        bfv8 cf[4], bfr[4];
#pragma unroll
        for (int i = 0; i < 4; ++i) {
            cf[i]  = cvt8f(&bc[(size_t)(bt0 + i * 16 + l16) * 128 + 64 + kq * 32 + quad * 8]);
            bfr[i] = cvt8f(&bc[(size_t)(bt0 + i * 16 + l16) * 128 + kq * 32 + quad * 8]);
        }
#pragma unroll
        for (int t4 = 0; t4 < 4; ++t4)
#pragma unroll
            for (int s4 = 0; s4 < 4; ++s4)
                g[t4][s4] = MF(cf[t4], bfr[s4], g[t4][s4]);
    }

    // ---- P -> LDS (decay, causal mask, swizzled) ----
#pragma unroll
    for (int t4 = 0; t4 < 4; ++t4)
#pragma unroll
        for (int s4 = 0; s4 < 4; ++s4)
#pragma unroll
            for (int i = 0; i < 4; ++i) {
                int t = t4 * 16 + quad * 4 + i, s = s4 * 16 + l16;
                float pv = (s <= t) ? g[t4][s4][i] * gmv[t4][i] * wsv[s4] : 0.f;
                int slot = (s >> 3) ^ (t & 7);
                *(__bf16*)(Pb + t * 128 + slot * 16 + (s & 7) * 2) = f2b(pv);
            }

    // ---- load X^T fragments (shared by PV and Sfin) ----
    bfv8 xf[8][2];
    const bf16* xtp = xt + (size_t)((b * 16 + h) * 128) * 1024 + ci * 64;
#pragma unroll
    for (int p4 = 0; p4 < 8; ++p4)
#pragma unroll
        for (int kq = 0; kq < 2; ++kq)
            xf[p4][kq] = *(const bfv8*)&xtp[(size_t)(p4 * 16 + l16) * 1024 + kq * 32 + quad * 8];

    // ---- Y = P @ X per t4 (causality-pruned kq), write immediately ----
    bf16* yp = yout + (size_t)bt0 * I_ + h * P_;
    const bf16* xp = xs + (size_t)bt0 * I_ + h * P_;
#pragma unroll
    for (int t4 = 0; t4 < 4; ++t4) {
        fv4 y[8] = {};
#pragma unroll
        for (int kq = 0; kq < ((t4 < 2) ? 1 : 2); ++kq) {
            int rr = t4 * 16 + l16;
            bfv8 pf = *(const bfv8*)(Pb + rr * 128 + (((kq * 4 + quad) ^ (rr & 7)) << 4));
#pragma unroll
            for (int p4 = 0; p4 < 8; ++p4)
                y[p4] = MF(pf, xf[p4][kq], y[p4]);
        }
#pragma unroll
        for (int p4 = 0; p4 < 8; ++p4)
#pragma unroll
            for (int i = 0; i < 4; ++i) {
                size_t a = (size_t)(t4 * 16 + quad * 4 + i) * I_ + p4 * 16 + l16;
                float xv = __bfloat162float(xp[a]);
                yp[a] = __float2bfloat16(y[p4][i] + Dv * xv);
            }
    }

    // ---- SfinT[p][n] = X^T @ (w2 . B)^T ----
    float ws8[2][8];
#pragma unroll
    for (int kq = 0; kq < 2; ++kq)
#pragma unroll
        for (int j = 0; j < 8; ++j)
            ws8[kq][j] = g63 * __shfl(wl, kq * 32 + quad * 8 + j);

    fv4 sa[8][4] = {};
    const bf16* btp = btb + (size_t)b * 64 * 1024 + ci * 64;
#pragma unroll
    for (int kq = 0; kq < 2; ++kq) {
        bfv8 sbv[4];
#pragma unroll
        for (int n4 = 0; n4 < 4; ++n4) {
            bfv8 raw = *(const bfv8*)&btp[(size_t)(n4 * 16 + l16) * 1024 + kq * 32 + quad * 8];
            bfv8 sb;
#pragma unroll
            for (int j = 0; j < 8; ++j) sb[j] = f2b(bb2f(raw[j]) * ws8[kq][j]);
            sbv[n4] = sb;
        }
#pragma unroll
        for (int p4 = 0; p4 < 8; ++p4)
#pragma unroll
            for (int n4 = 0; n4 < 4; ++n4)
                sa[p4][n4] = MF(xf[p4][kq], sbv[n4], sa[p4][n4]);
    }

    bf16* sp = sfin + (size_t)wid * (128 * 64);
#pragma unroll
    for (int p4 = 0; p4 < 8; ++p4)
#pragma unroll
        for (int n4 = 0; n4 < 4; ++n4)
#pragma unroll
            for (int i = 0; i < 4; ++i)
                sp[(p4 * 16 + quad * 4 + i) * 64 + n4 * 16 + l16] =
                    __float2bfloat16(sa[p4][n4][i]);
}

// ---------------------------------------------------------------------------
// Pass B: chunk combine — element-wise in state index, layout-agnostic.
// ---------------------------------------------------------------------------
__global__ __launch_bounds__(128) void scan_combine_k(bf16* __restrict__ sbuf,
                                                      const float* __restrict__ gma) {
    int bid = blockIdx.x;                   // b*H*64 + h*64 + q
    int n = bid & 63;
    int h = (bid >> 6) & (H_ - 1);
    int b = bid >> 10;
    int p = threadIdx.x;
    size_t base0 = ((size_t)(b * (H_ * NC) + h * NC) * (128 * 64)) + n * 128 + p;
    int gbase = b * T_ * H_ + h;
    float S = 0.f;
#pragma unroll
    for (int ci = 0; ci < NC; ++ci) {
        bf16* addr = sbuf + base0 + (size_t)ci * (128 * 64);
        float tmp = __bfloat162float(*addr);            // S_fin of chunk ci
        *addr = __float2bfloat16(S);                    // S_init of chunk ci
        float G = gma[gbase + (ci * TC + TC - 1) * H_]; // uniform per block
        S = fmaf(G, S, tmp);
    }
}

// ---------------------------------------------------------------------------
// Pass C via MFMA: y[t][p] += gma_t * (C @ S_init)[t][p]
// ---------------------------------------------------------------------------
__global__ __launch_bounds__(256) void scan_corr_k(const float* __restrict__ bc,
                                                   const bf16* __restrict__ sfin,
                                                   const float* __restrict__ gma,
                                                   bf16* __restrict__ yout) {
    const int wv = threadIdx.x >> 6, lane = threadIdx.x & 63;
    const int wid = blockIdx.x * 4 + wv;
    const int ci = wid & (NC - 1), h = (wid >> 4) & (H_ - 1), b = wid >> 8;
    if (ci == 0) return;
    const int l16 = lane & 15, quad = lane >> 4;
    const int bt0 = b * T_ + ci * TC;

    float gl = gma[(size_t)(bt0 + lane) * H_ + h];
    float gmv[4][4];
#pragma unroll
    for (int t4 = 0; t4 < 4; ++t4)
#pragma unroll
        for (int i = 0; i < 4; ++i) gmv[t4][i] = __shfl(gl, t4 * 16 + quad * 4 + i);

    const bf16* sp = sfin + (size_t)wid * (128 * 64);
    fv4 z[4][8] = {};
#pragma unroll
    for (int kq = 0; kq < 2; ++kq) {
        bfv8 cf[4];
#pragma unroll
        for (int i = 0; i < 4; ++i)
            cf[i] = cvt8f(&bc[(size_t)(bt0 + i * 16 + l16) * 128 + 64 + kq * 32 + quad * 8]);
#pragma unroll
        for (int p4 = 0; p4 < 8; ++p4) {
            bfv8 sf = *(const bfv8*)&sp[(p4 * 16 + l16) * 64 + kq * 32 + quad * 8];
#pragma unroll
            for (int t4 = 0; t4 < 4; ++t4)
                z[t4][p4] = MF(cf[t4], sf, z[t4][p4]);
        }
    }

    bf16* yp = yout + (size_t)bt0 * I_ + h * P_;
#pragma unroll
    for (int t4 = 0; t4 < 4; ++t4)
#pragma unroll
        for (int i = 0; i < 4; ++i) {
            float gm = gmv[t4][i];
#pragma unroll
            for (int p4 = 0; p4 < 8; ++p4) {
                size_t a = (size_t)(t4 * 16 + quad * 4 + i) * I_ + p4 * 16 + l16;
                float yv = __bfloat162float(yp[a]);
                yp[a] = __float2bfloat16(yv + gm * z[t4][p4][i]);
            }
        }
}

// ---------------------------------------------------------------------------
__global__ __launch_bounds__(256) void cast_f2b_k(const float* __restrict__ in,
                                                  bf16* __restrict__ out) {
    int i = (blockIdx.x * 256 + threadIdx.x) * 4;
    float4 v = *(const float4*)&in[i];
    bf16 ov[4] = {__float2bfloat16(v.x), __float2bfloat16(v.y),
                  __float2bfloat16(v.z), __float2bfloat16(v.w)};
    *(uint2*)&out[i] = *(uint2*)ov;
}

// ---------------------------------------------------------------------------

static inline size_t align256(size_t x) { return (x + 255) & ~(size_t)255; }

extern "C" void kernel_launch(void* const* d_in, const int* in_sizes, int n_in,
                              void* d_out, int out_size, void* d_ws, size_t ws_size,
                              hipStream_t stream) {
    const float* x_in     = (const float*)d_in[0];
    const float* in_w     = (const float*)d_in[1];
    const float* in_b     = (const float*)d_in[2];
    const float* norm_w   = (const float*)d_in[3];
    const float* mix_in_w = (const float*)d_in[4];
    const float* conv_w   = (const float*)d_in[5];
    const float* conv_b   = (const float*)d_in[6];
    const float* dt_bias  = (const float*)d_in[7];
    const float* A_log    = (const float*)d_in[8];
    const float* Dvec     = (const float*)d_in[9];
    const float* gnorm_w  = (const float*)d_in[10];
    const float* mix_out_w= (const float*)d_in[11];
    const float* out_w    = (const float*)d_in[12];
    const float* out_b    = (const float*)d_in[13];
    const float* code_w   = (const float*)d_in[14];
    const float* code_b   = (const float*)d_in[15];
    float* outF0 = (float*)d_out;                       // [8192][512]
    float* outF1 = (float*)d_out + (size_t)M_ * OUT_;   // [8192][1024]

    char* p = (char*)d_ws;
    auto alloc = [&](size_t bytes) -> char* { char* r = p; p += align256(bytes); return r; };

    // xt region; hn and xb alias its low part (liveness disjoint).
    bf16*  xt       = (bf16*)alloc((size_t)B_ * H_ * 128 * T_ * 2);     // 33.5 MiB
    bf16*  hn       = xt;                                 // [M][D] bf16
    bf16*  xb       = xt + (size_t)M_ * D_;               // [M][INP] bf16
    bf16*  v_inb    = (bf16*)alloc(D_ * 2);
    bf16*  v_normw  = (bf16*)alloc(L_ * D_ * 2);
    bf16*  v_convw  = (bf16*)alloc(L_ * 3 * CONV_DIM * 2);
    bf16*  v_convb  = (bf16*)alloc(L_ * CONV_DIM * 2);
    bf16*  v_gnw    = (bf16*)alloc(L_ * I_ * 2);
    bf16*  v_headb  = (bf16*)alloc((OUT_ + CB_) * 2);
    bf16*  wt_in    = (bf16*)alloc((size_t)1024 * 512 * 2);
    bf16*  wt_big   = (bf16*)alloc((size_t)4352 * 1024 * 2);   // per-layer reuse
    bf16*  wt_small = (bf16*)alloc((size_t)1024 * 2048 * 2);   // per-layer reuse
    bf16*  wt_head  = (bf16*)alloc((size_t)1536 * 1024 * 2);
    float* hbuf     = (float*)alloc((size_t)M_ * D_ * 4);      // residual fp32
    bf16*  gate     = (bf16*)alloc((size_t)M_ * I_ * 2);
    bf16*  hbc      = (bf16*)alloc((size_t)M_ * CONV_DIM * 2); // conv in; reused as yscan
    float* dtraw    = (float*)alloc((size_t)M_ * H_ * 4);
    bf16*  xs       = (bf16*)alloc((size_t)M_ * I_ * 2);
    float* bcbuf    = (float*)alloc((size_t)M_ * 128 * 4);     // B | C
    float* wcob     = (float*)alloc((size_t)M_ * H_ * 4);
    float* gmab     = (float*)alloc((size_t)M_ * H_ * 4);
    bf16*  sfin     = (bf16*)alloc((size_t)B_ * H_ * NC * 128 * 64 * 2); // 33.5 MiB
    bf16*  bt16     = (bf16*)alloc((size_t)B_ * 64 * T_ * 2);           // 1 MiB
    (void)in_sizes; (void)n_in; (void)out_size;

    size_t needed = (size_t)(p - (char*)d_ws);
    if (needed > ws_size) return;   // diagnostic: absmax reads max|ref| (zeros)

    constexpr size_t SH_SQ = 49152;   // RING3 x (128+128)x32 bf16 -> 3 blk/CU
    static bool attr_done = false;
    if (!attr_done) {
        attr_done = true;
        (void)hipFuncSetAttribute((const void*)gemm8p<0, 128, 128, 2, 2, 3, 256>,
                                  hipFuncAttributeMaxDynamicSharedMemorySize, (int)SH_SQ);
        (void)hipFuncSetAttribute((const void*)gemm8p<1, 128, 128, 2, 2, 3, 256>,
                                  hipFuncAttributeMaxDynamicSharedMemorySize, (int)SH_SQ);
        (void)hipFuncSetAttribute((const void*)gemm8p<2, 128, 128, 2, 2, 3, 256>,
                                  hipFuncAttributeMaxDynamicSharedMemorySize, (int)SH_SQ);
        (void)hipFuncSetAttribute((const void*)gemm8p<3, 128, 128, 2, 2, 3, 256>,
                                  hipFuncAttributeMaxDynamicSharedMemorySize, (int)SH_SQ);
    }

    auto ing = [&](const float* src, bf16* dst, int n) {
        ingest_k<<<(n + 255) / 256, 256, 0, stream>>>(src, dst, n);
    };
    ing(x_in, xb, M_ * INP);
    ing(in_b, v_inb, D_);
    ing(norm_w, v_normw, L_ * D_);
    ing(conv_w, v_convw, L_ * 3 * CONV_DIM);
    ing(conv_b, v_convb, L_ * CONV_DIM);
    ing(gnorm_w, v_gnw, L_ * I_);
    ing(out_b, v_headb, OUT_);
    ing(code_b, v_headb + OUT_, CB_);

    dim3 tb(32, 8);
    transpose_any<<<dim3(32, 16), tb, 0, stream>>>(in_w, 0, wt_in, 512, 1024);
    transpose_any<<<dim3(16, 32), tb, 0, stream>>>(out_w, 0, wt_head, 1024, 512);
    transpose_any<<<dim3(32, 32), tb, 0, stream>>>(code_w, 0, wt_head + (size_t)512 * 1024,
                                                   1024, 1024);

    // h = x @ in_w + in_b     (M=8192, K=512, N=1024)
    gemm8p<0, 128, 128, 2, 2, 3, 256><<<dim3(8, 64), 256, SH_SQ, stream>>>(
        xb, wt_in, INP, D_, v_inb, hbuf, nullptr, nullptr, nullptr);

    for (int i = 0; i < L_; ++i) {
        transpose_any<<<dim3(136, 32), tb, 0, stream>>>(mix_in_w, (size_t)i * 1024 * PROJ,
                                                        wt_big, 1024, PROJ);
        transpose_any<<<dim3(32, 64), tb, 0, stream>>>(mix_out_w, (size_t)i * 2048 * 1024,
                                                       wt_small, 2048, 1024);
        rmsnorm_k<<<M_, 256, 0, stream>>>(hbuf, v_normw + i * D_, hn);
        // proj: M=8192, K=1024, N=4352(pad) -> 2176 blocks, 3 blk/CU
        gemm8p<1, 128, 128, 2, 2, 3, 256><<<dim3(34, 64), 256, SH_SQ, stream>>>(
            hn, wt_big, D_, 4352, nullptr, nullptr, gate, hbc, dtraw);
        conv_k<<<dim3(3, M_), 256, 0, stream>>>(hbc, v_convw + i * 3 * CONV_DIM,
                                                v_convb + i * CONV_DIM, xs, bcbuf);
        dtprep_k<<<B_ * NC * H_ / 4, 256, 0, stream>>>(
            dtraw, dt_bias + i * H_, A_log + i * H_, wcob, gmab);
        xpose_k<<<dim3(16, 256), 256, 0, stream>>>(xs, xt);
        btpose_k<<<dim3(16, 8), 256, 0, stream>>>(bcbuf, bt16);
        scan_mm_k<<<512, 256, 0, stream>>>(bcbuf, xt, bt16, wcob, gmab,
                                           Dvec + i * H_, xs, hbc, sfin);
        scan_combine_k<<<B_ * H_ * 64, 128, 0, stream>>>(sfin, gmab);
        scan_corr_k<<<512, 256, 0, stream>>>(bcbuf, sfin, gmab, hbc);
        gatednorm_k<<<M_, 256, 0, stream>>>(hbc, gate, v_gnw + i * I_, xs);
        // out proj: M=8192, K=2048, N=1024
        gemm8p<2, 128, 128, 2, 2, 3, 256><<<dim3(8, 64), 256, SH_SQ, stream>>>(
            xs, wt_small, I_, D_, nullptr, hbuf, nullptr, nullptr, nullptr);
    }

    // merged heads: N = 512 | 1024, one launch (768 blocks)
    cast_f2b_k<<<(M_ * D_) / 1024, 256, 0, stream>>>(hbuf, hn);
    gemm8p<3, 128, 128, 2, 2, 3, 256><<<dim3(12, 64), 256, SH_SQ, stream>>>(
        hn, wt_head, D_, 1536, v_headb, outF0, nullptr, nullptr, outF1);
}

// Round 7
// 1586.712 us; speedup vs baseline: 1.3972x; 1.0233x over previous
//
#include <hip/hip_runtime.h>
#include <hip/hip_bf16.h>

typedef __hip_bfloat16 bf16;
typedef __bf16 bfv8 __attribute__((ext_vector_type(8)));
typedef float fv4 __attribute__((ext_vector_type(4)));

#define B_  8
#define T_  1024
#define INP 512
#define D_  1024
#define I_  2048
#define N_  64
#define H_  16
#define P_  128
#define L_  4
#define OUT_ 512
#define CB_ 1024
#define CONV_DIM 2176
#define PROJ 4240
#define M_  (B_*T_)       // 8192 rows
#define TC  64            // scan chunk length
#define NC  (T_/TC)       // 16 chunks

typedef const __attribute__((address_space(1))) void gv_t;
typedef __attribute__((address_space(3))) void lv_t;

__device__ __forceinline__ void load_lds16(const bf16* g, char* l) {
    __builtin_amdgcn_global_load_lds((gv_t*)g, (lv_t*)l, 16, 0, 0);
}

template <int N> __device__ __forceinline__ void wait_vm() {
    if constexpr (N == 0)      asm volatile("s_waitcnt vmcnt(0)" ::: "memory");
    else if constexpr (N == 2) asm volatile("s_waitcnt vmcnt(2)" ::: "memory");
    else if constexpr (N == 3) asm volatile("s_waitcnt vmcnt(3)" ::: "memory");
    else if constexpr (N == 4) asm volatile("s_waitcnt vmcnt(4)" ::: "memory");
    else if constexpr (N == 6) asm volatile("s_waitcnt vmcnt(6)" ::: "memory");
    else                       asm volatile("s_waitcnt vmcnt(8)" ::: "memory");
}
__device__ __forceinline__ void barrier_sync() {
    asm volatile("s_barrier" ::: "memory");
}

__device__ __forceinline__ fv4 MF(bfv8 a, bfv8 b, fv4 c) {
    return __builtin_amdgcn_mfma_f32_16x16x32_bf16(a, b, c, 0, 0, 0);
}
__device__ __forceinline__ __bf16 f2b(float x) {
    __hip_bfloat16 h = __float2bfloat16(x);
    union { unsigned short u; __bf16 b; } t;
    t.u = *reinterpret_cast<unsigned short*>(&h);
    return t.b;
}
__device__ __forceinline__ float bb2f(__bf16 x) {
    union { __bf16 b; unsigned short u; } t; t.b = x;
    union { unsigned int u; float f; } r; r.u = (unsigned int)t.u << 16;
    return r.f;
}
__device__ __forceinline__ bfv8 cvt8f(const float* p) {
    float4 a = *(const float4*)p, b = *(const float4*)(p + 4);
    bfv8 r;
    r[0] = f2b(a.x); r[1] = f2b(a.y); r[2] = f2b(a.z); r[3] = f2b(a.w);
    r[4] = f2b(b.x); r[5] = f2b(b.y); r[6] = f2b(b.z); r[7] = f2b(b.w);
    return r;
}

// ---------------------------------------------------------------------------
// fp32 -> bf16 copy
// ---------------------------------------------------------------------------
__global__ __launch_bounds__(256) void ingest_k(const float* __restrict__ src,
                                                bf16* __restrict__ dst, int n) {
    int i = blockIdx.x * 256 + threadIdx.x;
    if (i >= n) return;
    dst[i] = __float2bfloat16(src[i]);
}

// ---------------------------------------------------------------------------
// Transpose fp32 [R][C] -> bf16 [Cp][R], zero-padding rows C..Cp.
// ---------------------------------------------------------------------------
__global__ __launch_bounds__(256) void transpose_any(const float* __restrict__ in,
                                                     size_t off,
                                                     bf16* __restrict__ out,
                                                     int R, int C) {
    __shared__ bf16 tile[32][33];
    int c0 = blockIdx.x * 32, r0 = blockIdx.y * 32;
    int tx = threadIdx.x, ty = threadIdx.y;
#pragma unroll
    for (int i = 0; i < 4; ++i) {
        int r = r0 + ty + i * 8, c = c0 + tx;
        bf16 v = __float2bfloat16(0.f);
        if (c < C) v = __float2bfloat16(in[off + (size_t)r * C + c]);
        tile[ty + i * 8][tx] = v;
    }
    __syncthreads();
#pragma unroll
    for (int i = 0; i < 4; ++i) {
        int c = c0 + ty + i * 8;
        out[(size_t)c * R + r0 + tx] = tile[tx][ty + i * 8];
    }
}

// ---------------------------------------------------------------------------
// GEMM, half-tile ring pipeline.
// MODE 0: outF = acc + bias         MODE 1: split gate/hBC/dt
// MODE 2: outF += acc               MODE 3: heads, col-split fp32 + bias
// ---------------------------------------------------------------------------
template <int MODE, int BM, int BN, int WGM, int WGN, int RING, int NTHR>
__global__ __launch_bounds__(NTHR) void gemm8p(const bf16* __restrict__ A,
                                               const bf16* __restrict__ Bt,
                                               int K, int N,
                                               const bf16* __restrict__ bias,
                                               float* __restrict__ outF,
                                               bf16* __restrict__ outB,
                                               bf16* __restrict__ outB2,
                                               float* __restrict__ outF2) {
    constexpr int HK = 32;
    constexpr int MT = BM / WGM / 16;
    constexpr int NT = BN / WGN / 16;
    constexpr int ABY = BM * HK * 2;
    constexpr int BBY = BN * HK * 2;
    constexpr int BUF = ABY + BBY;
    constexpr int RPI = NTHR / 4;
    constexpr int AL = BM / RPI;
    constexpr int BL = BN / RPI;
    constexpr int LD = AL + BL;
    constexpr int IB = NTHR * 16;

    extern __shared__ char lds[];
    const int tid = threadIdx.x;
    const int wv = tid >> 6, lane = tid & 63;
    const int l16 = lane & 15, quad = lane >> 4;
    const int wm = (wv / WGN) * (BM / WGM);
    const int wn = (wv % WGN) * (BN / WGN);

    const int NX = gridDim.x;
    const int nwg = NX * gridDim.y;
    const int orig = blockIdx.y * NX + blockIdx.x;
    const int q = nwg >> 3, r = nwg & 7, xcd = orig & 7, lid = orig >> 3;
    const int wg = (xcd < r ? xcd * (q + 1) : r * (q + 1) + (xcd - r) * q) + lid;
    const int m0 = (wg / NX) * BM;
    const int n0 = (wg % NX) * BN;

    const int srow = tid >> 2, sslot = tid & 3;
    const int swz = (sslot ^ ((srow >> 1) & 3)) << 3;
    const bf16* ga = A  + (size_t)(m0 + srow) * K + swz;
    const bf16* gb = Bt + (size_t)(n0 + srow) * K + swz;
    char* lw = lds + wv * 1024;

    const int HT = K / HK;

    auto stageA = [&](int stg, int rbuf) {
#pragma unroll
        for (int j = 0; j < AL; ++j)
            load_lds16(ga + (size_t)stg * HK + (size_t)(j * RPI) * K,
                       lw + rbuf * BUF + j * IB);
    };
    auto stageB = [&](int stg, int rbuf) {
#pragma unroll
        for (int j = 0; j < BL; ++j)
            load_lds16(gb + (size_t)stg * HK + (size_t)(j * RPI) * K,
                       lw + rbuf * BUF + ABY + j * IB);
    };

#pragma unroll
    for (int h = 0; h < RING - 1; ++h) { stageA(h, h); stageB(h, h); }
    wait_vm<LD>();
    barrier_sync();

    fv4 acc[MT][NT] = {};
    int rb = 0;
    for (int ht = 0; ht < HT; ++ht) {
        const char* Ab = lds + rb * BUF;
        const char* Bb = Ab + ABY;
        const int stg = ht + RING - 1;
        const int sb = (rb == 0) ? RING - 1 : rb - 1;
        const bool dostage = stg < HT;

        bfv8 bf[NT], af[MT];
#pragma unroll
        for (int i = 0; i < NT; ++i) {
            int rr = wn + i * 16 + l16;
            bf[i] = *(const bfv8*)(Bb + rr * 64 + ((quad ^ ((rr >> 1) & 3)) << 4));
        }
#pragma unroll
        for (int i = 0; i < MT; ++i) {
            int rr = wm + i * 16 + l16;
            af[i] = *(const bfv8*)(Ab + rr * 64 + ((quad ^ ((rr >> 1) & 3)) << 4));
        }
        if (dostage) { stageA(stg, sb); stageB(stg, sb); }
        __builtin_amdgcn_s_setprio(1);
#pragma unroll
        for (int mt = 0; mt < MT; ++mt)
#pragma unroll
            for (int nt = 0; nt < NT; ++nt)
                acc[mt][nt] = MF(af[mt], bf[nt], acc[mt][nt]);
        __builtin_amdgcn_s_setprio(0);

        int fut = HT - 1 - ht; if (fut > RING - 1) fut = RING - 1;
        if (fut >= 1) {
            int w = (fut - 1) * LD;
            if (w >= LD) wait_vm<LD>();
            else wait_vm<0>();
        }
        barrier_sync();
        rb = (rb + 1 == RING) ? 0 : rb + 1;
    }

#pragma unroll
    for (int mt = 0; mt < MT; ++mt) {
#pragma unroll
        for (int nt = 0; nt < NT; ++nt) {
#pragma unroll
            for (int i = 0; i < 4; ++i) {
                int row = m0 + wm + mt * 16 + quad * 4 + i;
                int col = n0 + wn + nt * 16 + l16;
                float v = acc[mt][nt][i];
                if (MODE == 0) {
                    v += __bfloat162float(bias[col]);
                    outF[(size_t)row * N + col] = v;
                } else if (MODE == 1) {
                    if (col < I_)
                        outB[(size_t)row * I_ + col] = __float2bfloat16(v);
                    else if (col < I_ + CONV_DIM)
                        outB2[(size_t)row * CONV_DIM + (col - I_)] = __float2bfloat16(v);
                    else if (col < PROJ)
                        outF2[(size_t)row * H_ + (col - (I_ + CONV_DIM))] = v;
                } else if (MODE == 2) {
                    outF[(size_t)row * N + col] += v;
                } else if (MODE == 3) {
                    v += __bfloat162float(bias[col]);
                    if (col < OUT_) outF[(size_t)row * OUT_ + col] = v;
                    else            outF2[(size_t)row * CB_ + (col - OUT_)] = v;
                }
            }
        }
    }
}

// ---------------------------------------------------------------------------
__global__ __launch_bounds__(256) void rmsnorm_k(const float* __restrict__ x,
                                                 const bf16* __restrict__ w,
                                                 bf16* __restrict__ out) {
    int row = blockIdx.x, tid = threadIdx.x;
    float4 v = *(const float4*)&x[(size_t)row * D_ + tid * 4];
    float ss = v.x * v.x + v.y * v.y + v.z * v.z + v.w * v.w;
#pragma unroll
    for (int off = 32; off; off >>= 1) ss += __shfl_down(ss, off);
    __shared__ float sb[4];
    if ((tid & 63) == 0) sb[tid >> 6] = ss;
    __syncthreads();
    ss = sb[0] + sb[1] + sb[2] + sb[3];
    float rs = rsqrtf(ss * (1.f / D_) + 1e-6f);
    float xv[4] = {v.x, v.y, v.z, v.w};
#pragma unroll
    for (int j = 0; j < 4; ++j)
        out[(size_t)row * D_ + tid * 4 + j] =
            __float2bfloat16(xv[j] * rs * __bfloat162float(w[tid * 4 + j]));
}

// ---------------------------------------------------------------------------
__global__ __launch_bounds__(256) void gatednorm_k(const bf16* __restrict__ y,
                                                   const bf16* __restrict__ g,
                                                   const bf16* __restrict__ w,
                                                   bf16* __restrict__ out) {
    int row = blockIdx.x, tid = threadIdx.x;
    size_t base = (size_t)row * I_ + tid * 8;
    bf16 yv[8], gv[8];
    *(uint4*)yv = *(const uint4*)&y[base];
    *(uint4*)gv = *(const uint4*)&g[base];
    float vv[8]; float ss = 0.f;
#pragma unroll
    for (int j = 0; j < 8; ++j) {
        float yf = __bfloat162float(yv[j]);
        float gf = __bfloat162float(gv[j]);
        float sig = 1.f / (1.f + expf(-gf));
        vv[j] = yf * gf * sig;
        ss += vv[j] * vv[j];
    }
#pragma unroll
    for (int off = 32; off; off >>= 1) ss += __shfl_down(ss, off);
    __shared__ float sb[4];
    if ((tid & 63) == 0) sb[tid >> 6] = ss;
    __syncthreads();
    ss = sb[0] + sb[1] + sb[2] + sb[3];
    float rs = rsqrtf(ss * (1.f / I_) + 1e-6f);
    bf16 ov[8];
#pragma unroll
    for (int j = 0; j < 8; ++j)
        ov[j] = __float2bfloat16(vv[j] * rs * __bfloat162float(w[tid * 8 + j]));
    *(uint4*)&out[base] = *(uint4*)ov;
}

// ---------------------------------------------------------------------------
// conv, sliding-window: each thread owns 4 channels x 8 timesteps.
// Input rows loaded once (10-row window incl. 2-row halo), not 3x.
// grid (17, B_*T_/8/8), block 256 = 32 cq x 8 t-groups.
// ---------------------------------------------------------------------------
__global__ __launch_bounds__(256) void conv_k(const bf16* __restrict__ hbc,
                                              const bf16* __restrict__ w,
                                              const bf16* __restrict__ bias,
                                              bf16* __restrict__ xs,
                                              float* __restrict__ bc) {
    int cq = blockIdx.x * 32 + (threadIdx.x & 31);      // [0,544)
    int btg = blockIdx.y * 8 + (threadIdx.x >> 5);      // [0,1024)
    int c = cq * 4;
    int bt0 = btg * 8;
    int t0 = bt0 & (T_ - 1);

    bf16 bv[4]; *(uint2*)bv = *(const uint2*)&bias[c];
    float bsf[4];
#pragma unroll
    for (int j = 0; j < 4; ++j) bsf[j] = __bfloat162float(bv[j]);
    float wf[3][4];
#pragma unroll
    for (int k = 0; k < 3; ++k) {
        bf16 wv[4]; *(uint2*)wv = *(const uint2*)&w[k * CONV_DIM + c];
#pragma unroll
        for (int j = 0; j < 4; ++j) wf[k][j] = __bfloat162float(wv[j]);
    }

    float win[10][4];
#pragma unroll
    for (int r = 0; r < 10; ++r) {
        if (t0 - 2 + r < 0) {          // sequence-start padding (t0==0, r<2)
#pragma unroll
            for (int j = 0; j < 4; ++j) win[r][j] = 0.f;
        } else {
            bf16 sv[4];
            *(uint2*)sv = *(const uint2*)&hbc[(size_t)(bt0 - 2 + r) * CONV_DIM + c];
#pragma unroll
            for (int j = 0; j < 4; ++j) win[r][j] = __bfloat162float(sv[j]);
        }
    }

#pragma unroll
    for (int i = 0; i < 8; ++i) {
        float acc[4];
#pragma unroll
        for (int j = 0; j < 4; ++j) acc[j] = bsf[j];
#pragma unroll
        for (int k = 0; k < 3; ++k)
#pragma unroll
            for (int j = 0; j < 4; ++j)
                acc[j] = fmaf(wf[k][j], win[i + k][j], acc[j]);
#pragma unroll
        for (int j = 0; j < 4; ++j) acc[j] = acc[j] / (1.f + expf(-acc[j]));  // silu
        if (c < I_) {
            bf16 ov[4];
#pragma unroll
            for (int j = 0; j < 4; ++j) ov[j] = __float2bfloat16(acc[j]);
            *(uint2*)&xs[(size_t)(bt0 + i) * I_ + c] = *(uint2*)ov;
        } else {
            float4 o; o.x = acc[0]; o.y = acc[1]; o.z = acc[2]; o.w = acc[3];
            *(float4*)&bc[(size_t)(bt0 + i) * 128 + (c - I_)] = o;
        }
    }
}

// ---------------------------------------------------------------------------
// dt prep, wave-parallel prefix scan.
// ---------------------------------------------------------------------------
__global__ __launch_bounds__(256) void dtprep_k(const float* __restrict__ dtraw,
                                                const float* __restrict__ dtb,
                                                const float* __restrict__ alog,
                                                float* __restrict__ wco,
                                                float* __restrict__ gma) {
    int chain = blockIdx.x * 4 + (threadIdx.x >> 6);   // b*256 + ci*16 + h
    int s = threadIdx.x & 63;
    int h = chain & 15, ci = (chain >> 4) & (NC - 1), b = chain >> 8;
    float a = -expf(alog[h]);
    float bz = dtb[h];
    int idx = (b * T_ + ci * TC + s) * H_ + h;
    float z = dtraw[idx] + bz;
    float dt = fmaxf(z, 0.f) + log1pf(expf(-fabsf(z)));
    float ps = dt * a;
#pragma unroll
    for (int d = 1; d < 64; d <<= 1) {
        float o = __shfl_up(ps, d, 64);
        if (s >= d) ps += o;
    }
    float g = expf(ps);
    wco[idx] = dt / g;
    gma[idx] = g;
}

// ---------------------------------------------------------------------------
// X transpose: xs [b*T][h*128+p] bf16 -> xt [(b*16+h)*128+p][T] bf16
// ---------------------------------------------------------------------------
__global__ __launch_bounds__(256) void xpose_k(const bf16* __restrict__ in,
                                               bf16* __restrict__ out) {
    __shared__ bf16 tl[64][72];
    int t0 = blockIdx.x * 64;
    int by = blockIdx.y;                  // b*32 + h*2 + pg
    int pg = by & 1, h = (by >> 1) & 15, b = by >> 5;
    int p0 = pg * 64;
    int tx = threadIdx.x & 15, ty = threadIdx.x >> 4;
#pragma unroll
    for (int i = 0; i < 4; ++i) {
        ushort4 v = *(const ushort4*)&in[(size_t)(b * T_ + t0 + ty + 16 * i) * 2048
                                         + h * 128 + p0 + tx * 4];
        tl[ty + 16 * i][tx * 4 + 0] = *(bf16*)&v.x;
        tl[ty + 16 * i][tx * 4 + 1] = *(bf16*)&v.y;
        tl[ty + 16 * i][tx * 4 + 2] = *(bf16*)&v.z;
        tl[ty + 16 * i][tx * 4 + 3] = *(bf16*)&v.w;
    }
    __syncthreads();
#pragma unroll
    for (int i = 0; i < 4; ++i) {
        ushort4 v;
        v.x = *(unsigned short*)&tl[tx * 4 + 0][ty + 16 * i];
        v.y = *(unsigned short*)&tl[tx * 4 + 1][ty + 16 * i];
        v.z = *(unsigned short*)&tl[tx * 4 + 2][ty + 16 * i];
        v.w = *(unsigned short*)&tl[tx * 4 + 3][ty + 16 * i];
        *(ushort4*)&out[(size_t)((b * 16 + h) * 128 + p0 + ty + 16 * i) * 1024
                        + t0 + tx * 4] = v;
    }
}

// ---------------------------------------------------------------------------
// B transpose: bc [b*T][128] fp32 (cols 0..63 = B) -> bt16 [b*64+n][T] bf16
// ---------------------------------------------------------------------------
__global__ __launch_bounds__(256) void btpose_k(const float* __restrict__ in,
                                                bf16* __restrict__ out) {
    __shared__ bf16 tl[64][72];
    int t0 = blockIdx.x * 64;
    int b = blockIdx.y;
    int tx = threadIdx.x & 15, ty = threadIdx.x >> 4;
#pragma unroll
    for (int i = 0; i < 4; ++i) {
        float4 v = *(const float4*)&in[(size_t)(b * T_ + t0 + ty + 16 * i) * 128 + tx * 4];
        tl[ty + 16 * i][tx * 4 + 0] = __float2bfloat16(v.x);
        tl[ty + 16 * i][tx * 4 + 1] = __float2bfloat16(v.y);
        tl[ty + 16 * i][tx * 4 + 2] = __float2bfloat16(v.z);
        tl[ty + 16 * i][tx * 4 + 3] = __float2bfloat16(v.w);
    }
    __syncthreads();
#pragma unroll
    for (int i = 0; i < 4; ++i) {
        ushort4 v;
        v.x = *(unsigned short*)&tl[tx * 4 + 0][ty + 16 * i];
        v.y = *(unsigned short*)&tl[tx * 4 + 1][ty + 16 * i];
        v.z = *(unsigned short*)&tl[tx * 4 + 2][ty + 16 * i];
        v.w = *(unsigned short*)&tl[tx * 4 + 3][ty + 16 * i];
        *(ushort4*)&out[(size_t)(b * 64 + ty + 16 * i) * 1024 + t0 + tx * 4] = v;
    }
}

// ---------------------------------------------------------------------------
// Chunked scan via MFMA (Mamba2 matmul form). One wave per (b,h,ci).
// ---------------------------------------------------------------------------
__global__ __launch_bounds__(256) void scan_mm_k(const float* __restrict__ bc,
                                                 const bf16* __restrict__ xt,
                                                 const bf16* __restrict__ btb,
                                                 const float* __restrict__ wco,
                                                 const float* __restrict__ gma,
                                                 const float* __restrict__ dvec,
                                                 const bf16* __restrict__ xs,
                                                 bf16* __restrict__ yout,
                                                 bf16* __restrict__ sfin) {
    __shared__ __align__(64) char plds[4][8192];
    const int wv = threadIdx.x >> 6, lane = threadIdx.x & 63;
    const int l16 = lane & 15, quad = lane >> 4;
    const int wid = blockIdx.x * 4 + wv;
    const int ci = wid & (NC - 1), h = (wid >> 4) & (H_ - 1), b = wid >> 8;
    const int bt0 = b * T_ + ci * TC;
    char* Pb = plds[wv];

    float wl = wco[(size_t)(bt0 + lane) * H_ + h];
    float gl = gma[(size_t)(bt0 + lane) * H_ + h];
    float g63 = __shfl(gl, 63);
    float Dv = dvec[h];

    float wsv[4], gmv[4][4];
#pragma unroll
    for (int s4 = 0; s4 < 4; ++s4) wsv[s4] = __shfl(wl, s4 * 16 + l16);
#pragma unroll
    for (int t4 = 0; t4 < 4; ++t4)
#pragma unroll
        for (int i = 0; i < 4; ++i) gmv[t4][i] = __shfl(gl, t4 * 16 + quad * 4 + i);

    // ---- G = C @ B^T ----
    fv4 g[4][4] = {};
#pragma unroll
    for (int kq = 0; kq < 2; ++kq) {
        bfv8 cf[4], bfr[4];
#pragma unroll
        for (int i = 0; i < 4; ++i) {
            cf[i]  = cvt8f(&bc[(size_t)(bt0 + i * 16 + l16) * 128 + 64 + kq * 32 + quad * 8]);
            bfr[i] = cvt8f(&bc[(size_t)(bt0 + i * 16 + l16) * 128 + kq * 32 + quad * 8]);
        }
#pragma unroll
        for (int t4 = 0; t4 < 4; ++t4)
#pragma unroll
            for (int s4 = 0; s4 < 4; ++s4)
                g[t4][s4] = MF(cf[t4], bfr[s4], g[t4][s4]);
    }

    // ---- P -> LDS (decay, causal mask, swizzled) ----
#pragma unroll
    for (int t4 = 0; t4 < 4; ++t4)
#pragma unroll
        for (int s4 = 0; s4 < 4; ++s4)
#pragma unroll
            for (int i = 0; i < 4; ++i) {
                int t = t4 * 16 + quad * 4 + i, s = s4 * 16 + l16;
                float pv = (s <= t) ? g[t4][s4][i] * gmv[t4][i] * wsv[s4] : 0.f;
                int slot = (s >> 3) ^ (t & 7);
                *(__bf16*)(Pb + t * 128 + slot * 16 + (s & 7) * 2) = f2b(pv);
            }

    // ---- load X^T fragments (shared by PV and Sfin) ----
    bfv8 xf[8][2];
    const bf16* xtp = xt + (size_t)((b * 16 + h) * 128) * 1024 + ci * 64;
#pragma unroll
    for (int p4 = 0; p4 < 8; ++p4)
#pragma unroll
        for (int kq = 0; kq < 2; ++kq)
            xf[p4][kq] = *(const bfv8*)&xtp[(size_t)(p4 * 16 + l16) * 1024 + kq * 32 + quad * 8];

    // ---- Y = P @ X per t4 (causality-pruned kq), write immediately ----
    bf16* yp = yout + (size_t)bt0 * I_ + h * P_;
    const bf16* xp = xs + (size_t)bt0 * I_ + h * P_;
#pragma unroll
    for (int t4 = 0; t4 < 4; ++t4) {
        fv4 y[8] = {};
#pragma unroll
        for (int kq = 0; kq < ((t4 < 2) ? 1 : 2); ++kq) {
            int rr = t4 * 16 + l16;
            bfv8 pf = *(const bfv8*)(Pb + rr * 128 + (((kq * 4 + quad) ^ (rr & 7)) << 4));
#pragma unroll
            for (int p4 = 0; p4 < 8; ++p4)
                y[p4] = MF(pf, xf[p4][kq], y[p4]);
        }
#pragma unroll
        for (int p4 = 0; p4 < 8; ++p4)
#pragma unroll
            for (int i = 0; i < 4; ++i) {
                size_t a = (size_t)(t4 * 16 + quad * 4 + i) * I_ + p4 * 16 + l16;
                float xv = __bfloat162float(xp[a]);
                yp[a] = __float2bfloat16(y[p4][i] + Dv * xv);
            }
    }

    // ---- SfinT[p][n] = X^T @ (w2 . B)^T ----
    float ws8[2][8];
#pragma unroll
    for (int kq = 0; kq < 2; ++kq)
#pragma unroll
        for (int j = 0; j < 8; ++j)
            ws8[kq][j] = g63 * __shfl(wl, kq * 32 + quad * 8 + j);

    fv4 sa[8][4] = {};
    const bf16* btp = btb + (size_t)b * 64 * 1024 + ci * 64;
#pragma unroll
    for (int kq = 0; kq < 2; ++kq) {
        bfv8 sbv[4];
#pragma unroll
        for (int n4 = 0; n4 < 4; ++n4) {
            bfv8 raw = *(const bfv8*)&btp[(size_t)(n4 * 16 + l16) * 1024 + kq * 32 + quad * 8];
            bfv8 sb;
#pragma unroll
            for (int j = 0; j < 8; ++j) sb[j] = f2b(bb2f(raw[j]) * ws8[kq][j]);
            sbv[n4] = sb;
        }
#pragma unroll
        for (int p4 = 0; p4 < 8; ++p4)
#pragma unroll
            for (int n4 = 0; n4 < 4; ++n4)
                sa[p4][n4] = MF(xf[p4][kq], sbv[n4], sa[p4][n4]);
    }

    bf16* sp = sfin + (size_t)wid * (128 * 64);
#pragma unroll
    for (int p4 = 0; p4 < 8; ++p4)
#pragma unroll
        for (int n4 = 0; n4 < 4; ++n4)
#pragma unroll
            for (int i = 0; i < 4; ++i)
                sp[(p4 * 16 + quad * 4 + i) * 64 + n4 * 16 + l16] =
                    __float2bfloat16(sa[p4][n4][i]);
}

// ---------------------------------------------------------------------------
// Pass B: chunk combine — element-wise in state index, layout-agnostic.
// ---------------------------------------------------------------------------
__global__ __launch_bounds__(128) void scan_combine_k(bf16* __restrict__ sbuf,
                                                      const float* __restrict__ gma) {
    int bid = blockIdx.x;                   // b*H*64 + h*64 + q
    int n = bid & 63;
    int h = (bid >> 6) & (H_ - 1);
    int b = bid >> 10;
    int p = threadIdx.x;
    size_t base0 = ((size_t)(b * (H_ * NC) + h * NC) * (128 * 64)) + n * 128 + p;
    int gbase = b * T_ * H_ + h;
    float S = 0.f;
#pragma unroll
    for (int ci = 0; ci < NC; ++ci) {
        bf16* addr = sbuf + base0 + (size_t)ci * (128 * 64);
        float tmp = __bfloat162float(*addr);            // S_fin of chunk ci
        *addr = __float2bfloat16(S);                    // S_init of chunk ci
        float G = gma[gbase + (ci * TC + TC - 1) * H_]; // uniform per block
        S = fmaf(G, S, tmp);
    }
}

// ---------------------------------------------------------------------------
// Pass C via MFMA: y[t][p] += gma_t * (C @ S_init)[t][p]
// ---------------------------------------------------------------------------
__global__ __launch_bounds__(256) void scan_corr_k(const float* __restrict__ bc,
                                                   const bf16* __restrict__ sfin,
                                                   const float* __restrict__ gma,
                                                   bf16* __restrict__ yout) {
    const int wv = threadIdx.x >> 6, lane = threadIdx.x & 63;
    const int wid = blockIdx.x * 4 + wv;
    const int ci = wid & (NC - 1), h = (wid >> 4) & (H_ - 1), b = wid >> 8;
    if (ci == 0) return;
    const int l16 = lane & 15, quad = lane >> 4;
    const int bt0 = b * T_ + ci * TC;

    float gl = gma[(size_t)(bt0 + lane) * H_ + h];
    float gmv[4][4];
#pragma unroll
    for (int t4 = 0; t4 < 4; ++t4)
#pragma unroll
        for (int i = 0; i < 4; ++i) gmv[t4][i] = __shfl(gl, t4 * 16 + quad * 4 + i);

    const bf16* sp = sfin + (size_t)wid * (128 * 64);
    fv4 z[4][8] = {};
#pragma unroll
    for (int kq = 0; kq < 2; ++kq) {
        bfv8 cf[4];
#pragma unroll
        for (int i = 0; i < 4; ++i)
            cf[i] = cvt8f(&bc[(size_t)(bt0 + i * 16 + l16) * 128 + 64 + kq * 32 + quad * 8]);
#pragma unroll
        for (int p4 = 0; p4 < 8; ++p4) {
            bfv8 sf = *(const bfv8*)&sp[(p4 * 16 + l16) * 64 + kq * 32 + quad * 8];
#pragma unroll
            for (int t4 = 0; t4 < 4; ++t4)
                z[t4][p4] = MF(cf[t4], sf, z[t4][p4]);
        }
    }

    bf16* yp = yout + (size_t)bt0 * I_ + h * P_;
#pragma unroll
    for (int t4 = 0; t4 < 4; ++t4)
#pragma unroll
        for (int i = 0; i < 4; ++i) {
            float gm = gmv[t4][i];
#pragma unroll
            for (int p4 = 0; p4 < 8; ++p4) {
                size_t a = (size_t)(t4 * 16 + quad * 4 + i) * I_ + p4 * 16 + l16;
                float yv = __bfloat162float(yp[a]);
                yp[a] = __float2bfloat16(yv + gm * z[t4][p4][i]);
            }
        }
}

// ---------------------------------------------------------------------------
__global__ __launch_bounds__(256) void cast_f2b_k(const float* __restrict__ in,
                                                  bf16* __restrict__ out) {
    int i = (blockIdx.x * 256 + threadIdx.x) * 4;
    float4 v = *(const float4*)&in[i];
    bf16 ov[4] = {__float2bfloat16(v.x), __float2bfloat16(v.y),
                  __float2bfloat16(v.z), __float2bfloat16(v.w)};
    *(uint2*)&out[i] = *(uint2*)ov;
}

// ---------------------------------------------------------------------------

static inline size_t align256(size_t x) { return (x + 255) & ~(size_t)255; }

extern "C" void kernel_launch(void* const* d_in, const int* in_sizes, int n_in,
                              void* d_out, int out_size, void* d_ws, size_t ws_size,
                              hipStream_t stream) {
    const float* x_in     = (const float*)d_in[0];
    const float* in_w     = (const float*)d_in[1];
    const float* in_b     = (const float*)d_in[2];
    const float* norm_w   = (const float*)d_in[3];
    const float* mix_in_w = (const float*)d_in[4];
    const float* conv_w   = (const float*)d_in[5];
    const float* conv_b   = (const float*)d_in[6];
    const float* dt_bias  = (const float*)d_in[7];
    const float* A_log    = (const float*)d_in[8];
    const float* Dvec     = (const float*)d_in[9];
    const float* gnorm_w  = (const float*)d_in[10];
    const float* mix_out_w= (const float*)d_in[11];
    const float* out_w    = (const float*)d_in[12];
    const float* out_b    = (const float*)d_in[13];
    const float* code_w   = (const float*)d_in[14];
    const float* code_b   = (const float*)d_in[15];
    float* outF0 = (float*)d_out;                       // [8192][512]
    float* outF1 = (float*)d_out + (size_t)M_ * OUT_;   // [8192][1024]

    char* p = (char*)d_ws;
    auto alloc = [&](size_t bytes) -> char* { char* r = p; p += align256(bytes); return r; };

    // xt region; hn and xb alias its low part (liveness disjoint).
    bf16*  xt       = (bf16*)alloc((size_t)B_ * H_ * 128 * T_ * 2);     // 33.5 MiB
    bf16*  hn       = xt;                                 // [M][D] bf16
    bf16*  xb       = xt + (size_t)M_ * D_;               // [M][INP] bf16
    bf16*  v_inb    = (bf16*)alloc(D_ * 2);
    bf16*  v_normw  = (bf16*)alloc(L_ * D_ * 2);
    bf16*  v_convw  = (bf16*)alloc(L_ * 3 * CONV_DIM * 2);
    bf16*  v_convb  = (bf16*)alloc(L_ * CONV_DIM * 2);
    bf16*  v_gnw    = (bf16*)alloc(L_ * I_ * 2);
    bf16*  v_headb  = (bf16*)alloc((OUT_ + CB_) * 2);
    bf16*  wt_in    = (bf16*)alloc((size_t)1024 * 512 * 2);
    bf16*  wt_big   = (bf16*)alloc((size_t)4352 * 1024 * 2);   // per-layer reuse
    bf16*  wt_small = (bf16*)alloc((size_t)1024 * 2048 * 2);   // per-layer reuse
    bf16*  wt_head  = (bf16*)alloc((size_t)1536 * 1024 * 2);
    float* hbuf     = (float*)alloc((size_t)M_ * D_ * 4);      // residual fp32
    bf16*  gate     = (bf16*)alloc((size_t)M_ * I_ * 2);
    bf16*  hbc      = (bf16*)alloc((size_t)M_ * CONV_DIM * 2); // conv in; reused as yscan
    float* dtraw    = (float*)alloc((size_t)M_ * H_ * 4);
    bf16*  xs       = (bf16*)alloc((size_t)M_ * I_ * 2);
    float* bcbuf    = (float*)alloc((size_t)M_ * 128 * 4);     // B | C
    float* wcob     = (float*)alloc((size_t)M_ * H_ * 4);
    float* gmab     = (float*)alloc((size_t)M_ * H_ * 4);
    bf16*  sfin     = (bf16*)alloc((size_t)B_ * H_ * NC * 128 * 64 * 2); // 33.5 MiB
    bf16*  bt16     = (bf16*)alloc((size_t)B_ * 64 * T_ * 2);           // 1 MiB
    (void)in_sizes; (void)n_in; (void)out_size;

    size_t needed = (size_t)(p - (char*)d_ws);
    if (needed > ws_size) return;   // diagnostic: absmax reads max|ref| (zeros)

    constexpr size_t SH_PROJ = 73728;   // RING3 x (256+128)x32 bf16 -> 2 blk/CU
    constexpr size_t SH_SQ   = 49152;   // RING3 x (128+128)x32 bf16 -> 3 blk/CU
    static bool attr_done = false;
    if (!attr_done) {
        attr_done = true;
        (void)hipFuncSetAttribute((const void*)gemm8p<1, 256, 128, 4, 2, 3, 512>,
                                  hipFuncAttributeMaxDynamicSharedMemorySize, (int)SH_PROJ);
        (void)hipFuncSetAttribute((const void*)gemm8p<0, 128, 128, 2, 2, 3, 256>,
                                  hipFuncAttributeMaxDynamicSharedMemorySize, (int)SH_SQ);
        (void)hipFuncSetAttribute((const void*)gemm8p<2, 128, 128, 2, 2, 3, 256>,
                                  hipFuncAttributeMaxDynamicSharedMemorySize, (int)SH_SQ);
        (void)hipFuncSetAttribute((const void*)gemm8p<3, 128, 128, 2, 2, 3, 256>,
                                  hipFuncAttributeMaxDynamicSharedMemorySize, (int)SH_SQ);
    }

    auto ing = [&](const float* src, bf16* dst, int n) {
        ingest_k<<<(n + 255) / 256, 256, 0, stream>>>(src, dst, n);
    };
    ing(x_in, xb, M_ * INP);
    ing(in_b, v_inb, D_);
    ing(norm_w, v_normw, L_ * D_);
    ing(conv_w, v_convw, L_ * 3 * CONV_DIM);
    ing(conv_b, v_convb, L_ * CONV_DIM);
    ing(gnorm_w, v_gnw, L_ * I_);
    ing(out_b, v_headb, OUT_);
    ing(code_b, v_headb + OUT_, CB_);

    dim3 tb(32, 8);
    transpose_any<<<dim3(32, 16), tb, 0, stream>>>(in_w, 0, wt_in, 512, 1024);
    transpose_any<<<dim3(16, 32), tb, 0, stream>>>(out_w, 0, wt_head, 1024, 512);
    transpose_any<<<dim3(32, 32), tb, 0, stream>>>(code_w, 0, wt_head + (size_t)512 * 1024,
                                                   1024, 1024);

    // h = x @ in_w + in_b     (M=8192, K=512, N=1024)
    gemm8p<0, 128, 128, 2, 2, 3, 256><<<dim3(8, 64), 256, SH_SQ, stream>>>(
        xb, wt_in, INP, D_, v_inb, hbuf, nullptr, nullptr, nullptr);

    for (int i = 0; i < L_; ++i) {
        transpose_any<<<dim3(136, 32), tb, 0, stream>>>(mix_in_w, (size_t)i * 1024 * PROJ,
                                                        wt_big, 1024, PROJ);
        transpose_any<<<dim3(32, 64), tb, 0, stream>>>(mix_out_w, (size_t)i * 2048 * 1024,
                                                       wt_small, 2048, 1024);
        rmsnorm_k<<<M_, 256, 0, stream>>>(hbuf, v_normw + i * D_, hn);
        // proj: M=8192, K=1024, N=4352(pad) — r5-proven config (95 µs, FETCH 143MB)
        gemm8p<1, 256, 128, 4, 2, 3, 512><<<dim3(34, 32), 512, SH_PROJ, stream>>>(
            hn, wt_big, D_, 4352, nullptr, nullptr, gate, hbc, dtraw);
        conv_k<<<dim3(17, 128), 256, 0, stream>>>(hbc, v_convw + i * 3 * CONV_DIM,
                                                  v_convb + i * CONV_DIM, xs, bcbuf);
        dtprep_k<<<B_ * NC * H_ / 4, 256, 0, stream>>>(
            dtraw, dt_bias + i * H_, A_log + i * H_, wcob, gmab);
        xpose_k<<<dim3(16, 256), 256, 0, stream>>>(xs, xt);
        btpose_k<<<dim3(16, 8), 256, 0, stream>>>(bcbuf, bt16);
        scan_mm_k<<<512, 256, 0, stream>>>(bcbuf, xt, bt16, wcob, gmab,
                                           Dvec + i * H_, xs, hbc, sfin);
        scan_combine_k<<<B_ * H_ * 64, 128, 0, stream>>>(sfin, gmab);
        scan_corr_k<<<512, 256, 0, stream>>>(bcbuf, sfin, gmab, hbc);
        gatednorm_k<<<M_, 256, 0, stream>>>(hbc, gate, v_gnw + i * I_, xs);
        // out proj: M=8192, K=2048, N=1024
        gemm8p<2, 128, 128, 2, 2, 3, 256><<<dim3(8, 64), 256, SH_SQ, stream>>>(
            xs, wt_small, I_, D_, nullptr, hbuf, nullptr, nullptr, nullptr);
    }

    // merged heads: N = 512 | 1024, one launch (768 blocks)
    cast_f2b_k<<<(M_ * D_) / 1024, 256, 0, stream>>>(hbuf, hn);
    gemm8p<3, 128, 128, 2, 2, 3, 256><<<dim3(12, 64), 256, SH_SQ, stream>>>(
        hn, wt_head, D_, 1536, v_headb, outF0, nullptr, nullptr, outF1);
}